// Round 1
// baseline (313.153 us; speedup 1.0000x reference)
//
#include <hip/hip_runtime.h>
#include <stdint.h>

#define DEVI __device__ __forceinline__

constexpr int Bb = 2, NQ = 1024, S = 4096, H = 1024, NH = 16, HD = 64;

typedef __bf16 bf16x8 __attribute__((ext_vector_type(8)));
typedef float f32x4 __attribute__((ext_vector_type(4)));
typedef unsigned short u16;
typedef u16 u16x8 __attribute__((ext_vector_type(8)));

DEVI u16 f2bf(float f) {
  union { float f; unsigned u; } v; v.f = f;
  unsigned r = (v.u + 0x7fffu + ((v.u >> 16) & 1u)) >> 16;
  return (u16)r;
}

DEVI void gload_lds16(const void* g, void* lds) {
  __builtin_amdgcn_global_load_lds(
      (const __attribute__((address_space(1))) void*)(uintptr_t)g,
      (__attribute__((address_space(3))) void*)(uint32_t)(uintptr_t)lds,
      16, 0, 0);
}

// ---------------- mask normalize: detect bool(1B) vs int32(4B), emit u8 ----
__global__ void mask_norm_kernel(const unsigned char* __restrict__ m,
                                 unsigned char* __restrict__ out) {
  __shared__ int isByte;
  if (threadIdx.x == 0) isByte = 0;
  __syncthreads();
  int any = 0;
  for (int p = threadIdx.x; p < Bb * S; p += 256)
    if ((p & 3) && m[p]) any = 1;
  if (any) atomicOr(&isByte, 1);
  __syncthreads();
  const int bytemode = isByte;
  for (int i = threadIdx.x; i < Bb * S; i += 256) {
    unsigned char v = bytemode ? (unsigned char)(m[i] != 0)
                               : (unsigned char)(((const int*)m)[i] != 0);
    out[i] = v;
  }
}

// ---------------- LayerNorm (f32 in) + cast bf16, one wave per row ---------
__global__ __launch_bounds__(256) void ln_cast_kernel(
    const float* __restrict__ x, const float* __restrict__ gamma,
    const float* __restrict__ beta, u16* __restrict__ out, int nrows) {
  int row = blockIdx.x * 4 + (threadIdx.x >> 6);
  int lane = threadIdx.x & 63;
  if (row >= nrows) return;
  const float4* xr = (const float4*)(x + (size_t)row * H);
  float4 v[4];
  float s = 0.f, s2 = 0.f;
#pragma unroll
  for (int i = 0; i < 4; ++i) {
    v[i] = xr[lane + i * 64];
    s += v[i].x + v[i].y + v[i].z + v[i].w;
    s2 += v[i].x * v[i].x + v[i].y * v[i].y + v[i].z * v[i].z + v[i].w * v[i].w;
  }
#pragma unroll
  for (int d = 1; d < 64; d <<= 1) { s += __shfl_xor(s, d); s2 += __shfl_xor(s2, d); }
  float mu = s * (1.f / H);
  float rstd = rsqrtf(s2 * (1.f / H) - mu * mu + 1e-6f);
  u16* orow = out + (size_t)row * H;
  const float4* g4 = (const float4*)gamma;
  const float4* b4 = (const float4*)beta;
#pragma unroll
  for (int i = 0; i < 4; ++i) {
    float4 g = g4[lane + i * 64], bb = b4[lane + i * 64];
    ushort4 o;
    o.x = f2bf((v[i].x - mu) * rstd * g.x + bb.x);
    o.y = f2bf((v[i].y - mu) * rstd * g.y + bb.y);
    o.z = f2bf((v[i].z - mu) * rstd * g.z + bb.z);
    o.w = f2bf((v[i].w - mu) * rstd * g.w + bb.w);
    *(ushort4*)(orow + (size_t)(lane + i * 64) * 4) = o;
  }
}

// ---------------- transpose f32 [R][C] -> bf16 [C][R] ----------------------
__global__ __launch_bounds__(256) void transpose_cast_kernel(
    const float* __restrict__ in, u16* __restrict__ out, int R, int C) {
  __shared__ float tile[32][33];
  int c0 = blockIdx.x * 32, r0 = blockIdx.y * 32;
  int tx = threadIdx.x & 31, ty = threadIdx.x >> 5;
#pragma unroll
  for (int i = 0; i < 32; i += 8)
    tile[ty + i][tx] = in[(size_t)(r0 + ty + i) * C + c0 + tx];
  __syncthreads();
#pragma unroll
  for (int i = 0; i < 32; i += 8)
    out[(size_t)(c0 + ty + i) * R + r0 + tx] = f2bf(tile[tx][ty + i]);
}

// ---------------- 128x128 bf16 GEMM, C = A[M,K] * Bt[N,K]^T + bias ---------
// EPI 0: -> Q buf [B][NH][NQ][HD] bf16      (A rows = b*NQ+nq, c = h*64+d)
// EPI 1: -> K/V bufs [B][NH][S][HD] bf16    (c<1024 -> K, else V)
// EPI 2: -> f32 out [M][1024]
template <int EPI>
__global__ __launch_bounds__(256) void gemm_bt_kernel(
    const u16* __restrict__ A, const u16* __restrict__ Bt,
    const float* __restrict__ bias, void* __restrict__ outp) {
  constexpr int K = 1024, BK = 32;
  __shared__ __align__(16) u16 Ash[128 * BK];
  __shared__ __align__(16) u16 Bsh[128 * BK];
  const int tid = threadIdx.x, w = tid >> 6, lane = tid & 63;
  const int brow = blockIdx.y * 128, bcol = blockIdx.x * 128;
  const u16* Ag = A + (size_t)brow * K;
  const u16* Bg = Bt + (size_t)bcol * K;
  const int c0 = tid, c1 = tid + 256;
  const int wr = (w >> 1) * 64, wc = (w & 1) * 64;
  const int fr = lane & 15, fq = lane >> 4;
  f32x4 acc[4][4] = {};

  for (int k0 = 0; k0 < K; k0 += BK) {
    gload_lds16(Ag + (size_t)(c0 >> 2) * K + k0 + (c0 & 3) * 8, Ash + c0 * 8);
    gload_lds16(Ag + (size_t)(c1 >> 2) * K + k0 + (c1 & 3) * 8, Ash + c1 * 8);
    gload_lds16(Bg + (size_t)(c0 >> 2) * K + k0 + (c0 & 3) * 8, Bsh + c0 * 8);
    gload_lds16(Bg + (size_t)(c1 >> 2) * K + k0 + (c1 & 3) * 8, Bsh + c1 * 8);
    asm volatile("s_waitcnt vmcnt(0)" ::: "memory");
    __syncthreads();
    bf16x8 af[4], bfr[4];
#pragma unroll
    for (int m = 0; m < 4; ++m)
      af[m] = *(const bf16x8*)(Ash + (wr + m * 16 + fr) * BK + fq * 8);
#pragma unroll
    for (int n = 0; n < 4; ++n)
      bfr[n] = *(const bf16x8*)(Bsh + (wc + n * 16 + fr) * BK + fq * 8);
#pragma unroll
    for (int m = 0; m < 4; ++m)
#pragma unroll
      for (int n = 0; n < 4; ++n)
        acc[m][n] = __builtin_amdgcn_mfma_f32_16x16x32_bf16(af[m], bfr[n], acc[m][n], 0, 0, 0);
    __syncthreads();
  }

#pragma unroll
  for (int m = 0; m < 4; ++m)
#pragma unroll
    for (int n = 0; n < 4; ++n)
#pragma unroll
      for (int i = 0; i < 4; ++i) {
        int r = brow + wr + m * 16 + fq * 4 + i;
        int c = bcol + wc + n * 16 + fr;
        float val = acc[m][n][i] + bias[c];
        if constexpr (EPI == 0) {
          u16* qb = (u16*)outp;
          qb[((((size_t)(r >> 10)) * NH + (c >> 6)) * NQ + (r & (NQ - 1))) * HD + (c & 63)] = f2bf(val);
        } else if constexpr (EPI == 1) {
          u16* kb = (u16*)outp;
          u16* vb = kb + (size_t)Bb * NH * S * HD;
          int cc = c & 1023;
          u16* dst = (c < 1024) ? kb : vb;
          dst[((((size_t)(r >> 12)) * NH + (cc >> 6)) * S + (r & (S - 1))) * HD + (cc & 63)] = f2bf(val);
        } else {
          float* ob = (float*)outp;
          ob[(size_t)r * H + c] = val;
        }
      }
}

// ---------------- flash attention: 4 waves, QBLK=64 (16 rows/wave), KVBLK=64
__global__ __launch_bounds__(256) void attn_kernel(
    const u16* __restrict__ Qb, const u16* __restrict__ Kb,
    const u16* __restrict__ Vb, const unsigned char* __restrict__ mask,
    u16* __restrict__ out) {
  __shared__ __align__(16) u16 Ksh[64][72];
  __shared__ __align__(16) u16 Vsh[64][72];   // transposed: [dim][kv]
  __shared__ __align__(16) u16 Psh[4][16][72];
  __shared__ unsigned char msk[64];
  const int q0 = blockIdx.x * 64;
  const int bh = blockIdx.y, b = bh >> 4, h = bh & 15;
  const int tid = threadIdx.x, w = tid >> 6, lane = tid & 63;
  const int fr = lane & 15, fq = lane >> 4;
  const u16* Qg = Qb + ((size_t)bh * NQ + q0 + w * 16) * HD;
  const u16* Kg = Kb + (size_t)bh * S * HD;
  const u16* Vg = Vb + (size_t)bh * S * HD;
  const unsigned char* mg = mask + (size_t)b * S;

  bf16x8 qf0 = *(const bf16x8*)(Qg + fr * HD + fq * 8);
  bf16x8 qf1 = *(const bf16x8*)(Qg + fr * HD + 32 + fq * 8);

  f32x4 oacc[4] = {};
  float mrow[4] = {-1e30f, -1e30f, -1e30f, -1e30f};
  float lrow[4] = {0.f, 0.f, 0.f, 0.f};

  for (int kt = 0; kt < S; kt += 64) {
#pragma unroll
    for (int i = 0; i < 2; ++i) {
      int c = tid + i * 256;
      int r = c >> 3, cg = c & 7;
      u16x8 kv = *(const u16x8*)(Kg + (size_t)(kt + r) * HD + cg * 8);
      *(u16x8*)(&Ksh[r][cg * 8]) = kv;
      u16x8 vv = *(const u16x8*)(Vg + (size_t)(kt + r) * HD + cg * 8);
#pragma unroll
      for (int j = 0; j < 8; ++j) Vsh[cg * 8 + j][r] = vv[j];
    }
    if (tid < 64) msk[tid] = mg[kt + tid];
    __syncthreads();

    // S = Q K^T  (rows = q, cols = kv)
    f32x4 sa[4];
#pragma unroll
    for (int nt = 0; nt < 4; ++nt) {
      bf16x8 k0v = *(const bf16x8*)(&Ksh[nt * 16 + fr][fq * 8]);
      bf16x8 k1v = *(const bf16x8*)(&Ksh[nt * 16 + fr][32 + fq * 8]);
      f32x4 t = {};
      t = __builtin_amdgcn_mfma_f32_16x16x32_bf16(qf0, k0v, t, 0, 0, 0);
      t = __builtin_amdgcn_mfma_f32_16x16x32_bf16(qf1, k1v, t, 0, 0, 0);
      sa[nt] = t;
    }
    float pm[4] = {-1e30f, -1e30f, -1e30f, -1e30f};
#pragma unroll
    for (int nt = 0; nt < 4; ++nt) {
      bool ok = msk[nt * 16 + fr] != 0;
#pragma unroll
      for (int i = 0; i < 4; ++i) {
        float sv = ok ? sa[nt][i] * 0.125f : -1e30f;
        sa[nt][i] = sv;
        pm[i] = fmaxf(pm[i], sv);
      }
    }
#pragma unroll
    for (int d = 1; d < 16; d <<= 1)
#pragma unroll
      for (int i = 0; i < 4; ++i) pm[i] = fmaxf(pm[i], __shfl_xor(pm[i], d));
    float alpha[4], rs[4] = {0.f, 0.f, 0.f, 0.f};
#pragma unroll
    for (int i = 0; i < 4; ++i) {
      float mn = fmaxf(mrow[i], pm[i]);
      alpha[i] = __expf(mrow[i] - mn);
      mrow[i] = mn;
    }
#pragma unroll
    for (int nt = 0; nt < 4; ++nt)
#pragma unroll
      for (int i = 0; i < 4; ++i) {
        float p = __expf(sa[nt][i] - mrow[i]);
        rs[i] += p;
        Psh[w][fq * 4 + i][nt * 16 + fr] = f2bf(p);
      }
#pragma unroll
    for (int d = 1; d < 16; d <<= 1)
#pragma unroll
      for (int i = 0; i < 4; ++i) rs[i] += __shfl_xor(rs[i], d);
#pragma unroll
    for (int i = 0; i < 4; ++i) lrow[i] = lrow[i] * alpha[i] + rs[i];
#pragma unroll
    for (int nt = 0; nt < 4; ++nt)
#pragma unroll
      for (int i = 0; i < 4; ++i) oacc[nt][i] *= alpha[i];

    bf16x8 pa0 = *(const bf16x8*)(&Psh[w][fr][fq * 8]);
    bf16x8 pa1 = *(const bf16x8*)(&Psh[w][fr][32 + fq * 8]);
#pragma unroll
    for (int nt = 0; nt < 4; ++nt) {
      bf16x8 v0 = *(const bf16x8*)(&Vsh[nt * 16 + fr][fq * 8]);
      bf16x8 v1 = *(const bf16x8*)(&Vsh[nt * 16 + fr][32 + fq * 8]);
      oacc[nt] = __builtin_amdgcn_mfma_f32_16x16x32_bf16(pa0, v0, oacc[nt], 0, 0, 0);
      oacc[nt] = __builtin_amdgcn_mfma_f32_16x16x32_bf16(pa1, v1, oacc[nt], 0, 0, 0);
    }
    __syncthreads();
  }

#pragma unroll
  for (int nt = 0; nt < 4; ++nt)
#pragma unroll
    for (int i = 0; i < 4; ++i) {
      int q = q0 + w * 16 + fq * 4 + i;
      int d = nt * 16 + fr;
      out[((size_t)b * NQ + q) * H + h * HD + d] = f2bf(oacc[nt][i] / lrow[i]);
    }
}

// ---------------------------------------------------------------------------
extern "C" void kernel_launch(void* const* d_in, const int* in_sizes, int n_in,
                              void* d_out, int out_size, void* d_ws, size_t ws_size,
                              hipStream_t stream) {
  const float* queries = (const float*)d_in[0];
  const float* keys_values = (const float*)d_in[1];
  const void* amask = d_in[2];
  const float* W_qkv = (const float*)d_in[3];
  const float* b_qkv = (const float*)d_in[4];
  const float* W_out = (const float*)d_in[5];
  const float* b_out = (const float*)d_in[6];
  const float* gamma = (const float*)d_in[7];
  const float* beta = (const float*)d_in[8];

  char* ws = (char*)d_ws;
  unsigned char* maskN = (unsigned char*)ws;                 // 8 KB
  u16* Xq = (u16*)(ws + 8192);                               // [2048][1024]
  u16* Xkv = Xq + (size_t)Bb * NQ * H;                       // [8192][1024]
  u16* Wtq = Xkv + (size_t)Bb * S * H;                       // [3072][1024]
  u16* Wto = Wtq + (size_t)3 * H * H;                        // [1024][1024]
  u16* Qbuf = Wto + (size_t)H * H;                           // [B][NH][NQ][HD]
  u16* Kbuf = Qbuf + (size_t)Bb * NQ * H;                    // [B][NH][S][HD]
  u16* Vbuf = Kbuf + (size_t)Bb * S * H;                     // [B][NH][S][HD]
  u16* Aout = Vbuf + (size_t)Bb * S * H;                     // [2048][1024]

  hipLaunchKernelGGL(mask_norm_kernel, dim3(1), dim3(256), 0, stream,
                     (const unsigned char*)amask, maskN);
  hipLaunchKernelGGL(ln_cast_kernel, dim3(Bb * NQ / 4), dim3(256), 0, stream,
                     queries, gamma, beta, Xq, Bb * NQ);
  hipLaunchKernelGGL(ln_cast_kernel, dim3(Bb * S / 4), dim3(256), 0, stream,
                     keys_values, gamma, beta, Xkv, Bb * S);
  hipLaunchKernelGGL(transpose_cast_kernel, dim3(3 * H / 32, H / 32), dim3(256), 0, stream,
                     W_qkv, Wtq, H, 3 * H);
  hipLaunchKernelGGL(transpose_cast_kernel, dim3(H / 32, H / 32), dim3(256), 0, stream,
                     W_out, Wto, H, H);
  hipLaunchKernelGGL(gemm_bt_kernel<0>, dim3(H / 128, Bb * NQ / 128), dim3(256), 0, stream,
                     Xq, Wtq, b_qkv, (void*)Qbuf);
  hipLaunchKernelGGL(gemm_bt_kernel<1>, dim3(2 * H / 128, Bb * S / 128), dim3(256), 0, stream,
                     Xkv, Wtq + (size_t)H * H, b_qkv + H, (void*)Kbuf);
  hipLaunchKernelGGL(attn_kernel, dim3(NQ / 64, Bb * NH), dim3(256), 0, stream,
                     Qbuf, Kbuf, Vbuf, maskN, Aout);
  hipLaunchKernelGGL(gemm_bt_kernel<2>, dim3(H / 128, Bb * NQ / 128), dim3(256), 0, stream,
                     Aout, Wto, b_out, d_out);
}

// Round 2
// 272.544 us; speedup vs baseline: 1.1490x; 1.1490x over previous
//
#include <hip/hip_runtime.h>
#include <stdint.h>

#define DEVI __device__ __forceinline__

constexpr int Bb = 2, NQ = 1024, S = 4096, H = 1024, NH = 16, HD = 64;

typedef __bf16 bf16x8 __attribute__((ext_vector_type(8)));
typedef float f32x4 __attribute__((ext_vector_type(4)));
typedef unsigned short u16;
typedef u16 u16x8 __attribute__((ext_vector_type(8)));

DEVI u16 f2bf(float f) {
  union { float f; unsigned u; } v; v.f = f;
  unsigned r = (v.u + 0x7fffu + ((v.u >> 16) & 1u)) >> 16;
  return (u16)r;
}

DEVI void gload_lds16(const void* g, void* lds) {
  __builtin_amdgcn_global_load_lds(
      (const __attribute__((address_space(1))) void*)(uintptr_t)g,
      (__attribute__((address_space(3))) void*)(uint32_t)(uintptr_t)lds,
      16, 0, 0);
}

// ---------------- mask normalize: detect bool(1B) vs int32(4B), emit u8 ----
__global__ void mask_norm_kernel(const unsigned char* __restrict__ m,
                                 unsigned char* __restrict__ out) {
  __shared__ int isByte;
  if (threadIdx.x == 0) isByte = 0;
  __syncthreads();
  int any = 0;
  for (int p = threadIdx.x; p < Bb * S; p += 256)
    if ((p & 3) && m[p]) any = 1;
  if (any) atomicOr(&isByte, 1);
  __syncthreads();
  const int bytemode = isByte;
  for (int i = threadIdx.x; i < Bb * S; i += 256) {
    unsigned char v = bytemode ? (unsigned char)(m[i] != 0)
                               : (unsigned char)(((const int*)m)[i] != 0);
    out[i] = v;
  }
}

// ---------------- LayerNorm (f32 in) + cast bf16, one wave per row ---------
__global__ __launch_bounds__(256) void ln_cast_kernel(
    const float* __restrict__ x, const float* __restrict__ gamma,
    const float* __restrict__ beta, u16* __restrict__ out, int nrows) {
  int row = blockIdx.x * 4 + (threadIdx.x >> 6);
  int lane = threadIdx.x & 63;
  if (row >= nrows) return;
  const float4* xr = (const float4*)(x + (size_t)row * H);
  float4 v[4];
  float s = 0.f, s2 = 0.f;
#pragma unroll
  for (int i = 0; i < 4; ++i) {
    v[i] = xr[lane + i * 64];
    s += v[i].x + v[i].y + v[i].z + v[i].w;
    s2 += v[i].x * v[i].x + v[i].y * v[i].y + v[i].z * v[i].z + v[i].w * v[i].w;
  }
#pragma unroll
  for (int d = 1; d < 64; d <<= 1) { s += __shfl_xor(s, d); s2 += __shfl_xor(s2, d); }
  float mu = s * (1.f / H);
  float rstd = rsqrtf(s2 * (1.f / H) - mu * mu + 1e-6f);
  u16* orow = out + (size_t)row * H;
  const float4* g4 = (const float4*)gamma;
  const float4* b4 = (const float4*)beta;
#pragma unroll
  for (int i = 0; i < 4; ++i) {
    float4 g = g4[lane + i * 64], bb = b4[lane + i * 64];
    ushort4 o;
    o.x = f2bf((v[i].x - mu) * rstd * g.x + bb.x);
    o.y = f2bf((v[i].y - mu) * rstd * g.y + bb.y);
    o.z = f2bf((v[i].z - mu) * rstd * g.z + bb.z);
    o.w = f2bf((v[i].w - mu) * rstd * g.w + bb.w);
    *(ushort4*)(orow + (size_t)(lane + i * 64) * 4) = o;
  }
}

// ---------------- transpose f32 [R][C] -> bf16 [C][R] ----------------------
__global__ __launch_bounds__(256) void transpose_cast_kernel(
    const float* __restrict__ in, u16* __restrict__ out, int R, int C) {
  __shared__ float tile[32][33];
  int c0 = blockIdx.x * 32, r0 = blockIdx.y * 32;
  int tx = threadIdx.x & 31, ty = threadIdx.x >> 5;
#pragma unroll
  for (int i = 0; i < 32; i += 8)
    tile[ty + i][tx] = in[(size_t)(r0 + ty + i) * C + c0 + tx];
  __syncthreads();
#pragma unroll
  for (int i = 0; i < 32; i += 8)
    out[(size_t)(c0 + ty + i) * R + r0 + tx] = f2bf(tile[tx][ty + i]);
}

// ---------------- 128x128 bf16 GEMM, C = A[M,K] * Bt[N,K]^T + bias ---------
// EPI 0: -> Q buf [B][NH][NQ][HD] bf16      (A rows = b*NQ+nq, c = h*64+d)
// EPI 1: -> K buf [B][NH][S][HD] bf16       (N = 1024, c = h*64+d)
// EPI 2: -> f32 out [M][1024]
// EPI 3: -> V^T buf [B][NH][HD][S] bf16     (packed ushort4 along S)
template <int EPI>
__global__ __launch_bounds__(256) void gemm_bt_kernel(
    const u16* __restrict__ A, const u16* __restrict__ Bt,
    const float* __restrict__ bias, void* __restrict__ outp) {
  constexpr int K = 1024, BK = 32;
  __shared__ __align__(16) u16 Ash[128 * BK];
  __shared__ __align__(16) u16 Bsh[128 * BK];
  const int tid = threadIdx.x, w = tid >> 6, lane = tid & 63;
  const int brow = blockIdx.y * 128, bcol = blockIdx.x * 128;
  const u16* Ag = A + (size_t)brow * K;
  const u16* Bg = Bt + (size_t)bcol * K;
  const int c0 = tid, c1 = tid + 256;
  const int wr = (w >> 1) * 64, wc = (w & 1) * 64;
  const int fr = lane & 15, fq = lane >> 4;
  f32x4 acc[4][4] = {};

  for (int k0 = 0; k0 < K; k0 += BK) {
    gload_lds16(Ag + (size_t)(c0 >> 2) * K + k0 + (c0 & 3) * 8, Ash + c0 * 8);
    gload_lds16(Ag + (size_t)(c1 >> 2) * K + k0 + (c1 & 3) * 8, Ash + c1 * 8);
    gload_lds16(Bg + (size_t)(c0 >> 2) * K + k0 + (c0 & 3) * 8, Bsh + c0 * 8);
    gload_lds16(Bg + (size_t)(c1 >> 2) * K + k0 + (c1 & 3) * 8, Bsh + c1 * 8);
    asm volatile("s_waitcnt vmcnt(0)" ::: "memory");
    __syncthreads();
    bf16x8 af[4], bfr[4];
#pragma unroll
    for (int m = 0; m < 4; ++m)
      af[m] = *(const bf16x8*)(Ash + (wr + m * 16 + fr) * BK + fq * 8);
#pragma unroll
    for (int n = 0; n < 4; ++n)
      bfr[n] = *(const bf16x8*)(Bsh + (wc + n * 16 + fr) * BK + fq * 8);
#pragma unroll
    for (int m = 0; m < 4; ++m)
#pragma unroll
      for (int n = 0; n < 4; ++n)
        acc[m][n] = __builtin_amdgcn_mfma_f32_16x16x32_bf16(af[m], bfr[n], acc[m][n], 0, 0, 0);
    __syncthreads();
  }

#pragma unroll
  for (int m = 0; m < 4; ++m)
#pragma unroll
    for (int n = 0; n < 4; ++n) {
      if constexpr (EPI == 3) {
        // V^T [B][NH][HD][S]: r -> (b, kv), c -> (head, d); i=0..3 consecutive kv
        int r0 = brow + wr + m * 16 + fq * 4;
        int c = bcol + wc + n * 16 + fr;
        int b = r0 >> 12, kv = r0 & (S - 1);
        int head = c >> 6, d = c & 63;
        ushort4 o;
        o.x = f2bf(acc[m][n][0] + bias[c]);
        o.y = f2bf(acc[m][n][1] + bias[c]);
        o.z = f2bf(acc[m][n][2] + bias[c]);
        o.w = f2bf(acc[m][n][3] + bias[c]);
        u16* vb = (u16*)outp;
        *(ushort4*)(vb + (((size_t)(b * NH + head)) * HD + d) * S + kv) = o;
      } else {
#pragma unroll
        for (int i = 0; i < 4; ++i) {
          int r = brow + wr + m * 16 + fq * 4 + i;
          int c = bcol + wc + n * 16 + fr;
          float val = acc[m][n][i] + bias[c];
          if constexpr (EPI == 0) {
            u16* qb = (u16*)outp;
            qb[((((size_t)(r >> 10)) * NH + (c >> 6)) * NQ + (r & (NQ - 1))) * HD + (c & 63)] = f2bf(val);
          } else if constexpr (EPI == 1) {
            u16* kb = (u16*)outp;
            kb[((((size_t)(r >> 12)) * NH + (c >> 6)) * S + (r & (S - 1))) * HD + (c & 63)] = f2bf(val);
          } else {
            float* ob = (float*)outp;
            ob[(size_t)r * H + c] = val;
          }
        }
      }
    }
}

// ---------------- flash attention: 4 waves, QBLK=64 (16 rows/wave), KVBLK=64
// K staged [kv][64ch] and V^T staged [d][64kv], both XOR-swizzled (chunk^(row&7)),
// via global_load_lds (linear dest + pre-swizzled source), double-buffered.
__global__ __launch_bounds__(256) void attn_kernel(
    const u16* __restrict__ Qb, const u16* __restrict__ Kb,
    const u16* __restrict__ Vt, const unsigned char* __restrict__ mask,
    u16* __restrict__ out) {
  __shared__ __align__(16) u16 Ktile[2][64 * 64];
  __shared__ __align__(16) u16 Vtile[2][64 * 64];
  __shared__ __align__(16) u16 Psh[4][16][72];
  __shared__ unsigned char msk[2][64];
  const int q0 = blockIdx.x * 64;
  const int bh = blockIdx.y, b = bh >> 4;
  const int tid = threadIdx.x, w = tid >> 6, lane = tid & 63;
  const int fr = lane & 15, fq = lane >> 4, fr7 = fr & 7;
  const u16* Qg = Qb + ((size_t)bh * NQ + q0 + w * 16) * HD;
  const u16* Kg = Kb + (size_t)bh * S * HD;
  const u16* Vg = Vt + (size_t)bh * HD * S;
  const unsigned char* mg = mask + (size_t)b * S;

  const int c0 = tid, c1 = tid + 256;
  const int r0s = c0 >> 3, g0s = (c0 & 7) ^ (r0s & 7);
  const int r1s = c1 >> 3, g1s = (c1 & 7) ^ (r1s & 7);

  bf16x8 qf0 = *(const bf16x8*)(Qg + fr * HD + fq * 8);
  bf16x8 qf1 = *(const bf16x8*)(Qg + fr * HD + 32 + fq * 8);

  f32x4 oacc[4] = {};
  float mrow[4] = {-1e30f, -1e30f, -1e30f, -1e30f};
  float lrow[4] = {0.f, 0.f, 0.f, 0.f};

  // prologue: stage tile 0 into buffer 0
  if (tid < 64) msk[0][tid] = mg[tid];
  gload_lds16(Kg + (size_t)r0s * HD + g0s * 8, &Ktile[0][c0 * 8]);
  gload_lds16(Kg + (size_t)r1s * HD + g1s * 8, &Ktile[0][c1 * 8]);
  gload_lds16(Vg + (size_t)r0s * S + g0s * 8, &Vtile[0][c0 * 8]);
  gload_lds16(Vg + (size_t)r1s * S + g1s * 8, &Vtile[0][c1 * 8]);
  asm volatile("s_waitcnt vmcnt(0)" ::: "memory");
  __syncthreads();

  int cur = 0;
  for (int kt = 0; kt < S; kt += 64) {
    const int nb = cur ^ 1, kn = kt + 64;
    unsigned char mv = 0;
    if (kn < S) {
      if (tid < 64) mv = mg[kn + tid];  // issued first: later vmcnt waits don't stall gloads
      gload_lds16(Kg + (size_t)(kn + r0s) * HD + g0s * 8, &Ktile[nb][c0 * 8]);
      gload_lds16(Kg + (size_t)(kn + r1s) * HD + g1s * 8, &Ktile[nb][c1 * 8]);
      gload_lds16(Vg + (size_t)r0s * S + kn + g0s * 8, &Vtile[nb][c0 * 8]);
      gload_lds16(Vg + (size_t)r1s * S + kn + g1s * 8, &Vtile[nb][c1 * 8]);
    }

    const u16* Kc = &Ktile[cur][0];
    const u16* Vc = &Vtile[cur][0];

    // S = Q K^T  (rows = q, cols = kv), swizzled B-frag reads
    f32x4 sa[4];
#pragma unroll
    for (int nt = 0; nt < 4; ++nt) {
      const u16* kb2 = Kc + (nt * 16 + fr) * 64;
      bf16x8 k0v = *(const bf16x8*)(kb2 + ((fq) ^ fr7) * 8);
      bf16x8 k1v = *(const bf16x8*)(kb2 + ((4 + fq) ^ fr7) * 8);
      f32x4 t = {};
      t = __builtin_amdgcn_mfma_f32_16x16x32_bf16(qf0, k0v, t, 0, 0, 0);
      t = __builtin_amdgcn_mfma_f32_16x16x32_bf16(qf1, k1v, t, 0, 0, 0);
      sa[nt] = t;
    }
    float pm[4] = {-1e30f, -1e30f, -1e30f, -1e30f};
#pragma unroll
    for (int nt = 0; nt < 4; ++nt) {
      bool ok = msk[cur][nt * 16 + fr] != 0;
#pragma unroll
      for (int i = 0; i < 4; ++i) {
        float sv = ok ? sa[nt][i] * 0.125f : -1e30f;
        sa[nt][i] = sv;
        pm[i] = fmaxf(pm[i], sv);
      }
    }
#pragma unroll
    for (int d = 1; d < 16; d <<= 1)
#pragma unroll
      for (int i = 0; i < 4; ++i) pm[i] = fmaxf(pm[i], __shfl_xor(pm[i], d));
    float alpha[4], rs[4] = {0.f, 0.f, 0.f, 0.f};
#pragma unroll
    for (int i = 0; i < 4; ++i) {
      float mn = fmaxf(mrow[i], pm[i]);
      alpha[i] = __expf(mrow[i] - mn);
      mrow[i] = mn;
    }
#pragma unroll
    for (int nt = 0; nt < 4; ++nt)
#pragma unroll
      for (int i = 0; i < 4; ++i) {
        float p = __expf(sa[nt][i] - mrow[i]);
        rs[i] += p;
        Psh[w][fq * 4 + i][nt * 16 + fr] = f2bf(p);
      }
#pragma unroll
    for (int d = 1; d < 16; d <<= 1)
#pragma unroll
      for (int i = 0; i < 4; ++i) rs[i] += __shfl_xor(rs[i], d);
#pragma unroll
    for (int i = 0; i < 4; ++i) lrow[i] = lrow[i] * alpha[i] + rs[i];
#pragma unroll
    for (int nt = 0; nt < 4; ++nt)
#pragma unroll
      for (int i = 0; i < 4; ++i) oacc[nt][i] *= alpha[i];

    bf16x8 pa0 = *(const bf16x8*)(&Psh[w][fr][fq * 8]);
    bf16x8 pa1 = *(const bf16x8*)(&Psh[w][fr][32 + fq * 8]);
#pragma unroll
    for (int nt = 0; nt < 4; ++nt) {
      const u16* vb2 = Vc + (nt * 16 + fr) * 64;
      bf16x8 v0 = *(const bf16x8*)(vb2 + ((fq) ^ fr7) * 8);
      bf16x8 v1 = *(const bf16x8*)(vb2 + ((4 + fq) ^ fr7) * 8);
      oacc[nt] = __builtin_amdgcn_mfma_f32_16x16x32_bf16(pa0, v0, oacc[nt], 0, 0, 0);
      oacc[nt] = __builtin_amdgcn_mfma_f32_16x16x32_bf16(pa1, v1, oacc[nt], 0, 0, 0);
    }

    if (kn < S && tid < 64) msk[nb][tid] = mv;
    asm volatile("s_waitcnt vmcnt(0)" ::: "memory");
    __syncthreads();
    cur = nb;
  }

  const int h = bh & 15;
#pragma unroll
  for (int nt = 0; nt < 4; ++nt)
#pragma unroll
    for (int i = 0; i < 4; ++i) {
      int q = q0 + w * 16 + fq * 4 + i;
      int d = nt * 16 + fr;
      out[((size_t)b * NQ + q) * H + h * HD + d] = f2bf(oacc[nt][i] / lrow[i]);
    }
}

// ---------------------------------------------------------------------------
extern "C" void kernel_launch(void* const* d_in, const int* in_sizes, int n_in,
                              void* d_out, int out_size, void* d_ws, size_t ws_size,
                              hipStream_t stream) {
  const float* queries = (const float*)d_in[0];
  const float* keys_values = (const float*)d_in[1];
  const void* amask = d_in[2];
  const float* W_qkv = (const float*)d_in[3];
  const float* b_qkv = (const float*)d_in[4];
  const float* W_out = (const float*)d_in[5];
  const float* b_out = (const float*)d_in[6];
  const float* gamma = (const float*)d_in[7];
  const float* beta = (const float*)d_in[8];

  char* ws = (char*)d_ws;
  unsigned char* maskN = (unsigned char*)ws;                 // 8 KB
  u16* Xq = (u16*)(ws + 8192);                               // [2048][1024]
  u16* Xkv = Xq + (size_t)Bb * NQ * H;                       // [8192][1024]
  u16* Wtq = Xkv + (size_t)Bb * S * H;                       // [3072][1024]
  u16* Wto = Wtq + (size_t)3 * H * H;                        // [1024][1024]
  u16* Qbuf = Wto + (size_t)H * H;                           // [B][NH][NQ][HD]
  u16* Kbuf = Qbuf + (size_t)Bb * NQ * H;                    // [B][NH][S][HD]
  u16* Vbuf = Kbuf + (size_t)Bb * S * H;                     // [B][NH][HD][S] (transposed)
  u16* Aout = Vbuf + (size_t)Bb * S * H;                     // [2048][1024]

  hipLaunchKernelGGL(mask_norm_kernel, dim3(1), dim3(256), 0, stream,
                     (const unsigned char*)amask, maskN);
  hipLaunchKernelGGL(ln_cast_kernel, dim3(Bb * NQ / 4), dim3(256), 0, stream,
                     queries, gamma, beta, Xq, Bb * NQ);
  hipLaunchKernelGGL(ln_cast_kernel, dim3(Bb * S / 4), dim3(256), 0, stream,
                     keys_values, gamma, beta, Xkv, Bb * S);
  hipLaunchKernelGGL(transpose_cast_kernel, dim3(3 * H / 32, H / 32), dim3(256), 0, stream,
                     W_qkv, Wtq, H, 3 * H);
  hipLaunchKernelGGL(transpose_cast_kernel, dim3(H / 32, H / 32), dim3(256), 0, stream,
                     W_out, Wto, H, H);
  hipLaunchKernelGGL(gemm_bt_kernel<0>, dim3(H / 128, Bb * NQ / 128), dim3(256), 0, stream,
                     Xq, Wtq, b_qkv, (void*)Qbuf);
  hipLaunchKernelGGL(gemm_bt_kernel<1>, dim3(H / 128, Bb * S / 128), dim3(256), 0, stream,
                     Xkv, Wtq + (size_t)H * H, b_qkv + H, (void*)Kbuf);
  hipLaunchKernelGGL(gemm_bt_kernel<3>, dim3(H / 128, Bb * S / 128), dim3(256), 0, stream,
                     Xkv, Wtq + (size_t)2 * H * H, b_qkv + 2 * H, (void*)Vbuf);
  hipLaunchKernelGGL(attn_kernel, dim3(NQ / 64, Bb * NH), dim3(256), 0, stream,
                     Qbuf, Kbuf, Vbuf, maskN, Aout);
  hipLaunchKernelGGL(gemm_bt_kernel<2>, dim3(H / 128, Bb * NQ / 128), dim3(256), 0, stream,
                     Aout, Wto, b_out, d_out);
}

// Round 3
// 239.459 us; speedup vs baseline: 1.3078x; 1.1382x over previous
//
#include <hip/hip_runtime.h>
#include <stdint.h>

#define DEVI __device__ __forceinline__

constexpr int Bb = 2, NQ = 1024, S = 4096, H = 1024, NH = 16, HD = 64;

typedef __bf16 bf16x8 __attribute__((ext_vector_type(8)));
typedef float f32x4 __attribute__((ext_vector_type(4)));
typedef int i32x4 __attribute__((ext_vector_type(4)));
typedef unsigned short u16;
typedef u16 u16x8 __attribute__((ext_vector_type(8)));

DEVI u16 f2bf(float f) {
  union { float f; unsigned u; } v; v.f = f;
  unsigned r = (v.u + 0x7fffu + ((v.u >> 16) & 1u)) >> 16;
  return (u16)r;
}

DEVI float fexp2(float x) {
#if __has_builtin(__builtin_amdgcn_exp2f)
  return __builtin_amdgcn_exp2f(x);
#else
  return exp2f(x);
#endif
}

DEVI void gload_lds16(const void* g, void* lds) {
  __builtin_amdgcn_global_load_lds(
      (const __attribute__((address_space(1))) void*)(uintptr_t)g,
      (__attribute__((address_space(3))) void*)(uint32_t)(uintptr_t)lds,
      16, 0, 0);
}

// ---------------- mask normalize: detect bool(1B) vs int32(4B), emit u8 ----
__global__ void mask_norm_kernel(const unsigned char* __restrict__ m,
                                 unsigned char* __restrict__ out) {
  __shared__ int isByte;
  if (threadIdx.x == 0) isByte = 0;
  __syncthreads();
  int any = 0;
  for (int p = threadIdx.x; p < Bb * S; p += 256)
    if ((p & 3) && m[p]) any = 1;
  if (any) atomicOr(&isByte, 1);
  __syncthreads();
  const int bytemode = isByte;
  for (int i = threadIdx.x; i < Bb * S; i += 256) {
    unsigned char v = bytemode ? (unsigned char)(m[i] != 0)
                               : (unsigned char)(((const int*)m)[i] != 0);
    out[i] = v;
  }
}

// ---------------- LayerNorm (f32 in) + cast bf16, one wave per row ---------
__global__ __launch_bounds__(256) void ln_cast_kernel(
    const float* __restrict__ x, const float* __restrict__ gamma,
    const float* __restrict__ beta, u16* __restrict__ out, int nrows) {
  int row = blockIdx.x * 4 + (threadIdx.x >> 6);
  int lane = threadIdx.x & 63;
  if (row >= nrows) return;
  const float4* xr = (const float4*)(x + (size_t)row * H);
  float4 v[4];
  float s = 0.f, s2 = 0.f;
#pragma unroll
  for (int i = 0; i < 4; ++i) {
    v[i] = xr[lane + i * 64];
    s += v[i].x + v[i].y + v[i].z + v[i].w;
    s2 += v[i].x * v[i].x + v[i].y * v[i].y + v[i].z * v[i].z + v[i].w * v[i].w;
  }
#pragma unroll
  for (int d = 1; d < 64; d <<= 1) { s += __shfl_xor(s, d); s2 += __shfl_xor(s2, d); }
  float mu = s * (1.f / H);
  float rstd = rsqrtf(s2 * (1.f / H) - mu * mu + 1e-6f);
  u16* orow = out + (size_t)row * H;
  const float4* g4 = (const float4*)gamma;
  const float4* b4 = (const float4*)beta;
#pragma unroll
  for (int i = 0; i < 4; ++i) {
    float4 g = g4[lane + i * 64], bb = b4[lane + i * 64];
    ushort4 o;
    o.x = f2bf((v[i].x - mu) * rstd * g.x + bb.x);
    o.y = f2bf((v[i].y - mu) * rstd * g.y + bb.y);
    o.z = f2bf((v[i].z - mu) * rstd * g.z + bb.z);
    o.w = f2bf((v[i].w - mu) * rstd * g.w + bb.w);
    *(ushort4*)(orow + (size_t)(lane + i * 64) * 4) = o;
  }
}

// ---------------- transpose f32 [R][C] -> bf16 [C][R] ----------------------
__global__ __launch_bounds__(256) void transpose_cast_kernel(
    const float* __restrict__ in, u16* __restrict__ out, int R, int C) {
  __shared__ float tile[32][33];
  int c0 = blockIdx.x * 32, r0 = blockIdx.y * 32;
  int tx = threadIdx.x & 31, ty = threadIdx.x >> 5;
#pragma unroll
  for (int i = 0; i < 32; i += 8)
    tile[ty + i][tx] = in[(size_t)(r0 + ty + i) * C + c0 + tx];
  __syncthreads();
#pragma unroll
  for (int i = 0; i < 32; i += 8)
    out[(size_t)(c0 + ty + i) * R + r0 + tx] = f2bf(tile[tx][ty + i]);
}

// ---------------- 128x128 bf16 GEMM, C = A[M,K] * Bt[N,K]^T + bias ---------
// EPI 0: -> Q buf [B][NH][NQ][HD] bf16, pre-scaled by 0.125*log2(e)
// EPI 1: -> K buf [B][NH][S][HD] bf16
// EPI 2: -> f32 out [M][1024]
// EPI 3: -> V^T buf [B][NH][HD][S] bf16 (packed ushort4 along S)
template <int EPI>
__global__ __launch_bounds__(256) void gemm_bt_kernel(
    const u16* __restrict__ A, const u16* __restrict__ Bt,
    const float* __restrict__ bias, void* __restrict__ outp) {
  constexpr int K = 1024, BK = 32;
  __shared__ __align__(16) u16 Ash[128 * BK];
  __shared__ __align__(16) u16 Bsh[128 * BK];
  const int tid = threadIdx.x, w = tid >> 6, lane = tid & 63;
  const int brow = blockIdx.y * 128, bcol = blockIdx.x * 128;
  const u16* Ag = A + (size_t)brow * K;
  const u16* Bg = Bt + (size_t)bcol * K;
  const int c0 = tid, c1 = tid + 256;
  const int wr = (w >> 1) * 64, wc = (w & 1) * 64;
  const int fr = lane & 15, fq = lane >> 4;
  f32x4 acc[4][4] = {};

  for (int k0 = 0; k0 < K; k0 += BK) {
    gload_lds16(Ag + (size_t)(c0 >> 2) * K + k0 + (c0 & 3) * 8, Ash + c0 * 8);
    gload_lds16(Ag + (size_t)(c1 >> 2) * K + k0 + (c1 & 3) * 8, Ash + c1 * 8);
    gload_lds16(Bg + (size_t)(c0 >> 2) * K + k0 + (c0 & 3) * 8, Bsh + c0 * 8);
    gload_lds16(Bg + (size_t)(c1 >> 2) * K + k0 + (c1 & 3) * 8, Bsh + c1 * 8);
    asm volatile("s_waitcnt vmcnt(0)" ::: "memory");
    __syncthreads();
    bf16x8 af[4], bfr[4];
#pragma unroll
    for (int m = 0; m < 4; ++m)
      af[m] = *(const bf16x8*)(Ash + (wr + m * 16 + fr) * BK + fq * 8);
#pragma unroll
    for (int n = 0; n < 4; ++n)
      bfr[n] = *(const bf16x8*)(Bsh + (wc + n * 16 + fr) * BK + fq * 8);
#pragma unroll
    for (int m = 0; m < 4; ++m)
#pragma unroll
      for (int n = 0; n < 4; ++n)
        acc[m][n] = __builtin_amdgcn_mfma_f32_16x16x32_bf16(af[m], bfr[n], acc[m][n], 0, 0, 0);
    __syncthreads();
  }

  constexpr float QSCALE = 0.125f * 1.4426950408889634f;  // fold 1/sqrt(HD) * log2(e)
#pragma unroll
  for (int m = 0; m < 4; ++m)
#pragma unroll
    for (int n = 0; n < 4; ++n) {
      if constexpr (EPI == 3) {
        int r0 = brow + wr + m * 16 + fq * 4;
        int c = bcol + wc + n * 16 + fr;
        int b = r0 >> 12, kv = r0 & (S - 1);
        int head = c >> 6, d = c & 63;
        ushort4 o;
        o.x = f2bf(acc[m][n][0] + bias[c]);
        o.y = f2bf(acc[m][n][1] + bias[c]);
        o.z = f2bf(acc[m][n][2] + bias[c]);
        o.w = f2bf(acc[m][n][3] + bias[c]);
        u16* vb = (u16*)outp;
        *(ushort4*)(vb + (((size_t)(b * NH + head)) * HD + d) * S + kv) = o;
      } else {
#pragma unroll
        for (int i = 0; i < 4; ++i) {
          int r = brow + wr + m * 16 + fq * 4 + i;
          int c = bcol + wc + n * 16 + fr;
          float val = acc[m][n][i] + bias[c];
          if constexpr (EPI == 0) {
            u16* qb = (u16*)outp;
            qb[((((size_t)(r >> 10)) * NH + (c >> 6)) * NQ + (r & (NQ - 1))) * HD + (c & 63)] =
                f2bf(val * QSCALE);
          } else if constexpr (EPI == 1) {
            u16* kb = (u16*)outp;
            kb[((((size_t)(r >> 12)) * NH + (c >> 6)) * S + (r & (S - 1))) * HD + (c & 63)] = f2bf(val);
          } else {
            float* ob = (float*)outp;
            ob[(size_t)r * H + c] = val;
          }
        }
      }
    }
}

// ---------------- flash attention, swapped-QK^T in-register softmax --------
// 4 waves, QBLK=64 (16 q/wave), KVBLK=64. K [kv][d] and V^T [d][kv] staged
// XOR-swizzled via global_load_lds, double-buffered. S^T = mfma(K,Q): each
// lane owns q=fr, 16 kv values in-register -> in-lane softmax, cvt_pk +
// ds_bpermute builds PV B-frags (no P LDS round-trip). O^T = mfma(V^T, P^T).
__global__ __launch_bounds__(256) void attn_kernel(
    const u16* __restrict__ Qb, const u16* __restrict__ Kb,
    const u16* __restrict__ Vt, const unsigned char* __restrict__ mask,
    u16* __restrict__ out) {
  __shared__ __align__(16) u16 Ktile[2][64 * 64];
  __shared__ __align__(16) u16 Vtile[2][64 * 64];
  __shared__ __align__(16) float Mb[2][64];
  const int q0 = blockIdx.x * 64;
  const int bh = blockIdx.y, b = bh >> 4;
  const int tid = threadIdx.x, w = tid >> 6, lane = tid & 63;
  const int fr = lane & 15, fq = lane >> 4, fr7 = fr & 7;
  const u16* Qg = Qb + ((size_t)bh * NQ + q0 + w * 16) * HD;
  const u16* Kg = Kb + (size_t)bh * S * HD;
  const u16* Vg = Vt + (size_t)bh * HD * S;
  const unsigned char* mg = mask + (size_t)b * S;

  const int c0 = tid, c1 = tid + 256;
  const int r0s = c0 >> 3, g0s = (c0 & 7) ^ (r0s & 7);
  const int r1s = c1 >> 3, g1s = (c1 & 7) ^ (r1s & 7);

  // Q as B-operand fragments (rows = q = fr, contraction chunks over d)
  bf16x8 qf0 = *(const bf16x8*)(Qg + fr * HD + fq * 8);
  bf16x8 qf1 = *(const bf16x8*)(Qg + fr * HD + 32 + fq * 8);

  // bpermute byte-addresses for P redistribution
  const int A0 = ((((fq << 1)) & 3) * 16 + fr) << 2;
  const int A1 = ((((fq << 1) + 1) & 3) * 16 + fr) << 2;
  const bool lofq = (fq < 2);

  f32x4 oacc[4] = {};           // O^T: [d = nt*16 + fq*4 + i][q = fr]
  float mrow = -1e30f, lrow = 0.f;  // per q-row (log2 domain)

  // prologue: stage tile 0
  if (tid < 64) Mb[0][tid] = mg[tid] ? 0.f : -1e30f;
  gload_lds16(Kg + (size_t)r0s * HD + g0s * 8, &Ktile[0][c0 * 8]);
  gload_lds16(Kg + (size_t)r1s * HD + g1s * 8, &Ktile[0][c1 * 8]);
  gload_lds16(Vg + (size_t)r0s * S + g0s * 8, &Vtile[0][c0 * 8]);
  gload_lds16(Vg + (size_t)r1s * S + g1s * 8, &Vtile[0][c1 * 8]);
  asm volatile("s_waitcnt vmcnt(0)" ::: "memory");
  __syncthreads();

  int cur = 0;
  for (int kt = 0; kt < S; kt += 64) {
    const int nb = cur ^ 1, kn = kt + 64;
    if (kn < S) {
      if (tid < 64) Mb[nb][tid] = mg[kn + tid] ? 0.f : -1e30f;
      gload_lds16(Kg + (size_t)(kn + r0s) * HD + g0s * 8, &Ktile[nb][c0 * 8]);
      gload_lds16(Kg + (size_t)(kn + r1s) * HD + g1s * 8, &Ktile[nb][c1 * 8]);
      gload_lds16(Vg + (size_t)r0s * S + kn + g0s * 8, &Vtile[nb][c0 * 8]);
      gload_lds16(Vg + (size_t)r1s * S + kn + g1s * 8, &Vtile[nb][c1 * 8]);
    }

    const u16* Kc = &Ktile[cur][0];
    const u16* Vc = &Vtile[cur][0];

    // S^T = K Q^T : sa[nt][i] = S[kv = nt*16 + fq*4 + i][q = fr] (log2 units)
    float sv[4][4];
#pragma unroll
    for (int nt = 0; nt < 4; ++nt) {
      const u16* kb2 = Kc + (nt * 16 + fr) * 64;
      bf16x8 k0v = *(const bf16x8*)(kb2 + ((fq) ^ fr7) * 8);
      bf16x8 k1v = *(const bf16x8*)(kb2 + ((4 + fq) ^ fr7) * 8);
      f32x4 t = {};
      t = __builtin_amdgcn_mfma_f32_16x16x32_bf16(k0v, qf0, t, 0, 0, 0);
      t = __builtin_amdgcn_mfma_f32_16x16x32_bf16(k1v, qf1, t, 0, 0, 0);
      float4 mb = *(const float4*)&Mb[cur][nt * 16 + fq * 4];
      sv[nt][0] = t[0] + mb.x;
      sv[nt][1] = t[1] + mb.y;
      sv[nt][2] = t[2] + mb.z;
      sv[nt][3] = t[3] + mb.w;
    }

    // in-lane max over 16 + cross-fq reduce (lanes ^16, ^32)
    float pmax;
    {
      float m0 = fmaxf(fmaxf(sv[0][0], sv[0][1]), fmaxf(sv[0][2], sv[0][3]));
      float m1 = fmaxf(fmaxf(sv[1][0], sv[1][1]), fmaxf(sv[1][2], sv[1][3]));
      float m2 = fmaxf(fmaxf(sv[2][0], sv[2][1]), fmaxf(sv[2][2], sv[2][3]));
      float m3 = fmaxf(fmaxf(sv[3][0], sv[3][1]), fmaxf(sv[3][2], sv[3][3]));
      pmax = fmaxf(fmaxf(m0, m1), fmaxf(m2, m3));
    }
    pmax = fmaxf(pmax, __shfl_xor(pmax, 16));
    pmax = fmaxf(pmax, __shfl_xor(pmax, 32));

    // defer-max (T13): rescale only when max grew past threshold (log2 units)
    if (__any(pmax > mrow + 12.f)) {
      float nm = fmaxf(mrow, pmax);
      float al = fexp2(mrow - nm);
      mrow = nm;
      lrow *= al;
#pragma unroll
      for (int nt = 0; nt < 4; ++nt)
#pragma unroll
        for (int i = 0; i < 4; ++i) oacc[nt][i] *= al;
    }

    // P = 2^(sv - mrow); in-lane sum + cross-fq reduce
    float p[4][4];
    float rsum;
    {
#pragma unroll
      for (int nt = 0; nt < 4; ++nt)
#pragma unroll
        for (int i = 0; i < 4; ++i) p[nt][i] = fexp2(sv[nt][i] - mrow);
      float s0 = (p[0][0] + p[0][1]) + (p[0][2] + p[0][3]);
      float s1 = (p[1][0] + p[1][1]) + (p[1][2] + p[1][3]);
      float s2 = (p[2][0] + p[2][1]) + (p[2][2] + p[2][3]);
      float s3 = (p[3][0] + p[3][1]) + (p[3][2] + p[3][3]);
      rsum = (s0 + s1) + (s2 + s3);
    }
    rsum += __shfl_xor(rsum, 16);
    rsum += __shfl_xor(rsum, 32);
    lrow += rsum;

    // pack P to bf16 pairs: pk[nt][j] = {kv even, kv odd}
    int pk[4][2];
#pragma unroll
    for (int nt = 0; nt < 4; ++nt) {
      asm("v_cvt_pk_bf16_f32 %0, %1, %2" : "=v"(pk[nt][0]) : "v"(p[nt][0]), "v"(p[nt][1]));
      asm("v_cvt_pk_bf16_f32 %0, %1, %2" : "=v"(pk[nt][1]) : "v"(p[nt][2]), "v"(p[nt][3]));
    }

    // redistribute to PV B-frags (rows q=fr, contraction kv chunks fq*8) and PV
#pragma unroll
    for (int b2 = 0; b2 < 2; ++b2) {
      int w0a = __builtin_amdgcn_ds_bpermute(A0, pk[2 * b2][0]);
      int w0b = __builtin_amdgcn_ds_bpermute(A0, pk[2 * b2 + 1][0]);
      int w1a = __builtin_amdgcn_ds_bpermute(A0, pk[2 * b2][1]);
      int w1b = __builtin_amdgcn_ds_bpermute(A0, pk[2 * b2 + 1][1]);
      int w2a = __builtin_amdgcn_ds_bpermute(A1, pk[2 * b2][0]);
      int w2b = __builtin_amdgcn_ds_bpermute(A1, pk[2 * b2 + 1][0]);
      int w3a = __builtin_amdgcn_ds_bpermute(A1, pk[2 * b2][1]);
      int w3b = __builtin_amdgcn_ds_bpermute(A1, pk[2 * b2 + 1][1]);
      i32x4 wv;
      wv[0] = lofq ? w0a : w0b;
      wv[1] = lofq ? w1a : w1b;
      wv[2] = lofq ? w2a : w2b;
      wv[3] = lofq ? w3a : w3b;
      bf16x8 pfrag = __builtin_bit_cast(bf16x8, wv);
#pragma unroll
      for (int nt = 0; nt < 4; ++nt) {
        const u16* vb2 = Vc + (nt * 16 + fr) * 64;
        bf16x8 vf = *(const bf16x8*)(vb2 + ((b2 * 4 + fq) ^ fr7) * 8);
        oacc[nt] = __builtin_amdgcn_mfma_f32_16x16x32_bf16(vf, pfrag, oacc[nt], 0, 0, 0);
      }
    }

    asm volatile("s_waitcnt vmcnt(0)" ::: "memory");
    __syncthreads();
    cur = nb;
  }

  const int h = bh & 15;
  const float inv = 1.f / lrow;
  const int q = q0 + w * 16 + fr;
  u16* orow = out + ((size_t)b * NQ + q) * H + h * HD;
#pragma unroll
  for (int nt = 0; nt < 4; ++nt) {
    ushort4 o;
    o.x = f2bf(oacc[nt][0] * inv);
    o.y = f2bf(oacc[nt][1] * inv);
    o.z = f2bf(oacc[nt][2] * inv);
    o.w = f2bf(oacc[nt][3] * inv);
    *(ushort4*)(orow + nt * 16 + fq * 4) = o;
  }
}

// ---------------------------------------------------------------------------
extern "C" void kernel_launch(void* const* d_in, const int* in_sizes, int n_in,
                              void* d_out, int out_size, void* d_ws, size_t ws_size,
                              hipStream_t stream) {
  const float* queries = (const float*)d_in[0];
  const float* keys_values = (const float*)d_in[1];
  const void* amask = d_in[2];
  const float* W_qkv = (const float*)d_in[3];
  const float* b_qkv = (const float*)d_in[4];
  const float* W_out = (const float*)d_in[5];
  const float* b_out = (const float*)d_in[6];
  const float* gamma = (const float*)d_in[7];
  const float* beta = (const float*)d_in[8];

  char* ws = (char*)d_ws;
  unsigned char* maskN = (unsigned char*)ws;                 // 8 KB
  u16* Xq = (u16*)(ws + 8192);                               // [2048][1024]
  u16* Xkv = Xq + (size_t)Bb * NQ * H;                       // [8192][1024]
  u16* Wtq = Xkv + (size_t)Bb * S * H;                       // [3072][1024]
  u16* Wto = Wtq + (size_t)3 * H * H;                        // [1024][1024]
  u16* Qbuf = Wto + (size_t)H * H;                           // [B][NH][NQ][HD]
  u16* Kbuf = Qbuf + (size_t)Bb * NQ * H;                    // [B][NH][S][HD]
  u16* Vbuf = Kbuf + (size_t)Bb * S * H;                     // [B][NH][HD][S] (transposed)
  u16* Aout = Vbuf + (size_t)Bb * S * H;                     // [2048][1024]

  hipLaunchKernelGGL(mask_norm_kernel, dim3(1), dim3(256), 0, stream,
                     (const unsigned char*)amask, maskN);
  hipLaunchKernelGGL(ln_cast_kernel, dim3(Bb * NQ / 4), dim3(256), 0, stream,
                     queries, gamma, beta, Xq, Bb * NQ);
  hipLaunchKernelGGL(ln_cast_kernel, dim3(Bb * S / 4), dim3(256), 0, stream,
                     keys_values, gamma, beta, Xkv, Bb * S);
  hipLaunchKernelGGL(transpose_cast_kernel, dim3(3 * H / 32, H / 32), dim3(256), 0, stream,
                     W_qkv, Wtq, H, 3 * H);
  hipLaunchKernelGGL(transpose_cast_kernel, dim3(H / 32, H / 32), dim3(256), 0, stream,
                     W_out, Wto, H, H);
  hipLaunchKernelGGL(gemm_bt_kernel<0>, dim3(H / 128, Bb * NQ / 128), dim3(256), 0, stream,
                     Xq, Wtq, b_qkv, (void*)Qbuf);
  hipLaunchKernelGGL(gemm_bt_kernel<1>, dim3(H / 128, Bb * S / 128), dim3(256), 0, stream,
                     Xkv, Wtq + (size_t)H * H, b_qkv + H, (void*)Kbuf);
  hipLaunchKernelGGL(gemm_bt_kernel<3>, dim3(H / 128, Bb * S / 128), dim3(256), 0, stream,
                     Xkv, Wtq + (size_t)2 * H * H, b_qkv + 2 * H, (void*)Vbuf);
  hipLaunchKernelGGL(attn_kernel, dim3(NQ / 64, Bb * NH), dim3(256), 0, stream,
                     Qbuf, Kbuf, Vbuf, maskN, Aout);
  hipLaunchKernelGGL(gemm_bt_kernel<2>, dim3(H / 128, Bb * NQ / 128), dim3(256), 0, stream,
                     Aout, Wto, b_out, d_out);
}

// Round 4
// 221.513 us; speedup vs baseline: 1.4137x; 1.0810x over previous
//
#include <hip/hip_runtime.h>
#include <stdint.h>

#define DEVI __device__ __forceinline__

constexpr int Bb = 2, NQ = 1024, S = 4096, H = 1024, NH = 16, HD = 64;
constexpr int NSPLIT = 2, SLEN = S / NSPLIT;

typedef __bf16 bf16x8 __attribute__((ext_vector_type(8)));
typedef float f32x4 __attribute__((ext_vector_type(4)));
typedef int i32x4 __attribute__((ext_vector_type(4)));
typedef unsigned short u16;
typedef u16 u16x8 __attribute__((ext_vector_type(8)));

DEVI u16 f2bf(float f) {
  union { float f; unsigned u; } v; v.f = f;
  unsigned r = (v.u + 0x7fffu + ((v.u >> 16) & 1u)) >> 16;
  return (u16)r;
}

DEVI float fexp2(float x) {
#if __has_builtin(__builtin_amdgcn_exp2f)
  return __builtin_amdgcn_exp2f(x);
#else
  return exp2f(x);
#endif
}

DEVI void gload_lds16(const void* g, void* lds) {
  __builtin_amdgcn_global_load_lds(
      (const __attribute__((address_space(1))) void*)(uintptr_t)g,
      (__attribute__((address_space(3))) void*)(uint32_t)(uintptr_t)lds,
      16, 0, 0);
}

// ---------------- mask normalize: detect bool(1B) vs int32(4B), emit u8 ----
__global__ void mask_norm_kernel(const unsigned char* __restrict__ m,
                                 unsigned char* __restrict__ out) {
  __shared__ int isByte;
  if (threadIdx.x == 0) isByte = 0;
  __syncthreads();
  int any = 0;
  for (int p = threadIdx.x; p < Bb * S; p += 256)
    if ((p & 3) && m[p]) any = 1;
  if (any) atomicOr(&isByte, 1);
  __syncthreads();
  const int bytemode = isByte;
  for (int i = threadIdx.x; i < Bb * S; i += 256) {
    unsigned char v = bytemode ? (unsigned char)(m[i] != 0)
                               : (unsigned char)(((const int*)m)[i] != 0);
    out[i] = v;
  }
}

// ---------------- LayerNorm (f32 in) + cast bf16, one wave per row ---------
__global__ __launch_bounds__(256) void ln_cast_kernel(
    const float* __restrict__ x, const float* __restrict__ gamma,
    const float* __restrict__ beta, u16* __restrict__ out, int nrows) {
  int row = blockIdx.x * 4 + (threadIdx.x >> 6);
  int lane = threadIdx.x & 63;
  if (row >= nrows) return;
  const float4* xr = (const float4*)(x + (size_t)row * H);
  float4 v[4];
  float s = 0.f, s2 = 0.f;
#pragma unroll
  for (int i = 0; i < 4; ++i) {
    v[i] = xr[lane + i * 64];
    s += v[i].x + v[i].y + v[i].z + v[i].w;
    s2 += v[i].x * v[i].x + v[i].y * v[i].y + v[i].z * v[i].z + v[i].w * v[i].w;
  }
#pragma unroll
  for (int d = 1; d < 64; d <<= 1) { s += __shfl_xor(s, d); s2 += __shfl_xor(s2, d); }
  float mu = s * (1.f / H);
  float rstd = rsqrtf(s2 * (1.f / H) - mu * mu + 1e-6f);
  u16* orow = out + (size_t)row * H;
  const float4* g4 = (const float4*)gamma;
  const float4* b4 = (const float4*)beta;
#pragma unroll
  for (int i = 0; i < 4; ++i) {
    float4 g = g4[lane + i * 64], bb = b4[lane + i * 64];
    ushort4 o;
    o.x = f2bf((v[i].x - mu) * rstd * g.x + bb.x);
    o.y = f2bf((v[i].y - mu) * rstd * g.y + bb.y);
    o.z = f2bf((v[i].z - mu) * rstd * g.z + bb.z);
    o.w = f2bf((v[i].w - mu) * rstd * g.w + bb.w);
    *(ushort4*)(orow + (size_t)(lane + i * 64) * 4) = o;
  }
}

// ---------------- transpose f32 [R][C] -> bf16 [C][R] ----------------------
__global__ __launch_bounds__(256) void transpose_cast_kernel(
    const float* __restrict__ in, u16* __restrict__ out, int R, int C) {
  __shared__ float tile[32][33];
  int c0 = blockIdx.x * 32, r0 = blockIdx.y * 32;
  int tx = threadIdx.x & 31, ty = threadIdx.x >> 5;
#pragma unroll
  for (int i = 0; i < 32; i += 8)
    tile[ty + i][tx] = in[(size_t)(r0 + ty + i) * C + c0 + tx];
  __syncthreads();
#pragma unroll
  for (int i = 0; i < 32; i += 8)
    out[(size_t)(c0 + ty + i) * R + r0 + tx] = f2bf(tile[tx][ty + i]);
}

// ---------------- 128x128 bf16 GEMM, C = A[M,K] * Bt[N,K]^T + bias ---------
// EPI 0: -> Q buf [B][NH][NQ][HD] bf16, pre-scaled by 0.125*log2(e)
// EPI 1: merged K|V: c<1024 -> K [B][NH][S][HD]; c>=1024 -> V^T [B][NH][HD][S]
// EPI 2: -> f32 out [M][1024]
template <int EPI>
__global__ __launch_bounds__(256) void gemm_bt_kernel(
    const u16* __restrict__ A, const u16* __restrict__ Bt,
    const float* __restrict__ bias, void* __restrict__ outp) {
  constexpr int K = 1024, BK = 32;
  __shared__ __align__(16) u16 Ash[128 * BK];
  __shared__ __align__(16) u16 Bsh[128 * BK];
  const int tid = threadIdx.x, w = tid >> 6, lane = tid & 63;
  const int brow = blockIdx.y * 128, bcol = blockIdx.x * 128;
  const u16* Ag = A + (size_t)brow * K;
  const u16* Bg = Bt + (size_t)bcol * K;
  const int c0 = tid, c1 = tid + 256;
  const int wr = (w >> 1) * 64, wc = (w & 1) * 64;
  const int fr = lane & 15, fq = lane >> 4;
  f32x4 acc[4][4] = {};

  for (int k0 = 0; k0 < K; k0 += BK) {
    gload_lds16(Ag + (size_t)(c0 >> 2) * K + k0 + (c0 & 3) * 8, Ash + c0 * 8);
    gload_lds16(Ag + (size_t)(c1 >> 2) * K + k0 + (c1 & 3) * 8, Ash + c1 * 8);
    gload_lds16(Bg + (size_t)(c0 >> 2) * K + k0 + (c0 & 3) * 8, Bsh + c0 * 8);
    gload_lds16(Bg + (size_t)(c1 >> 2) * K + k0 + (c1 & 3) * 8, Bsh + c1 * 8);
    asm volatile("s_waitcnt vmcnt(0)" ::: "memory");
    __syncthreads();
    bf16x8 af[4], bfr[4];
#pragma unroll
    for (int m = 0; m < 4; ++m)
      af[m] = *(const bf16x8*)(Ash + (wr + m * 16 + fr) * BK + fq * 8);
#pragma unroll
    for (int n = 0; n < 4; ++n)
      bfr[n] = *(const bf16x8*)(Bsh + (wc + n * 16 + fr) * BK + fq * 8);
#pragma unroll
    for (int m = 0; m < 4; ++m)
#pragma unroll
      for (int n = 0; n < 4; ++n)
        acc[m][n] = __builtin_amdgcn_mfma_f32_16x16x32_bf16(af[m], bfr[n], acc[m][n], 0, 0, 0);
    __syncthreads();
  }

  constexpr float QSCALE = 0.125f * 1.4426950408889634f;  // fold 1/sqrt(HD) * log2(e)
#pragma unroll
  for (int m = 0; m < 4; ++m)
#pragma unroll
    for (int n = 0; n < 4; ++n) {
      const int c = bcol + wc + n * 16 + fr;
      const int r0 = brow + wr + m * 16 + fq * 4;
      if constexpr (EPI == 1) {
        if (c >= 1024) {  // V^T path: pack 4 consecutive kv along S
          int b = r0 >> 12, kv = r0 & (S - 1);
          int cc = c - 1024, head = cc >> 6, d = cc & 63;
          ushort4 o;
          o.x = f2bf(acc[m][n][0] + bias[c]);
          o.y = f2bf(acc[m][n][1] + bias[c]);
          o.z = f2bf(acc[m][n][2] + bias[c]);
          o.w = f2bf(acc[m][n][3] + bias[c]);
          u16* vb = (u16*)outp + (size_t)Bb * NH * S * HD;
          *(ushort4*)(vb + (((size_t)(b * NH + head)) * HD + d) * S + kv) = o;
        } else {  // K path
          u16* kb = (u16*)outp;
#pragma unroll
          for (int i = 0; i < 4; ++i) {
            int r = r0 + i;
            kb[((((size_t)(r >> 12)) * NH + (c >> 6)) * S + (r & (S - 1))) * HD + (c & 63)] =
                f2bf(acc[m][n][i] + bias[c]);
          }
        }
      } else {
#pragma unroll
        for (int i = 0; i < 4; ++i) {
          int r = r0 + i;
          float val = acc[m][n][i] + bias[c];
          if constexpr (EPI == 0) {
            u16* qb = (u16*)outp;
            qb[((((size_t)(r >> 10)) * NH + (c >> 6)) * NQ + (r & (NQ - 1))) * HD + (c & 63)] =
                f2bf(val * QSCALE);
          } else {
            float* ob = (float*)outp;
            ob[(size_t)r * H + c] = val;
          }
        }
      }
    }
}

// ---------------- flash attention, 8 waves, QBLK=128, split-S --------------
// Swapped QK^T in-register softmax (lane owns q=fr). K [kv][d], V^T [d][kv]
// staged XOR-swizzled via global_load_lds, double-buffered. Partial O (f32,
// [q][d]) + (m,l) per row written per split; combine_kernel merges.
__global__ __launch_bounds__(512, 4) void attn_kernel(
    const u16* __restrict__ Qb, const u16* __restrict__ Kb,
    const u16* __restrict__ Vt, const unsigned char* __restrict__ mask,
    float* __restrict__ Opart, float2* __restrict__ ml) {
  __shared__ __align__(16) char smem[34816];  // stage: 2x8K K + 2x8K V + 512B mask; epi: 8x16x68 f32
  u16* Ktile = (u16*)smem;
  u16* Vtile = Ktile + 8192;
  float* Mb = (float*)(Vtile + 8192);
  const int q0 = blockIdx.x * 128;
  const int bh = blockIdx.y, b = bh >> 4;
  const int z = blockIdx.z, kv0 = z * SLEN;
  const int tid = threadIdx.x, w = tid >> 6, lane = tid & 63;
  const int fr = lane & 15, fq = lane >> 4, fr7 = fr & 7;
  const u16* Qg = Qb + ((size_t)bh * NQ + q0 + w * 16) * HD;
  const u16* Kg = Kb + (size_t)bh * S * HD;
  const u16* Vg = Vt + (size_t)bh * HD * S;
  const unsigned char* mg = mask + (size_t)b * S + kv0;

  const int rs = tid >> 3, gs = (tid & 7) ^ (rs & 7);

  // Q as B-operand fragments (rows = q = fr, contraction chunks over d)
  bf16x8 qf0 = *(const bf16x8*)(Qg + fr * HD + fq * 8);
  bf16x8 qf1 = *(const bf16x8*)(Qg + fr * HD + 32 + fq * 8);

  // bpermute byte-addresses for P redistribution
  const int A0 = ((((fq << 1)) & 3) * 16 + fr) << 2;
  const int A1 = ((((fq << 1) + 1) & 3) * 16 + fr) << 2;
  const bool lofq = (fq < 2);

  f32x4 oacc[4] = {};               // O^T: [d = nt*16 + fq*4 + i][q = fr]
  float mrow = -1e30f, lrow = 0.f;  // per q-row (log2 domain)

  // prologue: stage tile 0
  if (tid < 64) Mb[tid] = mg[tid] ? 0.f : -1e30f;
  gload_lds16(Kg + (size_t)(kv0 + rs) * HD + gs * 8, Ktile + tid * 8);
  gload_lds16(Vg + (size_t)rs * S + kv0 + gs * 8, Vtile + tid * 8);
  asm volatile("s_waitcnt vmcnt(0)" ::: "memory");
  __syncthreads();

  int cur = 0;
  for (int kt = 0; kt < SLEN; kt += 64) {
    const int nb = cur ^ 1, kn = kt + 64;
    if (kn < SLEN) {
      if (tid < 64) Mb[nb * 64 + tid] = mg[kn + tid] ? 0.f : -1e30f;
      gload_lds16(Kg + (size_t)(kv0 + kn + rs) * HD + gs * 8, Ktile + nb * 4096 + tid * 8);
      gload_lds16(Vg + (size_t)rs * S + kv0 + kn + gs * 8, Vtile + nb * 4096 + tid * 8);
    }

    const u16* Kc = Ktile + cur * 4096;
    const u16* Vc = Vtile + cur * 4096;

    // S^T = K Q^T : sv[nt][i] = S[kv = nt*16 + fq*4 + i][q = fr] (log2 units)
    float sv[4][4];
#pragma unroll
    for (int nt = 0; nt < 4; ++nt) {
      const u16* kb2 = Kc + (nt * 16 + fr) * 64;
      bf16x8 k0v = *(const bf16x8*)(kb2 + ((fq) ^ fr7) * 8);
      bf16x8 k1v = *(const bf16x8*)(kb2 + ((4 + fq) ^ fr7) * 8);
      f32x4 t = {};
      t = __builtin_amdgcn_mfma_f32_16x16x32_bf16(k0v, qf0, t, 0, 0, 0);
      t = __builtin_amdgcn_mfma_f32_16x16x32_bf16(k1v, qf1, t, 0, 0, 0);
      float4 mb = *(const float4*)&Mb[cur * 64 + nt * 16 + fq * 4];
      sv[nt][0] = t[0] + mb.x;
      sv[nt][1] = t[1] + mb.y;
      sv[nt][2] = t[2] + mb.z;
      sv[nt][3] = t[3] + mb.w;
    }

    // in-lane max over 16 + cross-fq reduce (lanes ^16, ^32)
    float pmax;
    {
      float m0 = fmaxf(fmaxf(sv[0][0], sv[0][1]), fmaxf(sv[0][2], sv[0][3]));
      float m1 = fmaxf(fmaxf(sv[1][0], sv[1][1]), fmaxf(sv[1][2], sv[1][3]));
      float m2 = fmaxf(fmaxf(sv[2][0], sv[2][1]), fmaxf(sv[2][2], sv[2][3]));
      float m3 = fmaxf(fmaxf(sv[3][0], sv[3][1]), fmaxf(sv[3][2], sv[3][3]));
      pmax = fmaxf(fmaxf(m0, m1), fmaxf(m2, m3));
    }
    pmax = fmaxf(pmax, __shfl_xor(pmax, 16));
    pmax = fmaxf(pmax, __shfl_xor(pmax, 32));

    // defer-max (T13): rescale only when max grew past threshold (log2 units)
    if (__any(pmax > mrow + 12.f)) {
      float nm = fmaxf(mrow, pmax);
      float al = fexp2(mrow - nm);
      mrow = nm;
      lrow *= al;
#pragma unroll
      for (int nt = 0; nt < 4; ++nt)
#pragma unroll
        for (int i = 0; i < 4; ++i) oacc[nt][i] *= al;
    }

    // P = 2^(sv - mrow); in-lane sum + cross-fq reduce
    float p[4][4];
    float rsum;
    {
#pragma unroll
      for (int nt = 0; nt < 4; ++nt)
#pragma unroll
        for (int i = 0; i < 4; ++i) p[nt][i] = fexp2(sv[nt][i] - mrow);
      float s0 = (p[0][0] + p[0][1]) + (p[0][2] + p[0][3]);
      float s1 = (p[1][0] + p[1][1]) + (p[1][2] + p[1][3]);
      float s2 = (p[2][0] + p[2][1]) + (p[2][2] + p[2][3]);
      float s3 = (p[3][0] + p[3][1]) + (p[3][2] + p[3][3]);
      rsum = (s0 + s1) + (s2 + s3);
    }
    rsum += __shfl_xor(rsum, 16);
    rsum += __shfl_xor(rsum, 32);
    lrow += rsum;

    // pack P to bf16 pairs
    int pk[4][2];
#pragma unroll
    for (int nt = 0; nt < 4; ++nt) {
      asm("v_cvt_pk_bf16_f32 %0, %1, %2" : "=v"(pk[nt][0]) : "v"(p[nt][0]), "v"(p[nt][1]));
      asm("v_cvt_pk_bf16_f32 %0, %1, %2" : "=v"(pk[nt][1]) : "v"(p[nt][2]), "v"(p[nt][3]));
    }

    // redistribute to PV B-frags and PV MFMAs
#pragma unroll
    for (int b2 = 0; b2 < 2; ++b2) {
      int w0a = __builtin_amdgcn_ds_bpermute(A0, pk[2 * b2][0]);
      int w0b = __builtin_amdgcn_ds_bpermute(A0, pk[2 * b2 + 1][0]);
      int w1a = __builtin_amdgcn_ds_bpermute(A0, pk[2 * b2][1]);
      int w1b = __builtin_amdgcn_ds_bpermute(A0, pk[2 * b2 + 1][1]);
      int w2a = __builtin_amdgcn_ds_bpermute(A1, pk[2 * b2][0]);
      int w2b = __builtin_amdgcn_ds_bpermute(A1, pk[2 * b2 + 1][0]);
      int w3a = __builtin_amdgcn_ds_bpermute(A1, pk[2 * b2][1]);
      int w3b = __builtin_amdgcn_ds_bpermute(A1, pk[2 * b2 + 1][1]);
      i32x4 wv;
      wv[0] = lofq ? w0a : w0b;
      wv[1] = lofq ? w1a : w1b;
      wv[2] = lofq ? w2a : w2b;
      wv[3] = lofq ? w3a : w3b;
      bf16x8 pfrag = __builtin_bit_cast(bf16x8, wv);
#pragma unroll
      for (int nt = 0; nt < 4; ++nt) {
        const u16* vb2 = Vc + (nt * 16 + fr) * 64;
        bf16x8 vf = *(const bf16x8*)(vb2 + ((b2 * 4 + fq) ^ fr7) * 8);
        oacc[nt] = __builtin_amdgcn_mfma_f32_16x16x32_bf16(vf, pfrag, oacc[nt], 0, 0, 0);
      }
    }

    asm volatile("s_waitcnt vmcnt(0)" ::: "memory");
    __syncthreads();
    cur = nb;
  }

  // epilogue: (m,l) per row + O^T -> [q][d] transpose through LDS -> f32 partials
  if (fq == 0)
    ml[((size_t)z * 32 + bh) * NQ + q0 + w * 16 + fr] = float2{mrow, lrow};

  float* tb = (float*)smem + w * 1088;  // per-wave 16 x 68 f32
#pragma unroll
  for (int nt = 0; nt < 4; ++nt)
#pragma unroll
    for (int i = 0; i < 4; ++i)
      tb[fr * 68 + nt * 16 + fq * 4 + i] = oacc[nt][i];

  const int qloc = lane >> 2, dl = lane & 3;
  const float* trow = tb + qloc * 68 + dl * 16;
  float* gdst = Opart + (((size_t)z * 32 + bh) * NQ + q0 + w * 16 + qloc) * 64 + dl * 16;
#pragma unroll
  for (int j = 0; j < 4; ++j)
    ((float4*)gdst)[j] = ((const float4*)trow)[j];
}

// ---------------- combine split partials -> bf16 Aout ----------------------
__global__ __launch_bounds__(256) void combine_kernel(
    const float* __restrict__ Opart, const float2* __restrict__ ml,
    u16* __restrict__ out) {
  const int bh = blockIdx.y, b = bh >> 4, h = bh & 15;
  const int q = blockIdx.x * 64 + (threadIdx.x >> 2);
  const int dl = threadIdx.x & 3;
  float2 m0 = ml[(size_t)bh * NQ + q];
  float2 m1 = ml[(size_t)(32 + bh) * NQ + q];
  float M = fmaxf(m0.x, m1.x);
  float w0 = fexp2(m0.x - M), w1 = fexp2(m1.x - M);
  float inv = 1.f / (m0.y * w0 + m1.y * w1);
  w0 *= inv; w1 *= inv;
  const float* o0 = Opart + ((size_t)bh * NQ + q) * 64 + dl * 16;
  const float* o1 = Opart + ((size_t)(32 + bh) * NQ + q) * 64 + dl * 16;
  u16* orow = out + ((size_t)b * NQ + q) * H + h * HD + dl * 16;
#pragma unroll
  for (int j = 0; j < 4; ++j) {
    float4 a = ((const float4*)o0)[j];
    float4 c = ((const float4*)o1)[j];
    ushort4 o;
    o.x = f2bf(w0 * a.x + w1 * c.x);
    o.y = f2bf(w0 * a.y + w1 * c.y);
    o.z = f2bf(w0 * a.z + w1 * c.z);
    o.w = f2bf(w0 * a.w + w1 * c.w);
    *(ushort4*)(orow + j * 4) = o;
  }
}

// ---------------------------------------------------------------------------
extern "C" void kernel_launch(void* const* d_in, const int* in_sizes, int n_in,
                              void* d_out, int out_size, void* d_ws, size_t ws_size,
                              hipStream_t stream) {
  const float* queries = (const float*)d_in[0];
  const float* keys_values = (const float*)d_in[1];
  const void* amask = d_in[2];
  const float* W_qkv = (const float*)d_in[3];
  const float* b_qkv = (const float*)d_in[4];
  const float* W_out = (const float*)d_in[5];
  const float* b_out = (const float*)d_in[6];
  const float* gamma = (const float*)d_in[7];
  const float* beta = (const float*)d_in[8];

  char* ws = (char*)d_ws;
  unsigned char* maskN = (unsigned char*)ws;                 // 8 KB
  u16* Xq = (u16*)(ws + 8192);                               // [2048][1024]
  u16* Xkv = Xq + (size_t)Bb * NQ * H;                       // [8192][1024]
  u16* Wtq = Xkv + (size_t)Bb * S * H;                       // [3072][1024]
  u16* Wto = Wtq + (size_t)3 * H * H;                        // [1024][1024]
  u16* Qbuf = Wto + (size_t)H * H;                           // [B][NH][NQ][HD]
  u16* Kbuf = Qbuf + (size_t)Bb * NQ * H;                    // [B][NH][S][HD]; V^T follows
  u16* Vbuf = Kbuf + (size_t)Bb * S * H;                     // [B][NH][HD][S]
  u16* Aout = Vbuf + (size_t)Bb * S * H;                     // [2048][1024]
  // attn partials OVERLAY dead Xq/Xkv region (rewritten by LN each call
  // before GEMMs read them; Opart/ml written after GEMMs consume Xq/Xkv)
  float* Opart = (float*)(ws + 8192);                        // [2][32][1024][64] f32 = 16 MB
  float2* ml = (float2*)((char*)Opart + (size_t)NSPLIT * 32 * NQ * 64 * 4);  // 512 KB

  hipLaunchKernelGGL(mask_norm_kernel, dim3(1), dim3(256), 0, stream,
                     (const unsigned char*)amask, maskN);
  hipLaunchKernelGGL(ln_cast_kernel, dim3(Bb * NQ / 4), dim3(256), 0, stream,
                     queries, gamma, beta, Xq, Bb * NQ);
  hipLaunchKernelGGL(ln_cast_kernel, dim3(Bb * S / 4), dim3(256), 0, stream,
                     keys_values, gamma, beta, Xkv, Bb * S);
  hipLaunchKernelGGL(transpose_cast_kernel, dim3(3 * H / 32, H / 32), dim3(256), 0, stream,
                     W_qkv, Wtq, H, 3 * H);
  hipLaunchKernelGGL(transpose_cast_kernel, dim3(H / 32, H / 32), dim3(256), 0, stream,
                     W_out, Wto, H, H);
  hipLaunchKernelGGL(gemm_bt_kernel<0>, dim3(H / 128, Bb * NQ / 128), dim3(256), 0, stream,
                     Xq, Wtq, b_qkv, (void*)Qbuf);
  hipLaunchKernelGGL(gemm_bt_kernel<1>, dim3(2 * H / 128, Bb * S / 128), dim3(256), 0, stream,
                     Xkv, Wtq + (size_t)H * H, b_qkv + H, (void*)Kbuf);
  hipLaunchKernelGGL(attn_kernel, dim3(NQ / 128, Bb * NH, NSPLIT), dim3(512), 0, stream,
                     Qbuf, Kbuf, Vbuf, maskN, Opart, ml);
  hipLaunchKernelGGL(combine_kernel, dim3(NQ / 64, Bb * NH), dim3(256), 0, stream,
                     Opart, ml, Aout);
  hipLaunchKernelGGL(gemm_bt_kernel<2>, dim3(H / 128, Bb * NQ / 128), dim3(256), 0, stream,
                     Aout, Wto, b_out, d_out);
}

// Round 5
// 216.158 us; speedup vs baseline: 1.4487x; 1.0248x over previous
//
#include <hip/hip_runtime.h>
#include <stdint.h>

#define DEVI __device__ __forceinline__

constexpr int Bb = 2, NQ = 1024, S = 4096, H = 1024, NH = 16, HD = 64;
constexpr int NSPLIT = 4, SLEN = S / NSPLIT;

typedef __bf16 bf16x8 __attribute__((ext_vector_type(8)));
typedef float f32x4 __attribute__((ext_vector_type(4)));
typedef int i32x4 __attribute__((ext_vector_type(4)));
typedef unsigned short u16;
typedef u16 u16x8 __attribute__((ext_vector_type(8)));

DEVI u16 f2bf(float f) {
  union { float f; unsigned u; } v; v.f = f;
  unsigned r = (v.u + 0x7fffu + ((v.u >> 16) & 1u)) >> 16;
  return (u16)r;
}

DEVI float bf2f(u16 x) {
  union { unsigned u; float f; } v; v.u = ((unsigned)x) << 16;
  return v.f;
}

DEVI float fexp2(float x) {
#if __has_builtin(__builtin_amdgcn_exp2f)
  return __builtin_amdgcn_exp2f(x);
#else
  return exp2f(x);
#endif
}

DEVI void gload_lds16(const void* g, void* lds) {
  __builtin_amdgcn_global_load_lds(
      (const __attribute__((address_space(1))) void*)(uintptr_t)g,
      (__attribute__((address_space(3))) void*)(uint32_t)(uintptr_t)lds,
      16, 0, 0);
}

// ---------------- mask normalize: detect bool(1B) vs int32(4B), emit u8 ----
__global__ void mask_norm_kernel(const unsigned char* __restrict__ m,
                                 unsigned char* __restrict__ out) {
  __shared__ int isByte;
  if (threadIdx.x == 0) isByte = 0;
  __syncthreads();
  int any = 0;
  for (int p = threadIdx.x; p < Bb * S; p += 256)
    if ((p & 3) && m[p]) any = 1;
  if (any) atomicOr(&isByte, 1);
  __syncthreads();
  const int bytemode = isByte;
  for (int i = threadIdx.x; i < Bb * S; i += 256) {
    unsigned char v = bytemode ? (unsigned char)(m[i] != 0)
                               : (unsigned char)(((const int*)m)[i] != 0);
    out[i] = v;
  }
}

// ---------------- LayerNorm (f32 in) + cast bf16, one wave per row ---------
__global__ __launch_bounds__(256) void ln_cast_kernel(
    const float* __restrict__ x, const float* __restrict__ gamma,
    const float* __restrict__ beta, u16* __restrict__ out, int nrows) {
  int row = blockIdx.x * 4 + (threadIdx.x >> 6);
  int lane = threadIdx.x & 63;
  if (row >= nrows) return;
  const float4* xr = (const float4*)(x + (size_t)row * H);
  float4 v[4];
  float s = 0.f, s2 = 0.f;
#pragma unroll
  for (int i = 0; i < 4; ++i) {
    v[i] = xr[lane + i * 64];
    s += v[i].x + v[i].y + v[i].z + v[i].w;
    s2 += v[i].x * v[i].x + v[i].y * v[i].y + v[i].z * v[i].z + v[i].w * v[i].w;
  }
#pragma unroll
  for (int d = 1; d < 64; d <<= 1) { s += __shfl_xor(s, d); s2 += __shfl_xor(s2, d); }
  float mu = s * (1.f / H);
  float rstd = rsqrtf(s2 * (1.f / H) - mu * mu + 1e-6f);
  u16* orow = out + (size_t)row * H;
  const float4* g4 = (const float4*)gamma;
  const float4* b4 = (const float4*)beta;
#pragma unroll
  for (int i = 0; i < 4; ++i) {
    float4 g = g4[lane + i * 64], bb = b4[lane + i * 64];
    ushort4 o;
    o.x = f2bf((v[i].x - mu) * rstd * g.x + bb.x);
    o.y = f2bf((v[i].y - mu) * rstd * g.y + bb.y);
    o.z = f2bf((v[i].z - mu) * rstd * g.z + bb.z);
    o.w = f2bf((v[i].w - mu) * rstd * g.w + bb.w);
    *(ushort4*)(orow + (size_t)(lane + i * 64) * 4) = o;
  }
}

// ---------------- transpose f32 [R][C] -> bf16 [C][R] ----------------------
__global__ __launch_bounds__(256) void transpose_cast_kernel(
    const float* __restrict__ in, u16* __restrict__ out, int R, int C) {
  __shared__ float tile[32][33];
  int c0 = blockIdx.x * 32, r0 = blockIdx.y * 32;
  int tx = threadIdx.x & 31, ty = threadIdx.x >> 5;
#pragma unroll
  for (int i = 0; i < 32; i += 8)
    tile[ty + i][tx] = in[(size_t)(r0 + ty + i) * C + c0 + tx];
  __syncthreads();
#pragma unroll
  for (int i = 0; i < 32; i += 8)
    out[(size_t)(c0 + ty + i) * R + r0 + tx] = f2bf(tile[tx][ty + i]);
}

// ---------------- 128x128 bf16 GEMM, C = A[M,K] * Bt[N,K]^T + bias ---------
// EPI 0: -> Q buf [B][NH][NQ][HD] bf16, pre-scaled by 0.125*log2(e)
// EPI 1: merged K|V: c<1024 -> K [B][NH][S][HD]; c>=1024 -> V^T [B][NH][HD][S]
// EPI 2: -> f32 out [M][1024]
template <int EPI>
__global__ __launch_bounds__(256) void gemm_bt_kernel(
    const u16* __restrict__ A, const u16* __restrict__ Bt,
    const float* __restrict__ bias, void* __restrict__ outp) {
  constexpr int K = 1024, BK = 32;
  __shared__ __align__(16) u16 Ash[128 * BK];
  __shared__ __align__(16) u16 Bsh[128 * BK];
  const int tid = threadIdx.x, w = tid >> 6, lane = tid & 63;
  const int brow = blockIdx.y * 128, bcol = blockIdx.x * 128;
  const u16* Ag = A + (size_t)brow * K;
  const u16* Bg = Bt + (size_t)bcol * K;
  const int c0 = tid, c1 = tid + 256;
  const int wr = (w >> 1) * 64, wc = (w & 1) * 64;
  const int fr = lane & 15, fq = lane >> 4;
  f32x4 acc[4][4] = {};

  for (int k0 = 0; k0 < K; k0 += BK) {
    gload_lds16(Ag + (size_t)(c0 >> 2) * K + k0 + (c0 & 3) * 8, Ash + c0 * 8);
    gload_lds16(Ag + (size_t)(c1 >> 2) * K + k0 + (c1 & 3) * 8, Ash + c1 * 8);
    gload_lds16(Bg + (size_t)(c0 >> 2) * K + k0 + (c0 & 3) * 8, Bsh + c0 * 8);
    gload_lds16(Bg + (size_t)(c1 >> 2) * K + k0 + (c1 & 3) * 8, Bsh + c1 * 8);
    asm volatile("s_waitcnt vmcnt(0)" ::: "memory");
    __syncthreads();
    bf16x8 af[4], bfr[4];
#pragma unroll
    for (int m = 0; m < 4; ++m)
      af[m] = *(const bf16x8*)(Ash + (wr + m * 16 + fr) * BK + fq * 8);
#pragma unroll
    for (int n = 0; n < 4; ++n)
      bfr[n] = *(const bf16x8*)(Bsh + (wc + n * 16 + fr) * BK + fq * 8);
#pragma unroll
    for (int m = 0; m < 4; ++m)
#pragma unroll
      for (int n = 0; n < 4; ++n)
        acc[m][n] = __builtin_amdgcn_mfma_f32_16x16x32_bf16(af[m], bfr[n], acc[m][n], 0, 0, 0);
    __syncthreads();
  }

  constexpr float QSCALE = 0.125f * 1.4426950408889634f;  // fold 1/sqrt(HD) * log2(e)
#pragma unroll
  for (int m = 0; m < 4; ++m)
#pragma unroll
    for (int n = 0; n < 4; ++n) {
      const int c = bcol + wc + n * 16 + fr;
      const int r0 = brow + wr + m * 16 + fq * 4;
      if constexpr (EPI == 1) {
        if (c >= 1024) {  // V^T path: pack 4 consecutive kv along S
          int b = r0 >> 12, kv = r0 & (S - 1);
          int cc = c - 1024, head = cc >> 6, d = cc & 63;
          ushort4 o;
          o.x = f2bf(acc[m][n][0] + bias[c]);
          o.y = f2bf(acc[m][n][1] + bias[c]);
          o.z = f2bf(acc[m][n][2] + bias[c]);
          o.w = f2bf(acc[m][n][3] + bias[c]);
          u16* vb = (u16*)outp + (size_t)Bb * NH * S * HD;
          *(ushort4*)(vb + (((size_t)(b * NH + head)) * HD + d) * S + kv) = o;
        } else {  // K path
          u16* kb = (u16*)outp;
#pragma unroll
          for (int i = 0; i < 4; ++i) {
            int r = r0 + i;
            kb[((((size_t)(r >> 12)) * NH + (c >> 6)) * S + (r & (S - 1))) * HD + (c & 63)] =
                f2bf(acc[m][n][i] + bias[c]);
          }
        }
      } else {
#pragma unroll
        for (int i = 0; i < 4; ++i) {
          int r = r0 + i;
          float val = acc[m][n][i] + bias[c];
          if constexpr (EPI == 0) {
            u16* qb = (u16*)outp;
            qb[((((size_t)(r >> 10)) * NH + (c >> 6)) * NQ + (r & (NQ - 1))) * HD + (c & 63)] =
                f2bf(val * QSCALE);
          } else {
            float* ob = (float*)outp;
            ob[(size_t)r * H + c] = val;
          }
        }
      }
    }
}

// ---------------- flash attention, 8 waves, QBLK=128, split-S=4 ------------
// Swapped QK^T in-register softmax (lane owns q=fr). K [kv][d], V^T [d][kv]
// staged XOR-swizzled via global_load_lds, double-buffered. Partial O (bf16,
// [q][d]) + (m,l) per row written per split; combine_kernel merges.
__global__ __launch_bounds__(512, 4) void attn_kernel(
    const u16* __restrict__ Qb, const u16* __restrict__ Kb,
    const u16* __restrict__ Vt, const unsigned char* __restrict__ mask,
    u16* __restrict__ Opart, float2* __restrict__ ml) {
  __shared__ __align__(16) char smem[34816];  // stage: 2x8K K + 2x8K V + 512B mask; epi: 8x16x68 f32
  u16* Ktile = (u16*)smem;
  u16* Vtile = Ktile + 8192;
  float* Mb = (float*)(Vtile + 8192);
  const int q0 = blockIdx.x * 128;
  const int bh = blockIdx.y, b = bh >> 4;
  const int z = blockIdx.z, kv0 = z * SLEN;
  const int tid = threadIdx.x, w = tid >> 6, lane = tid & 63;
  const int fr = lane & 15, fq = lane >> 4, fr7 = fr & 7;
  const u16* Qg = Qb + ((size_t)bh * NQ + q0 + w * 16) * HD;
  const u16* Kg = Kb + (size_t)bh * S * HD;
  const u16* Vg = Vt + (size_t)bh * HD * S;
  const unsigned char* mg = mask + (size_t)b * S + kv0;

  const int rs = tid >> 3, gs = (tid & 7) ^ (rs & 7);

  // Q as B-operand fragments (rows = q = fr, contraction chunks over d)
  bf16x8 qf0 = *(const bf16x8*)(Qg + fr * HD + fq * 8);
  bf16x8 qf1 = *(const bf16x8*)(Qg + fr * HD + 32 + fq * 8);

  // bpermute byte-addresses for P redistribution
  const int A0 = ((((fq << 1)) & 3) * 16 + fr) << 2;
  const int A1 = ((((fq << 1) + 1) & 3) * 16 + fr) << 2;
  const bool lofq = (fq < 2);

  f32x4 oacc[4] = {};               // O^T: [d = nt*16 + fq*4 + i][q = fr]
  float mrow = -1e30f, lrow = 0.f;  // per q-row (log2 domain)

  // prologue: stage tile 0
  if (tid < 64) Mb[tid] = mg[tid] ? 0.f : -1e30f;
  gload_lds16(Kg + (size_t)(kv0 + rs) * HD + gs * 8, Ktile + tid * 8);
  gload_lds16(Vg + (size_t)rs * S + kv0 + gs * 8, Vtile + tid * 8);
  asm volatile("s_waitcnt vmcnt(0)" ::: "memory");
  __syncthreads();

  int cur = 0;
  for (int kt = 0; kt < SLEN; kt += 64) {
    const int nb = cur ^ 1, kn = kt + 64;
    if (kn < SLEN) {
      if (tid < 64) Mb[nb * 64 + tid] = mg[kn + tid] ? 0.f : -1e30f;
      gload_lds16(Kg + (size_t)(kv0 + kn + rs) * HD + gs * 8, Ktile + nb * 4096 + tid * 8);
      gload_lds16(Vg + (size_t)rs * S + kv0 + kn + gs * 8, Vtile + nb * 4096 + tid * 8);
    }

    const u16* Kc = Ktile + cur * 4096;
    const u16* Vc = Vtile + cur * 4096;

    // S^T = K Q^T : sv[nt][i] = S[kv = nt*16 + fq*4 + i][q = fr] (log2 units)
    float sv[4][4];
#pragma unroll
    for (int nt = 0; nt < 4; ++nt) {
      const u16* kb2 = Kc + (nt * 16 + fr) * 64;
      bf16x8 k0v = *(const bf16x8*)(kb2 + ((fq) ^ fr7) * 8);
      bf16x8 k1v = *(const bf16x8*)(kb2 + ((4 + fq) ^ fr7) * 8);
      f32x4 t = {};
      t = __builtin_amdgcn_mfma_f32_16x16x32_bf16(k0v, qf0, t, 0, 0, 0);
      t = __builtin_amdgcn_mfma_f32_16x16x32_bf16(k1v, qf1, t, 0, 0, 0);
      float4 mb = *(const float4*)&Mb[cur * 64 + nt * 16 + fq * 4];
      sv[nt][0] = t[0] + mb.x;
      sv[nt][1] = t[1] + mb.y;
      sv[nt][2] = t[2] + mb.z;
      sv[nt][3] = t[3] + mb.w;
    }

    // in-lane max over 16 + cross-fq reduce (lanes ^16, ^32)
    float pmax;
    {
      float m0 = fmaxf(fmaxf(sv[0][0], sv[0][1]), fmaxf(sv[0][2], sv[0][3]));
      float m1 = fmaxf(fmaxf(sv[1][0], sv[1][1]), fmaxf(sv[1][2], sv[1][3]));
      float m2 = fmaxf(fmaxf(sv[2][0], sv[2][1]), fmaxf(sv[2][2], sv[2][3]));
      float m3 = fmaxf(fmaxf(sv[3][0], sv[3][1]), fmaxf(sv[3][2], sv[3][3]));
      pmax = fmaxf(fmaxf(m0, m1), fmaxf(m2, m3));
    }
    pmax = fmaxf(pmax, __shfl_xor(pmax, 16));
    pmax = fmaxf(pmax, __shfl_xor(pmax, 32));

    // defer-max (T13): rescale only when max grew past threshold (log2 units)
    if (__any(pmax > mrow + 12.f)) {
      float nm = fmaxf(mrow, pmax);
      float al = fexp2(mrow - nm);
      mrow = nm;
      lrow *= al;
#pragma unroll
      for (int nt = 0; nt < 4; ++nt)
#pragma unroll
        for (int i = 0; i < 4; ++i) oacc[nt][i] *= al;
    }

    // P = 2^(sv - mrow); in-lane sum + cross-fq reduce
    float p[4][4];
    float rsum;
    {
#pragma unroll
      for (int nt = 0; nt < 4; ++nt)
#pragma unroll
        for (int i = 0; i < 4; ++i) p[nt][i] = fexp2(sv[nt][i] - mrow);
      float s0 = (p[0][0] + p[0][1]) + (p[0][2] + p[0][3]);
      float s1 = (p[1][0] + p[1][1]) + (p[1][2] + p[1][3]);
      float s2 = (p[2][0] + p[2][1]) + (p[2][2] + p[2][3]);
      float s3 = (p[3][0] + p[3][1]) + (p[3][2] + p[3][3]);
      rsum = (s0 + s1) + (s2 + s3);
    }
    rsum += __shfl_xor(rsum, 16);
    rsum += __shfl_xor(rsum, 32);
    lrow += rsum;

    // pack P to bf16 pairs
    int pk[4][2];
#pragma unroll
    for (int nt = 0; nt < 4; ++nt) {
      asm("v_cvt_pk_bf16_f32 %0, %1, %2" : "=v"(pk[nt][0]) : "v"(p[nt][0]), "v"(p[nt][1]));
      asm("v_cvt_pk_bf16_f32 %0, %1, %2" : "=v"(pk[nt][1]) : "v"(p[nt][2]), "v"(p[nt][3]));
    }

    // redistribute to PV B-frags and PV MFMAs
#pragma unroll
    for (int b2 = 0; b2 < 2; ++b2) {
      int w0a = __builtin_amdgcn_ds_bpermute(A0, pk[2 * b2][0]);
      int w0b = __builtin_amdgcn_ds_bpermute(A0, pk[2 * b2 + 1][0]);
      int w1a = __builtin_amdgcn_ds_bpermute(A0, pk[2 * b2][1]);
      int w1b = __builtin_amdgcn_ds_bpermute(A0, pk[2 * b2 + 1][1]);
      int w2a = __builtin_amdgcn_ds_bpermute(A1, pk[2 * b2][0]);
      int w2b = __builtin_amdgcn_ds_bpermute(A1, pk[2 * b2 + 1][0]);
      int w3a = __builtin_amdgcn_ds_bpermute(A1, pk[2 * b2][1]);
      int w3b = __builtin_amdgcn_ds_bpermute(A1, pk[2 * b2 + 1][1]);
      i32x4 wv;
      wv[0] = lofq ? w0a : w0b;
      wv[1] = lofq ? w1a : w1b;
      wv[2] = lofq ? w2a : w2b;
      wv[3] = lofq ? w3a : w3b;
      bf16x8 pfrag = __builtin_bit_cast(bf16x8, wv);
#pragma unroll
      for (int nt = 0; nt < 4; ++nt) {
        const u16* vb2 = Vc + (nt * 16 + fr) * 64;
        bf16x8 vf = *(const bf16x8*)(vb2 + ((b2 * 4 + fq) ^ fr7) * 8);
        oacc[nt] = __builtin_amdgcn_mfma_f32_16x16x32_bf16(vf, pfrag, oacc[nt], 0, 0, 0);
      }
    }

    asm volatile("s_waitcnt vmcnt(0)" ::: "memory");
    __syncthreads();
    cur = nb;
  }

  // epilogue: (m,l) per row + O^T -> [q][d] transpose through LDS -> bf16 partials
  if (fq == 0)
    ml[((size_t)z * 32 + bh) * NQ + q0 + w * 16 + fr] = float2{mrow, lrow};

  float* tb = (float*)smem + w * 1088;  // per-wave 16 x 68 f32
#pragma unroll
  for (int nt = 0; nt < 4; ++nt)
#pragma unroll
    for (int i = 0; i < 4; ++i)
      tb[fr * 68 + nt * 16 + fq * 4 + i] = oacc[nt][i];

  const int qloc = lane >> 2, dl = lane & 3;
  const float* trow = tb + qloc * 68 + dl * 16;
  u16* gdst = Opart + (((size_t)z * 32 + bh) * NQ + q0 + w * 16 + qloc) * 64 + dl * 16;
  u16x8 o0, o1;
#pragma unroll
  for (int j = 0; j < 8; ++j) {
    o0[j] = f2bf(trow[j]);
    o1[j] = f2bf(trow[8 + j]);
  }
  *(u16x8*)gdst = o0;
  *(u16x8*)(gdst + 8) = o1;
}

// ---------------- combine split partials -> bf16 Aout ----------------------
__global__ __launch_bounds__(256) void combine_kernel(
    const u16* __restrict__ Opart, const float2* __restrict__ ml,
    u16* __restrict__ out) {
  const int bh = blockIdx.y, b = bh >> 4, h = bh & 15;
  const int q = blockIdx.x * 64 + (threadIdx.x >> 2);
  const int dl = threadIdx.x & 3;
  float2 mm[NSPLIT];
  float M = -1e30f;
#pragma unroll
  for (int zz = 0; zz < NSPLIT; ++zz) {
    mm[zz] = ml[((size_t)zz * 32 + bh) * NQ + q];
    M = fmaxf(M, mm[zz].x);
  }
  float wz[NSPLIT], lsum = 0.f;
#pragma unroll
  for (int zz = 0; zz < NSPLIT; ++zz) {
    wz[zz] = fexp2(mm[zz].x - M);
    lsum += mm[zz].y * wz[zz];
  }
  const float inv = 1.f / lsum;
  float acc[16] = {};
#pragma unroll
  for (int zz = 0; zz < NSPLIT; ++zz) {
    const u16* op = Opart + (((size_t)zz * 32 + bh) * NQ + q) * 64 + dl * 16;
    u16x8 a0 = *(const u16x8*)op;
    u16x8 a1 = *(const u16x8*)(op + 8);
    float wi = wz[zz] * inv;
#pragma unroll
    for (int j = 0; j < 8; ++j) {
      acc[j] += wi * bf2f(a0[j]);
      acc[8 + j] += wi * bf2f(a1[j]);
    }
  }
  u16* orow = out + ((size_t)b * NQ + q) * H + h * HD + dl * 16;
  u16x8 o0, o1;
#pragma unroll
  for (int j = 0; j < 8; ++j) {
    o0[j] = f2bf(acc[j]);
    o1[j] = f2bf(acc[8 + j]);
  }
  *(u16x8*)orow = o0;
  *(u16x8*)(orow + 8) = o1;
}

// ---------------------------------------------------------------------------
extern "C" void kernel_launch(void* const* d_in, const int* in_sizes, int n_in,
                              void* d_out, int out_size, void* d_ws, size_t ws_size,
                              hipStream_t stream) {
  const float* queries = (const float*)d_in[0];
  const float* keys_values = (const float*)d_in[1];
  const void* amask = d_in[2];
  const float* W_qkv = (const float*)d_in[3];
  const float* b_qkv = (const float*)d_in[4];
  const float* W_out = (const float*)d_in[5];
  const float* b_out = (const float*)d_in[6];
  const float* gamma = (const float*)d_in[7];
  const float* beta = (const float*)d_in[8];

  char* ws = (char*)d_ws;
  unsigned char* maskN = (unsigned char*)ws;                 // 8 KB
  u16* Xq = (u16*)(ws + 8192);                               // [2048][1024]
  u16* Xkv = Xq + (size_t)Bb * NQ * H;                       // [8192][1024]
  u16* Wtq = Xkv + (size_t)Bb * S * H;                       // [3072][1024]
  u16* Wto = Wtq + (size_t)3 * H * H;                        // [1024][1024]
  u16* Qbuf = Wto + (size_t)H * H;                           // [B][NH][NQ][HD]
  u16* Kbuf = Qbuf + (size_t)Bb * NQ * H;                    // [B][NH][S][HD]; V^T follows
  u16* Vbuf = Kbuf + (size_t)Bb * S * H;                     // [B][NH][HD][S]
  u16* Aout = Vbuf + (size_t)Bb * S * H;                     // [2048][1024]
  // attn partials OVERLAY dead Xq/Xkv region (rewritten by LN each call
  // before GEMMs read them; Opart/ml written after GEMMs consume Xq/Xkv).
  // bf16 partials: 4*32*1024*64*2B = 16 MB; ml 4*32*1024*8B = 1 MB; fits 20 MB.
  u16* Opart = (u16*)(ws + 8192);
  float2* ml = (float2*)((char*)Opart + (size_t)NSPLIT * 32 * NQ * 64 * 2);

  hipLaunchKernelGGL(mask_norm_kernel, dim3(1), dim3(256), 0, stream,
                     (const unsigned char*)amask, maskN);
  hipLaunchKernelGGL(ln_cast_kernel, dim3(Bb * NQ / 4), dim3(256), 0, stream,
                     queries, gamma, beta, Xq, Bb * NQ);
  hipLaunchKernelGGL(ln_cast_kernel, dim3(Bb * S / 4), dim3(256), 0, stream,
                     keys_values, gamma, beta, Xkv, Bb * S);
  hipLaunchKernelGGL(transpose_cast_kernel, dim3(3 * H / 32, H / 32), dim3(256), 0, stream,
                     W_qkv, Wtq, H, 3 * H);
  hipLaunchKernelGGL(transpose_cast_kernel, dim3(H / 32, H / 32), dim3(256), 0, stream,
                     W_out, Wto, H, H);
  hipLaunchKernelGGL(gemm_bt_kernel<0>, dim3(H / 128, Bb * NQ / 128), dim3(256), 0, stream,
                     Xq, Wtq, b_qkv, (void*)Qbuf);
  hipLaunchKernelGGL(gemm_bt_kernel<1>, dim3(2 * H / 128, Bb * S / 128), dim3(256), 0, stream,
                     Xkv, Wtq + (size_t)H * H, b_qkv + H, (void*)Kbuf);
  hipLaunchKernelGGL(attn_kernel, dim3(NQ / 128, Bb * NH, NSPLIT), dim3(512), 0, stream,
                     Qbuf, Kbuf, Vbuf, maskN, Opart, ml);
  hipLaunchKernelGGL(combine_kernel, dim3(NQ / 64, Bb * NH), dim3(256), 0, stream,
                     Opart, ml, Aout);
  hipLaunchKernelGGL(gemm_bt_kernel<2>, dim3(H / 128, Bb * NQ / 128), dim3(256), 0, stream,
                     Aout, Wto, b_out, d_out);
}

// Round 6
// 194.856 us; speedup vs baseline: 1.6071x; 1.1093x over previous
//
#include <hip/hip_runtime.h>
#include <stdint.h>

#define DEVI __device__ __forceinline__

constexpr int Bb = 2, NQ = 1024, S = 4096, H = 1024, NH = 16, HD = 64;
constexpr int NSPLIT = 4, SLEN = S / NSPLIT;

typedef __bf16 bf16x8 __attribute__((ext_vector_type(8)));
typedef float f32x4 __attribute__((ext_vector_type(4)));
typedef int i32x4 __attribute__((ext_vector_type(4)));
typedef unsigned short u16;
typedef u16 u16x8 __attribute__((ext_vector_type(8)));

DEVI u16 f2bf(float f) {
  union { float f; unsigned u; } v; v.f = f;
  unsigned r = (v.u + 0x7fffu + ((v.u >> 16) & 1u)) >> 16;
  return (u16)r;
}

DEVI float bf2f(u16 x) {
  union { unsigned u; float f; } v; v.u = ((unsigned)x) << 16;
  return v.f;
}

DEVI float fexp2(float x) {
#if __has_builtin(__builtin_amdgcn_exp2f)
  return __builtin_amdgcn_exp2f(x);
#else
  return exp2f(x);
#endif
}

DEVI void gload_lds16(const void* g, void* lds) {
  __builtin_amdgcn_global_load_lds(
      (const __attribute__((address_space(1))) void*)(uintptr_t)g,
      (__attribute__((address_space(3))) void*)(uint32_t)(uintptr_t)lds,
      16, 0, 0);
}

// ---------------- fused prep: mask-norm | LN(q) | LN(kv) | W transposes ----
// block 0: mask; [1,513): LN q; [513,2561): LN kv; [2561,5633): W_qkv^T;
// [5633,6657): W_out^T. All roles 256 threads, independent outputs.
DEVI void ln_body(const float* __restrict__ x, const float* __restrict__ gamma,
                  const float* __restrict__ beta, u16* __restrict__ out, int row) {
  int lane = threadIdx.x & 63;
  const float4* xr = (const float4*)(x + (size_t)row * H);
  float4 v[4];
  float s = 0.f, s2 = 0.f;
#pragma unroll
  for (int i = 0; i < 4; ++i) {
    v[i] = xr[lane + i * 64];
    s += v[i].x + v[i].y + v[i].z + v[i].w;
    s2 += v[i].x * v[i].x + v[i].y * v[i].y + v[i].z * v[i].z + v[i].w * v[i].w;
  }
#pragma unroll
  for (int d = 1; d < 64; d <<= 1) { s += __shfl_xor(s, d); s2 += __shfl_xor(s2, d); }
  float mu = s * (1.f / H);
  float rstd = rsqrtf(s2 * (1.f / H) - mu * mu + 1e-6f);
  u16* orow = out + (size_t)row * H;
  const float4* g4 = (const float4*)gamma;
  const float4* b4 = (const float4*)beta;
#pragma unroll
  for (int i = 0; i < 4; ++i) {
    float4 g = g4[lane + i * 64], bb = b4[lane + i * 64];
    ushort4 o;
    o.x = f2bf((v[i].x - mu) * rstd * g.x + bb.x);
    o.y = f2bf((v[i].y - mu) * rstd * g.y + bb.y);
    o.z = f2bf((v[i].z - mu) * rstd * g.z + bb.z);
    o.w = f2bf((v[i].w - mu) * rstd * g.w + bb.w);
    *(ushort4*)(orow + (size_t)(lane + i * 64) * 4) = o;
  }
}

__global__ __launch_bounds__(256) void prep_kernel(
    const unsigned char* __restrict__ mraw, unsigned char* __restrict__ maskN,
    const float* __restrict__ queries, const float* __restrict__ keys_values,
    const float* __restrict__ gamma, const float* __restrict__ beta,
    u16* __restrict__ Xq, u16* __restrict__ Xkv,
    const float* __restrict__ W_qkv, const float* __restrict__ W_out,
    u16* __restrict__ Wtq, u16* __restrict__ Wto) {
  __shared__ int isByte;
  __shared__ float tile[32][33];
  const int b = blockIdx.x;
  if (b == 0) {
    if (threadIdx.x == 0) isByte = 0;
    __syncthreads();
    int any = 0;
    for (int p = threadIdx.x; p < Bb * S; p += 256)
      if ((p & 3) && mraw[p]) any = 1;
    if (any) atomicOr(&isByte, 1);
    __syncthreads();
    const int bytemode = isByte;
    for (int i = threadIdx.x; i < Bb * S; i += 256) {
      unsigned char v = bytemode ? (unsigned char)(mraw[i] != 0)
                                 : (unsigned char)(((const int*)mraw)[i] != 0);
      maskN[i] = v;
    }
  } else if (b < 513) {
    ln_body(queries, gamma, beta, Xq, (b - 1) * 4 + (threadIdx.x >> 6));
  } else if (b < 2561) {
    ln_body(keys_values, gamma, beta, Xkv, (b - 513) * 4 + (threadIdx.x >> 6));
  } else {
    const float* in; u16* out; int C, t;
    if (b < 5633) { t = b - 2561; in = W_qkv; out = Wtq; C = 3 * H; }
    else          { t = b - 5633; in = W_out; out = Wto; C = H; }
    const int nbx = C / 32;
    int c0 = (t % nbx) * 32, r0 = (t / nbx) * 32;
    int tx = threadIdx.x & 31, ty = threadIdx.x >> 5;
#pragma unroll
    for (int i = 0; i < 32; i += 8)
      tile[ty + i][tx] = in[(size_t)(r0 + ty + i) * C + c0 + tx];
    __syncthreads();
#pragma unroll
    for (int i = 0; i < 32; i += 8)
      out[(size_t)(c0 + ty + i) * H + r0 + tx] = f2bf(tile[tx][ty + i]);
  }
}

// ---------------- GEMM core (128x128 tile, BK=32, bf16 MFMA) ---------------
#define GEMM_CORE(Ag, Bg)                                                        \
  f32x4 acc[4][4] = {};                                                          \
  {                                                                              \
    for (int k0 = 0; k0 < 1024; k0 += 32) {                                      \
      gload_lds16(Ag + (size_t)(c0 >> 2) * 1024 + k0 + (c0 & 3) * 8, Ash + c0 * 8); \
      gload_lds16(Ag + (size_t)(c1 >> 2) * 1024 + k0 + (c1 & 3) * 8, Ash + c1 * 8); \
      gload_lds16(Bg + (size_t)(c0 >> 2) * 1024 + k0 + (c0 & 3) * 8, Bsh + c0 * 8); \
      gload_lds16(Bg + (size_t)(c1 >> 2) * 1024 + k0 + (c1 & 3) * 8, Bsh + c1 * 8); \
      asm volatile("s_waitcnt vmcnt(0)" ::: "memory");                           \
      __syncthreads();                                                           \
      bf16x8 af[4], bfr[4];                                                      \
      _Pragma("unroll") for (int m = 0; m < 4; ++m)                              \
          af[m] = *(const bf16x8*)(Ash + (wr + m * 16 + fr) * 32 + fq * 8);      \
      _Pragma("unroll") for (int n = 0; n < 4; ++n)                              \
          bfr[n] = *(const bf16x8*)(Bsh + (wc + n * 16 + fr) * 32 + fq * 8);     \
      _Pragma("unroll") for (int m = 0; m < 4; ++m)                              \
          _Pragma("unroll") for (int n = 0; n < 4; ++n)                          \
              acc[m][n] = __builtin_amdgcn_mfma_f32_16x16x32_bf16(af[m], bfr[n], acc[m][n], 0, 0, 0); \
      __syncthreads();                                                           \
    }                                                                            \
  }

// ---------------- fused Q + K/V projection GEMM ----------------------------
// blocks [0,128): Q-gemm (Xq x Wtq[:,0:1024]) -> Qbuf bf16 (pre-scaled)
// blocks [128,1152): KV-gemm (Xkv x Wtq[:,1024:3072]) -> K + V^T bufs
__global__ __launch_bounds__(256) void gemm_qkv_kernel(
    const u16* __restrict__ Xq, const u16* __restrict__ Xkv,
    const u16* __restrict__ Wtq, const float* __restrict__ b_qkv,
    u16* __restrict__ Qbuf, u16* __restrict__ KVbuf) {
  __shared__ __align__(16) u16 Ash[128 * 32];
  __shared__ __align__(16) u16 Bsh[128 * 32];
  const int tid = threadIdx.x, w = tid >> 6, lane = tid & 63;
  const int c0 = tid, c1 = tid + 256;
  const int wr = (w >> 1) * 64, wc = (w & 1) * 64;
  const int fr = lane & 15, fq = lane >> 4;
  const int bidx = blockIdx.x;
  const bool isQ = bidx < 128;
  int bx, by;
  const u16 *Ap, *Bp;
  const float* bias;
  if (isQ) { bx = bidx & 7; by = bidx >> 3; Ap = Xq; Bp = Wtq; bias = b_qkv; }
  else { int t = bidx - 128; bx = t & 15; by = t >> 4; Ap = Xkv; Bp = Wtq + (size_t)H * H; bias = b_qkv + H; }
  const int brow = by * 128, bcol = bx * 128;
  const u16* Ag = Ap + (size_t)brow * 1024;
  const u16* Bg = Bp + (size_t)bcol * 1024;
  GEMM_CORE(Ag, Bg)

  constexpr float QSCALE = 0.125f * 1.4426950408889634f;
#pragma unroll
  for (int m = 0; m < 4; ++m)
#pragma unroll
    for (int n = 0; n < 4; ++n) {
      const int c = bcol + wc + n * 16 + fr;
      const int r0 = brow + wr + m * 16 + fq * 4;
      if (isQ) {
#pragma unroll
        for (int i = 0; i < 4; ++i) {
          int r = r0 + i;
          Qbuf[((((size_t)(r >> 10)) * NH + (c >> 6)) * NQ + (r & (NQ - 1))) * HD + (c & 63)] =
              f2bf((acc[m][n][i] + bias[c]) * QSCALE);
        }
      } else if (c >= 1024) {  // V^T: [B][NH][HD][S], 4 consecutive kv packed
        int bb = r0 >> 12, kv = r0 & (S - 1);
        int cc = c - 1024, head = cc >> 6, d = cc & 63;
        ushort4 o;
        o.x = f2bf(acc[m][n][0] + bias[c]);
        o.y = f2bf(acc[m][n][1] + bias[c]);
        o.z = f2bf(acc[m][n][2] + bias[c]);
        o.w = f2bf(acc[m][n][3] + bias[c]);
        u16* vb = KVbuf + (size_t)Bb * NH * S * HD;
        *(ushort4*)(vb + (((size_t)(bb * NH + head)) * HD + d) * S + kv) = o;
      } else {  // K: [B][NH][S][HD]
#pragma unroll
        for (int i = 0; i < 4; ++i) {
          int r = r0 + i;
          KVbuf[((((size_t)(r >> 12)) * NH + (c >> 6)) * S + (r & (S - 1))) * HD + (c & 63)] =
              f2bf(acc[m][n][i] + bias[c]);
        }
      }
    }
}

// ---------------- output projection GEMM -> f32 d_out ----------------------
__global__ __launch_bounds__(256) void gemm_out_kernel(
    const u16* __restrict__ A, const u16* __restrict__ Bt,
    const float* __restrict__ bias, float* __restrict__ outp) {
  __shared__ __align__(16) u16 Ash[128 * 32];
  __shared__ __align__(16) u16 Bsh[128 * 32];
  const int tid = threadIdx.x, w = tid >> 6, lane = tid & 63;
  const int c0 = tid, c1 = tid + 256;
  const int wr = (w >> 1) * 64, wc = (w & 1) * 64;
  const int fr = lane & 15, fq = lane >> 4;
  const int brow = blockIdx.y * 128, bcol = blockIdx.x * 128;
  const u16* Ag = A + (size_t)brow * 1024;
  const u16* Bg = Bt + (size_t)bcol * 1024;
  GEMM_CORE(Ag, Bg)
#pragma unroll
  for (int m = 0; m < 4; ++m)
#pragma unroll
    for (int n = 0; n < 4; ++n) {
      const int c = bcol + wc + n * 16 + fr;
      const int r0 = brow + wr + m * 16 + fq * 4;
#pragma unroll
      for (int i = 0; i < 4; ++i)
        outp[(size_t)(r0 + i) * H + c] = acc[m][n][i] + bias[c];
    }
}

// ---------------- flash attention, 8 waves, QBLK=128, split-S=4 ------------
// XCD-locality block swizzle: all 8 q-blocks of one (bh,z) share b%8 -> same
// XCD L2 caches that K/V range once. Swapped QK^T in-register softmax; lazy
// in-lane max (wave __any gate); lrow reduced only at epilogue.
__global__ __launch_bounds__(512, 4) void attn_kernel(
    const u16* __restrict__ Qb, const u16* __restrict__ Kb,
    const u16* __restrict__ Vt, const unsigned char* __restrict__ mask,
    u16* __restrict__ Opart, float2* __restrict__ ml) {
  __shared__ __align__(16) char smem[34816];
  u16* Ktile = (u16*)smem;
  u16* Vtile = Ktile + 8192;
  float* Mb = (float*)(Vtile + 8192);
  // decode swizzled block id: b = cb*8 + r; q-block = cb&7; group g = r*16+(cb>>3)
  const int bflat = blockIdx.x;
  const int r = bflat & 7, cb = bflat >> 3;
  const int q0 = (cb & 7) * 128;
  const int g = r * 16 + (cb >> 3);
  const int bh = g & 31, z = g >> 5;
  const int b = bh >> 4, kv0 = z * SLEN;
  const int tid = threadIdx.x, w = tid >> 6, lane = tid & 63;
  const int fr = lane & 15, fq = lane >> 4, fr7 = fr & 7;
  const u16* Qg = Qb + ((size_t)bh * NQ + q0 + w * 16) * HD;
  const u16* Kg = Kb + (size_t)bh * S * HD;
  const u16* Vg = Vt + (size_t)bh * HD * S;
  const unsigned char* mg = mask + (size_t)b * S + kv0;

  const int rs = tid >> 3, gs = (tid & 7) ^ (rs & 7);

  bf16x8 qf0 = *(const bf16x8*)(Qg + fr * HD + fq * 8);
  bf16x8 qf1 = *(const bf16x8*)(Qg + fr * HD + 32 + fq * 8);

  const int A0 = ((((fq << 1)) & 3) * 16 + fr) << 2;
  const int A1 = ((((fq << 1) + 1) & 3) * 16 + fr) << 2;
  const bool lofq = (fq < 2);

  f32x4 oacc[4] = {};               // O^T: [d = nt*16 + fq*4 + i][q = fr]
  float mrow = -1e30f, lrow = 0.f;  // mrow row-uniform; lrow per-lane partial

  if (tid < 64) Mb[tid] = mg[tid] ? 0.f : -1e30f;
  gload_lds16(Kg + (size_t)(kv0 + rs) * HD + gs * 8, Ktile + tid * 8);
  gload_lds16(Vg + (size_t)rs * S + kv0 + gs * 8, Vtile + tid * 8);
  asm volatile("s_waitcnt vmcnt(0)" ::: "memory");
  __syncthreads();

  int cur = 0;
  for (int kt = 0; kt < SLEN; kt += 64) {
    const int nb = cur ^ 1, kn = kt + 64;
    if (kn < SLEN) {
      if (tid < 64) Mb[nb * 64 + tid] = mg[kn + tid] ? 0.f : -1e30f;
      gload_lds16(Kg + (size_t)(kv0 + kn + rs) * HD + gs * 8, Ktile + nb * 4096 + tid * 8);
      gload_lds16(Vg + (size_t)rs * S + kv0 + kn + gs * 8, Vtile + nb * 4096 + tid * 8);
    }

    const u16* Kc = Ktile + cur * 4096;
    const u16* Vc = Vtile + cur * 4096;

    float sv[4][4];
#pragma unroll
    for (int nt = 0; nt < 4; ++nt) {
      const u16* kb2 = Kc + (nt * 16 + fr) * 64;
      bf16x8 k0v = *(const bf16x8*)(kb2 + ((fq) ^ fr7) * 8);
      bf16x8 k1v = *(const bf16x8*)(kb2 + ((4 + fq) ^ fr7) * 8);
      f32x4 t = {};
      t = __builtin_amdgcn_mfma_f32_16x16x32_bf16(k0v, qf0, t, 0, 0, 0);
      t = __builtin_amdgcn_mfma_f32_16x16x32_bf16(k1v, qf1, t, 0, 0, 0);
      float4 mb = *(const float4*)&Mb[cur * 64 + nt * 16 + fq * 4];
      sv[nt][0] = t[0] + mb.x;
      sv[nt][1] = t[1] + mb.y;
      sv[nt][2] = t[2] + mb.z;
      sv[nt][3] = t[3] + mb.w;
    }

    // in-lane max only; wave-wide __any gates the (rare) rescale path
    float pmax;
    {
      float m0 = fmaxf(fmaxf(sv[0][0], sv[0][1]), fmaxf(sv[0][2], sv[0][3]));
      float m1 = fmaxf(fmaxf(sv[1][0], sv[1][1]), fmaxf(sv[1][2], sv[1][3]));
      float m2 = fmaxf(fmaxf(sv[2][0], sv[2][1]), fmaxf(sv[2][2], sv[2][3]));
      float m3 = fmaxf(fmaxf(sv[3][0], sv[3][1]), fmaxf(sv[3][2], sv[3][3]));
      pmax = fmaxf(fmaxf(m0, m1), fmaxf(m2, m3));
    }
    if (__any(pmax > mrow + 12.f)) {
      pmax = fmaxf(pmax, __shfl_xor(pmax, 16));
      pmax = fmaxf(pmax, __shfl_xor(pmax, 32));
      float nm = fmaxf(mrow, pmax);
      float al = fexp2(mrow - nm);
      mrow = nm;
      lrow *= al;
#pragma unroll
      for (int nt = 0; nt < 4; ++nt)
#pragma unroll
        for (int i = 0; i < 4; ++i) oacc[nt][i] *= al;
    }

    // P = 2^(sv - mrow); lrow accumulates per-lane partial (no cross-lane)
    float p[4][4];
#pragma unroll
    for (int nt = 0; nt < 4; ++nt)
#pragma unroll
      for (int i = 0; i < 4; ++i) p[nt][i] = fexp2(sv[nt][i] - mrow);
    {
      float s0 = (p[0][0] + p[0][1]) + (p[0][2] + p[0][3]);
      float s1 = (p[1][0] + p[1][1]) + (p[1][2] + p[1][3]);
      float s2 = (p[2][0] + p[2][1]) + (p[2][2] + p[2][3]);
      float s3 = (p[3][0] + p[3][1]) + (p[3][2] + p[3][3]);
      lrow += (s0 + s1) + (s2 + s3);
    }

    int pk[4][2];
#pragma unroll
    for (int nt = 0; nt < 4; ++nt) {
      asm("v_cvt_pk_bf16_f32 %0, %1, %2" : "=v"(pk[nt][0]) : "v"(p[nt][0]), "v"(p[nt][1]));
      asm("v_cvt_pk_bf16_f32 %0, %1, %2" : "=v"(pk[nt][1]) : "v"(p[nt][2]), "v"(p[nt][3]));
    }

#pragma unroll
    for (int b2 = 0; b2 < 2; ++b2) {
      int w0a = __builtin_amdgcn_ds_bpermute(A0, pk[2 * b2][0]);
      int w0b = __builtin_amdgcn_ds_bpermute(A0, pk[2 * b2 + 1][0]);
      int w1a = __builtin_amdgcn_ds_bpermute(A0, pk[2 * b2][1]);
      int w1b = __builtin_amdgcn_ds_bpermute(A0, pk[2 * b2 + 1][1]);
      int w2a = __builtin_amdgcn_ds_bpermute(A1, pk[2 * b2][0]);
      int w2b = __builtin_amdgcn_ds_bpermute(A1, pk[2 * b2 + 1][0]);
      int w3a = __builtin_amdgcn_ds_bpermute(A1, pk[2 * b2][1]);
      int w3b = __builtin_amdgcn_ds_bpermute(A1, pk[2 * b2 + 1][1]);
      i32x4 wv;
      wv[0] = lofq ? w0a : w0b;
      wv[1] = lofq ? w1a : w1b;
      wv[2] = lofq ? w2a : w2b;
      wv[3] = lofq ? w3a : w3b;
      bf16x8 pfrag = __builtin_bit_cast(bf16x8, wv);
#pragma unroll
      for (int nt = 0; nt < 4; ++nt) {
        const u16* vb2 = Vc + (nt * 16 + fr) * 64;
        bf16x8 vf = *(const bf16x8*)(vb2 + ((b2 * 4 + fq) ^ fr7) * 8);
        oacc[nt] = __builtin_amdgcn_mfma_f32_16x16x32_bf16(vf, pfrag, oacc[nt], 0, 0, 0);
      }
    }

    asm volatile("s_waitcnt vmcnt(0)" ::: "memory");
    __syncthreads();
    cur = nb;
  }

  // epilogue: reduce lrow across fq lanes, write (m,l), transpose O^T -> [q][d]
  lrow += __shfl_xor(lrow, 16);
  lrow += __shfl_xor(lrow, 32);
  if (fq == 0)
    ml[((size_t)z * 32 + bh) * NQ + q0 + w * 16 + fr] = float2{mrow, lrow};

  float* tb = (float*)smem + w * 1088;  // per-wave 16 x 68 f32
#pragma unroll
  for (int nt = 0; nt < 4; ++nt)
#pragma unroll
    for (int i = 0; i < 4; ++i)
      tb[fr * 68 + nt * 16 + fq * 4 + i] = oacc[nt][i];

  const int qloc = lane >> 2, dl = lane & 3;
  const float* trow = tb + qloc * 68 + dl * 16;
  u16* gdst = Opart + (((size_t)z * 32 + bh) * NQ + q0 + w * 16 + qloc) * 64 + dl * 16;
  u16x8 o0, o1;
#pragma unroll
  for (int j = 0; j < 8; ++j) {
    o0[j] = f2bf(trow[j]);
    o1[j] = f2bf(trow[8 + j]);
  }
  *(u16x8*)gdst = o0;
  *(u16x8*)(gdst + 8) = o1;
}

// ---------------- combine split partials -> bf16 Aout ----------------------
__global__ __launch_bounds__(256) void combine_kernel(
    const u16* __restrict__ Opart, const float2* __restrict__ ml,
    u16* __restrict__ out) {
  const int bh = blockIdx.y, b = bh >> 4, h = bh & 15;
  const int q = blockIdx.x * 64 + (threadIdx.x >> 2);
  const int dl = threadIdx.x & 3;
  float2 mm[NSPLIT];
  float M = -1e30f;
#pragma unroll
  for (int zz = 0; zz < NSPLIT; ++zz) {
    mm[zz] = ml[((size_t)zz * 32 + bh) * NQ + q];
    M = fmaxf(M, mm[zz].x);
  }
  float wz[NSPLIT], lsum = 0.f;
#pragma unroll
  for (int zz = 0; zz < NSPLIT; ++zz) {
    wz[zz] = fexp2(mm[zz].x - M);
    lsum += mm[zz].y * wz[zz];
  }
  const float inv = 1.f / lsum;
  float acc[16] = {};
#pragma unroll
  for (int zz = 0; zz < NSPLIT; ++zz) {
    const u16* op = Opart + (((size_t)zz * 32 + bh) * NQ + q) * 64 + dl * 16;
    u16x8 a0 = *(const u16x8*)op;
    u16x8 a1 = *(const u16x8*)(op + 8);
    float wi = wz[zz] * inv;
#pragma unroll
    for (int j = 0; j < 8; ++j) {
      acc[j] += wi * bf2f(a0[j]);
      acc[8 + j] += wi * bf2f(a1[j]);
    }
  }
  u16* orow = out + ((size_t)b * NQ + q) * H + h * HD + dl * 16;
  u16x8 o0, o1;
#pragma unroll
  for (int j = 0; j < 8; ++j) {
    o0[j] = f2bf(acc[j]);
    o1[j] = f2bf(acc[8 + j]);
  }
  *(u16x8*)orow = o0;
  *(u16x8*)(orow + 8) = o1;
}

// ---------------------------------------------------------------------------
extern "C" void kernel_launch(void* const* d_in, const int* in_sizes, int n_in,
                              void* d_out, int out_size, void* d_ws, size_t ws_size,
                              hipStream_t stream) {
  const float* queries = (const float*)d_in[0];
  const float* keys_values = (const float*)d_in[1];
  const void* amask = d_in[2];
  const float* W_qkv = (const float*)d_in[3];
  const float* b_qkv = (const float*)d_in[4];
  const float* W_out = (const float*)d_in[5];
  const float* b_out = (const float*)d_in[6];
  const float* gamma = (const float*)d_in[7];
  const float* beta = (const float*)d_in[8];

  char* ws = (char*)d_ws;
  unsigned char* maskN = (unsigned char*)ws;                 // 8 KB
  u16* Xq = (u16*)(ws + 8192);                               // [2048][1024]
  u16* Xkv = Xq + (size_t)Bb * NQ * H;                       // [8192][1024]
  u16* Wtq = Xkv + (size_t)Bb * S * H;                       // [3072][1024]
  u16* Wto = Wtq + (size_t)3 * H * H;                        // [1024][1024]
  u16* Qbuf = Wto + (size_t)H * H;                           // [B][NH][NQ][HD]
  u16* Kbuf = Qbuf + (size_t)Bb * NQ * H;                    // [B][NH][S][HD]; V^T follows
  u16* Aout = Kbuf + (size_t)2 * Bb * S * H;                 // [2048][1024]
  // attn partials OVERLAY dead Xq/Xkv region (rewritten by prep each call
  // before GEMMs read them; Opart/ml written after GEMMs consume Xq/Xkv).
  u16* Opart = (u16*)(ws + 8192);                            // 16 MB bf16
  float2* ml = (float2*)((char*)Opart + (size_t)NSPLIT * 32 * NQ * 64 * 2);  // 1 MB

  hipLaunchKernelGGL(prep_kernel, dim3(6657), dim3(256), 0, stream,
                     (const unsigned char*)amask, maskN, queries, keys_values,
                     gamma, beta, Xq, Xkv, W_qkv, W_out, Wtq, Wto);
  hipLaunchKernelGGL(gemm_qkv_kernel, dim3(1152), dim3(256), 0, stream,
                     Xq, Xkv, Wtq, b_qkv, Qbuf, Kbuf);
  hipLaunchKernelGGL(attn_kernel, dim3(NQ / 128 * Bb * NH * NSPLIT), dim3(512), 0, stream,
                     Qbuf, Kbuf, Kbuf + (size_t)Bb * S * H, maskN, Opart, ml);
  hipLaunchKernelGGL(combine_kernel, dim3(NQ / 64, Bb * NH), dim3(256), 0, stream,
                     Opart, ml, Aout);
  hipLaunchKernelGGL(gemm_out_kernel, dim3(H / 128, Bb * NQ / 128), dim3(256), 0, stream,
                     Aout, Wto, b_out, (float*)d_out);
}

// Round 7
// 185.586 us; speedup vs baseline: 1.6874x; 1.0500x over previous
//
#include <hip/hip_runtime.h>
#include <stdint.h>

#define DEVI __device__ __forceinline__

constexpr int Bb = 2, NQ = 1024, S = 4096, H = 1024, NH = 16, HD = 64;
constexpr int NSPLIT = 4, SLEN = S / NSPLIT;

typedef __bf16 bf16x8 __attribute__((ext_vector_type(8)));
typedef float f32x4 __attribute__((ext_vector_type(4)));
typedef int i32x4 __attribute__((ext_vector_type(4)));
typedef unsigned short u16;
typedef u16 u16x8 __attribute__((ext_vector_type(8)));

DEVI u16 f2bf(float f) {
  union { float f; unsigned u; } v; v.f = f;
  unsigned r = (v.u + 0x7fffu + ((v.u >> 16) & 1u)) >> 16;
  return (u16)r;
}

DEVI float bf2f(u16 x) {
  union { unsigned u; float f; } v; v.u = ((unsigned)x) << 16;
  return v.f;
}

DEVI float fexp2(float x) {
#if __has_builtin(__builtin_amdgcn_exp2f)
  return __builtin_amdgcn_exp2f(x);
#else
  return exp2f(x);
#endif
}

DEVI void gload_lds16(const void* g, void* lds) {
  __builtin_amdgcn_global_load_lds(
      (const __attribute__((address_space(1))) void*)(uintptr_t)g,
      (__attribute__((address_space(3))) void*)(uint32_t)(uintptr_t)lds,
      16, 0, 0);
}

// ---------------- fused prep: mask-norm | LN(q) | LN(kv) | W transposes ----
DEVI void ln_body(const float* __restrict__ x, const float* __restrict__ gamma,
                  const float* __restrict__ beta, u16* __restrict__ out, int row) {
  int lane = threadIdx.x & 63;
  const float4* xr = (const float4*)(x + (size_t)row * H);
  float4 v[4];
  float s = 0.f, s2 = 0.f;
#pragma unroll
  for (int i = 0; i < 4; ++i) {
    v[i] = xr[lane + i * 64];
    s += v[i].x + v[i].y + v[i].z + v[i].w;
    s2 += v[i].x * v[i].x + v[i].y * v[i].y + v[i].z * v[i].z + v[i].w * v[i].w;
  }
#pragma unroll
  for (int d = 1; d < 64; d <<= 1) { s += __shfl_xor(s, d); s2 += __shfl_xor(s2, d); }
  float mu = s * (1.f / H);
  float rstd = rsqrtf(s2 * (1.f / H) - mu * mu + 1e-6f);
  u16* orow = out + (size_t)row * H;
  const float4* g4 = (const float4*)gamma;
  const float4* b4 = (const float4*)beta;
#pragma unroll
  for (int i = 0; i < 4; ++i) {
    float4 g = g4[lane + i * 64], bb = b4[lane + i * 64];
    ushort4 o;
    o.x = f2bf((v[i].x - mu) * rstd * g.x + bb.x);
    o.y = f2bf((v[i].y - mu) * rstd * g.y + bb.y);
    o.z = f2bf((v[i].z - mu) * rstd * g.z + bb.z);
    o.w = f2bf((v[i].w - mu) * rstd * g.w + bb.w);
    *(ushort4*)(orow + (size_t)(lane + i * 64) * 4) = o;
  }
}

__global__ __launch_bounds__(256) void prep_kernel(
    const unsigned char* __restrict__ mraw, unsigned char* __restrict__ maskN,
    const float* __restrict__ queries, const float* __restrict__ keys_values,
    const float* __restrict__ gamma, const float* __restrict__ beta,
    u16* __restrict__ Xq, u16* __restrict__ Xkv,
    const float* __restrict__ W_qkv, const float* __restrict__ W_out,
    u16* __restrict__ Wtq, u16* __restrict__ Wto) {
  __shared__ int isByte;
  __shared__ float tile[32][33];
  const int b = blockIdx.x;
  if (b == 0) {
    if (threadIdx.x == 0) isByte = 0;
    __syncthreads();
    int any = 0;
    for (int p = threadIdx.x; p < Bb * S; p += 256)
      if ((p & 3) && mraw[p]) any = 1;
    if (any) atomicOr(&isByte, 1);
    __syncthreads();
    const int bytemode = isByte;
    for (int i = threadIdx.x; i < Bb * S; i += 256) {
      unsigned char v = bytemode ? (unsigned char)(mraw[i] != 0)
                                 : (unsigned char)(((const int*)mraw)[i] != 0);
      maskN[i] = v;
    }
  } else if (b < 513) {
    ln_body(queries, gamma, beta, Xq, (b - 1) * 4 + (threadIdx.x >> 6));
  } else if (b < 2561) {
    ln_body(keys_values, gamma, beta, Xkv, (b - 513) * 4 + (threadIdx.x >> 6));
  } else {
    const float* in; u16* out; int C, t;
    if (b < 5633) { t = b - 2561; in = W_qkv; out = Wtq; C = 3 * H; }
    else          { t = b - 5633; in = W_out; out = Wto; C = H; }
    const int nbx = C / 32;
    int c0 = (t % nbx) * 32, r0 = (t / nbx) * 32;
    int tx = threadIdx.x & 31, ty = threadIdx.x >> 5;
#pragma unroll
    for (int i = 0; i < 32; i += 8)
      tile[ty + i][tx] = in[(size_t)(r0 + ty + i) * C + c0 + tx];
    __syncthreads();
#pragma unroll
    for (int i = 0; i < 32; i += 8)
      out[(size_t)(c0 + ty + i) * H + r0 + tx] = f2bf(tile[tx][ty + i]);
  }
}

// ---------------- GEMM core (128x128 tile, BK=32, single-buffered) ---------
#define GEMM_CORE(Ag, Bg)                                                        \
  f32x4 acc[4][4] = {};                                                          \
  {                                                                              \
    for (int k0 = 0; k0 < 1024; k0 += 32) {                                      \
      gload_lds16(Ag + (size_t)(c0 >> 2) * 1024 + k0 + (c0 & 3) * 8, Ash + c0 * 8); \
      gload_lds16(Ag + (size_t)(c1 >> 2) * 1024 + k0 + (c1 & 3) * 8, Ash + c1 * 8); \
      gload_lds16(Bg + (size_t)(c0 >> 2) * 1024 + k0 + (c0 & 3) * 8, Bsh + c0 * 8); \
      gload_lds16(Bg + (size_t)(c1 >> 2) * 1024 + k0 + (c1 & 3) * 8, Bsh + c1 * 8); \
      asm volatile("s_waitcnt vmcnt(0)" ::: "memory");                           \
      __syncthreads();                                                           \
      bf16x8 af[4], bfr[4];                                                      \
      _Pragma("unroll") for (int m = 0; m < 4; ++m)                              \
          af[m] = *(const bf16x8*)(Ash + (wr + m * 16 + fr) * 32 + fq * 8);      \
      _Pragma("unroll") for (int n = 0; n < 4; ++n)                              \
          bfr[n] = *(const bf16x8*)(Bsh + (wc + n * 16 + fr) * 32 + fq * 8);     \
      _Pragma("unroll") for (int m = 0; m < 4; ++m)                              \
          _Pragma("unroll") for (int n = 0; n < 4; ++n)                          \
              acc[m][n] = __builtin_amdgcn_mfma_f32_16x16x32_bf16(af[m], bfr[n], acc[m][n], 0, 0, 0); \
      __syncthreads();                                                           \
    }                                                                            \
  }

// ---------------- Q projection GEMM (128^2) -> Qbuf bf16, pre-scaled -------
__global__ __launch_bounds__(256) void gemm_q_kernel(
    const u16* __restrict__ Xq, const u16* __restrict__ Wtq,
    const float* __restrict__ bias, u16* __restrict__ Qbuf) {
  __shared__ __align__(16) u16 Ash[128 * 32];
  __shared__ __align__(16) u16 Bsh[128 * 32];
  const int tid = threadIdx.x, w = tid >> 6, lane = tid & 63;
  const int c0 = tid, c1 = tid + 256;
  const int wr = (w >> 1) * 64, wc = (w & 1) * 64;
  const int fr = lane & 15, fq = lane >> 4;
  const int brow = blockIdx.y * 128, bcol = blockIdx.x * 128;
  const u16* Ag = Xq + (size_t)brow * 1024;
  const u16* Bg = Wtq + (size_t)bcol * 1024;
  GEMM_CORE(Ag, Bg)
  constexpr float QSCALE = 0.125f * 1.4426950408889634f;
#pragma unroll
  for (int m = 0; m < 4; ++m)
#pragma unroll
    for (int n = 0; n < 4; ++n) {
      const int c = bcol + wc + n * 16 + fr;
      const int r0 = brow + wr + m * 16 + fq * 4;
#pragma unroll
      for (int i = 0; i < 4; ++i) {
        int r = r0 + i;
        Qbuf[((((size_t)(r >> 10)) * NH + (c >> 6)) * NQ + (r & (NQ - 1))) * HD + (c & 63)] =
            f2bf((acc[m][n][i] + bias[c]) * QSCALE);
      }
    }
}

// ---------------- KV projection GEMM: 256^2 tile, BK=64, 2-phase dbuf ------
// 8 waves (2Mx4N), per-wave 128x64 output. XCD-chunked block map: xcd owns
// 4 contiguous by rows -> A-panel slice (2 MB) stays L2-resident per XCD.
// Schedule per tile: STAGE(next) -> ds_read+MFMA(cur) -> vmcnt(0)+barrier.
__global__ __launch_bounds__(512, 2) void gemm_kv_kernel(
    const u16* __restrict__ Xkv, const u16* __restrict__ WtqKV,
    const float* __restrict__ bias, u16* __restrict__ KVbuf) {
  __shared__ __align__(16) u16 Abuf[2][256 * 64];
  __shared__ __align__(16) u16 Bbuf[2][256 * 64];
  const int tid = threadIdx.x, wid = tid >> 6, lane = tid & 63;
  const int fr = lane & 15, fq = lane >> 4;
  const int wr = (wid >> 2) * 128, wc = (wid & 3) * 64;
  const int bid = blockIdx.x;
  const int xcd = bid & 7, loc = bid >> 3;
  const int by = xcd * 4 + (loc & 3), bx = loc >> 2;  // by:0..31, bx:0..7
  const u16* Ag = Xkv + (size_t)(by * 256) * 1024;
  const u16* Bg = WtqKV + (size_t)(bx * 256) * 1024;

  f32x4 acc[8][4] = {};

  // prologue: stage k-tile 0 into buffer 0
#pragma unroll
  for (int l = 0; l < 4; ++l) {
    int ci = tid + l * 512;
    int row = ci >> 3, ch = ci & 7;
    gload_lds16(Ag + (size_t)row * 1024 + ch * 8, &Abuf[0][ci * 8]);
    gload_lds16(Bg + (size_t)row * 1024 + ch * 8, &Bbuf[0][ci * 8]);
  }
  asm volatile("s_waitcnt vmcnt(0)" ::: "memory");
  __syncthreads();

  for (int t = 0; t < 16; ++t) {
    const int cb = t & 1, nb2 = cb ^ 1;
    if (t < 15) {
      const int k0 = (t + 1) * 64;
#pragma unroll
      for (int l = 0; l < 4; ++l) {
        int ci = tid + l * 512;
        int row = ci >> 3, ch = ci & 7;
        gload_lds16(Ag + (size_t)row * 1024 + k0 + ch * 8, &Abuf[nb2][ci * 8]);
        gload_lds16(Bg + (size_t)row * 1024 + k0 + ch * 8, &Bbuf[nb2][ci * 8]);
      }
    }
#pragma unroll
    for (int ks = 0; ks < 2; ++ks) {
      bf16x8 af[8], bfv[4];
#pragma unroll
      for (int m = 0; m < 8; ++m)
        af[m] = *(const bf16x8*)(&Abuf[cb][(wr + m * 16 + fr) * 64 + ks * 32 + fq * 8]);
#pragma unroll
      for (int n = 0; n < 4; ++n)
        bfv[n] = *(const bf16x8*)(&Bbuf[cb][(wc + n * 16 + fr) * 64 + ks * 32 + fq * 8]);
#pragma unroll
      for (int m = 0; m < 8; ++m)
#pragma unroll
        for (int n = 0; n < 4; ++n)
          acc[m][n] = __builtin_amdgcn_mfma_f32_16x16x32_bf16(af[m], bfv[n], acc[m][n], 0, 0, 0);
    }
    asm volatile("s_waitcnt vmcnt(0)" ::: "memory");
    __syncthreads();
  }

  // epilogue: c<1024 -> K [B][NH][S][HD]; c>=1024 -> V^T [B][NH][HD][S]
#pragma unroll
  for (int m = 0; m < 8; ++m)
#pragma unroll
    for (int n = 0; n < 4; ++n) {
      const int c = bx * 256 + wc + n * 16 + fr;
      const int r0 = by * 256 + wr + m * 16 + fq * 4;
      const float bv = bias[c];
      if (c >= 1024) {
        int bb = r0 >> 12, kv = r0 & (S - 1);
        int cc = c - 1024, head = cc >> 6, d = cc & 63;
        ushort4 o;
        o.x = f2bf(acc[m][n][0] + bv);
        o.y = f2bf(acc[m][n][1] + bv);
        o.z = f2bf(acc[m][n][2] + bv);
        o.w = f2bf(acc[m][n][3] + bv);
        u16* vb = KVbuf + (size_t)Bb * NH * S * HD;
        *(ushort4*)(vb + (((size_t)(bb * NH + head)) * HD + d) * S + kv) = o;
      } else {
#pragma unroll
        for (int i = 0; i < 4; ++i) {
          int r = r0 + i;
          KVbuf[((((size_t)(r >> 12)) * NH + (c >> 6)) * S + (r & (S - 1))) * HD + (c & 63)] =
              f2bf(acc[m][n][i] + bv);
        }
      }
    }
}

// ---------------- output projection GEMM -> f32 d_out ----------------------
__global__ __launch_bounds__(256) void gemm_out_kernel(
    const u16* __restrict__ A, const u16* __restrict__ Bt,
    const float* __restrict__ bias, float* __restrict__ outp) {
  __shared__ __align__(16) u16 Ash[128 * 32];
  __shared__ __align__(16) u16 Bsh[128 * 32];
  const int tid = threadIdx.x, w = tid >> 6, lane = tid & 63;
  const int c0 = tid, c1 = tid + 256;
  const int wr = (w >> 1) * 64, wc = (w & 1) * 64;
  const int fr = lane & 15, fq = lane >> 4;
  const int brow = blockIdx.y * 128, bcol = blockIdx.x * 128;
  const u16* Ag = A + (size_t)brow * 1024;
  const u16* Bg = Bt + (size_t)bcol * 1024;
  GEMM_CORE(Ag, Bg)
#pragma unroll
  for (int m = 0; m < 4; ++m)
#pragma unroll
    for (int n = 0; n < 4; ++n) {
      const int c = bcol + wc + n * 16 + fr;
      const int r0 = brow + wr + m * 16 + fq * 4;
#pragma unroll
      for (int i = 0; i < 4; ++i)
        outp[(size_t)(r0 + i) * H + c] = acc[m][n][i] + bias[c];
    }
}

// ---------------- flash attention, 8 waves, QBLK=128, split-S=4 ------------
__global__ __launch_bounds__(512, 4) void attn_kernel(
    const u16* __restrict__ Qb, const u16* __restrict__ Kb,
    const u16* __restrict__ Vt, const unsigned char* __restrict__ mask,
    u16* __restrict__ Opart, float2* __restrict__ ml) {
  __shared__ __align__(16) char smem[34816];
  u16* Ktile = (u16*)smem;
  u16* Vtile = Ktile + 8192;
  float* Mb = (float*)(Vtile + 8192);
  const int bflat = blockIdx.x;
  const int r = bflat & 7, cb = bflat >> 3;
  const int q0 = (cb & 7) * 128;
  const int g = r * 16 + (cb >> 3);
  const int bh = g & 31, z = g >> 5;
  const int b = bh >> 4, kv0 = z * SLEN;
  const int tid = threadIdx.x, w = tid >> 6, lane = tid & 63;
  const int fr = lane & 15, fq = lane >> 4, fr7 = fr & 7;
  const u16* Qg = Qb + ((size_t)bh * NQ + q0 + w * 16) * HD;
  const u16* Kg = Kb + (size_t)bh * S * HD;
  const u16* Vg = Vt + (size_t)bh * HD * S;
  const unsigned char* mg = mask + (size_t)b * S + kv0;

  const int rs = tid >> 3, gs = (tid & 7) ^ (rs & 7);

  bf16x8 qf0 = *(const bf16x8*)(Qg + fr * HD + fq * 8);
  bf16x8 qf1 = *(const bf16x8*)(Qg + fr * HD + 32 + fq * 8);

  const int A0 = ((((fq << 1)) & 3) * 16 + fr) << 2;
  const int A1 = ((((fq << 1) + 1) & 3) * 16 + fr) << 2;
  const bool lofq = (fq < 2);

  f32x4 oacc[4] = {};
  float mrow = -1e30f, lrow = 0.f;

  if (tid < 64) Mb[tid] = mg[tid] ? 0.f : -1e30f;
  gload_lds16(Kg + (size_t)(kv0 + rs) * HD + gs * 8, Ktile + tid * 8);
  gload_lds16(Vg + (size_t)rs * S + kv0 + gs * 8, Vtile + tid * 8);
  asm volatile("s_waitcnt vmcnt(0)" ::: "memory");
  __syncthreads();

  int cur = 0;
  for (int kt = 0; kt < SLEN; kt += 64) {
    const int nb = cur ^ 1, kn = kt + 64;
    if (kn < SLEN) {
      if (tid < 64) Mb[nb * 64 + tid] = mg[kn + tid] ? 0.f : -1e30f;
      gload_lds16(Kg + (size_t)(kv0 + kn + rs) * HD + gs * 8, Ktile + nb * 4096 + tid * 8);
      gload_lds16(Vg + (size_t)rs * S + kv0 + kn + gs * 8, Vtile + nb * 4096 + tid * 8);
    }

    const u16* Kc = Ktile + cur * 4096;
    const u16* Vc = Vtile + cur * 4096;

    float sv[4][4];
#pragma unroll
    for (int nt = 0; nt < 4; ++nt) {
      const u16* kb2 = Kc + (nt * 16 + fr) * 64;
      bf16x8 k0v = *(const bf16x8*)(kb2 + ((fq) ^ fr7) * 8);
      bf16x8 k1v = *(const bf16x8*)(kb2 + ((4 + fq) ^ fr7) * 8);
      f32x4 t = {};
      t = __builtin_amdgcn_mfma_f32_16x16x32_bf16(k0v, qf0, t, 0, 0, 0);
      t = __builtin_amdgcn_mfma_f32_16x16x32_bf16(k1v, qf1, t, 0, 0, 0);
      float4 mb = *(const float4*)&Mb[cur * 64 + nt * 16 + fq * 4];
      sv[nt][0] = t[0] + mb.x;
      sv[nt][1] = t[1] + mb.y;
      sv[nt][2] = t[2] + mb.z;
      sv[nt][3] = t[3] + mb.w;
    }

    float pmax;
    {
      float m0 = fmaxf(fmaxf(sv[0][0], sv[0][1]), fmaxf(sv[0][2], sv[0][3]));
      float m1 = fmaxf(fmaxf(sv[1][0], sv[1][1]), fmaxf(sv[1][2], sv[1][3]));
      float m2 = fmaxf(fmaxf(sv[2][0], sv[2][1]), fmaxf(sv[2][2], sv[2][3]));
      float m3 = fmaxf(fmaxf(sv[3][0], sv[3][1]), fmaxf(sv[3][2], sv[3][3]));
      pmax = fmaxf(fmaxf(m0, m1), fmaxf(m2, m3));
    }
    if (__any(pmax > mrow + 12.f)) {
      pmax = fmaxf(pmax, __shfl_xor(pmax, 16));
      pmax = fmaxf(pmax, __shfl_xor(pmax, 32));
      float nm = fmaxf(mrow, pmax);
      float al = fexp2(mrow - nm);
      mrow = nm;
      lrow *= al;
#pragma unroll
      for (int nt = 0; nt < 4; ++nt)
#pragma unroll
        for (int i = 0; i < 4; ++i) oacc[nt][i] *= al;
    }

    float p[4][4];
#pragma unroll
    for (int nt = 0; nt < 4; ++nt)
#pragma unroll
      for (int i = 0; i < 4; ++i) p[nt][i] = fexp2(sv[nt][i] - mrow);
    {
      float s0 = (p[0][0] + p[0][1]) + (p[0][2] + p[0][3]);
      float s1 = (p[1][0] + p[1][1]) + (p[1][2] + p[1][3]);
      float s2 = (p[2][0] + p[2][1]) + (p[2][2] + p[2][3]);
      float s3 = (p[3][0] + p[3][1]) + (p[3][2] + p[3][3]);
      lrow += (s0 + s1) + (s2 + s3);
    }

    int pk[4][2];
#pragma unroll
    for (int nt = 0; nt < 4; ++nt) {
      asm("v_cvt_pk_bf16_f32 %0, %1, %2" : "=v"(pk[nt][0]) : "v"(p[nt][0]), "v"(p[nt][1]));
      asm("v_cvt_pk_bf16_f32 %0, %1, %2" : "=v"(pk[nt][1]) : "v"(p[nt][2]), "v"(p[nt][3]));
    }

#pragma unroll
    for (int b2 = 0; b2 < 2; ++b2) {
      int w0a = __builtin_amdgcn_ds_bpermute(A0, pk[2 * b2][0]);
      int w0b = __builtin_amdgcn_ds_bpermute(A0, pk[2 * b2 + 1][0]);
      int w1a = __builtin_amdgcn_ds_bpermute(A0, pk[2 * b2][1]);
      int w1b = __builtin_amdgcn_ds_bpermute(A0, pk[2 * b2 + 1][1]);
      int w2a = __builtin_amdgcn_ds_bpermute(A1, pk[2 * b2][0]);
      int w2b = __builtin_amdgcn_ds_bpermute(A1, pk[2 * b2 + 1][0]);
      int w3a = __builtin_amdgcn_ds_bpermute(A1, pk[2 * b2][1]);
      int w3b = __builtin_amdgcn_ds_bpermute(A1, pk[2 * b2 + 1][1]);
      i32x4 wv;
      wv[0] = lofq ? w0a : w0b;
      wv[1] = lofq ? w1a : w1b;
      wv[2] = lofq ? w2a : w2b;
      wv[3] = lofq ? w3a : w3b;
      bf16x8 pfrag = __builtin_bit_cast(bf16x8, wv);
#pragma unroll
      for (int nt = 0; nt < 4; ++nt) {
        const u16* vb2 = Vc + (nt * 16 + fr) * 64;
        bf16x8 vf = *(const bf16x8*)(vb2 + ((b2 * 4 + fq) ^ fr7) * 8);
        oacc[nt] = __builtin_amdgcn_mfma_f32_16x16x32_bf16(vf, pfrag, oacc[nt], 0, 0, 0);
      }
    }

    asm volatile("s_waitcnt vmcnt(0)" ::: "memory");
    __syncthreads();
    cur = nb;
  }

  lrow += __shfl_xor(lrow, 16);
  lrow += __shfl_xor(lrow, 32);
  if (fq == 0)
    ml[((size_t)z * 32 + bh) * NQ + q0 + w * 16 + fr] = float2{mrow, lrow};

  float* tb = (float*)smem + w * 1088;
#pragma unroll
  for (int nt = 0; nt < 4; ++nt)
#pragma unroll
    for (int i = 0; i < 4; ++i)
      tb[fr * 68 + nt * 16 + fq * 4 + i] = oacc[nt][i];

  const int qloc = lane >> 2, dl = lane & 3;
  const float* trow = tb + qloc * 68 + dl * 16;
  u16* gdst = Opart + (((size_t)z * 32 + bh) * NQ + q0 + w * 16 + qloc) * 64 + dl * 16;
  u16x8 o0, o1;
#pragma unroll
  for (int j = 0; j < 8; ++j) {
    o0[j] = f2bf(trow[j]);
    o1[j] = f2bf(trow[8 + j]);
  }
  *(u16x8*)gdst = o0;
  *(u16x8*)(gdst + 8) = o1;
}

// ---------------- combine split partials -> bf16 Aout ----------------------
__global__ __launch_bounds__(256) void combine_kernel(
    const u16* __restrict__ Opart, const float2* __restrict__ ml,
    u16* __restrict__ out) {
  const int bh = blockIdx.y, b = bh >> 4, h = bh & 15;
  const int q = blockIdx.x * 64 + (threadIdx.x >> 2);
  const int dl = threadIdx.x & 3;
  float2 mm[NSPLIT];
  float M = -1e30f;
#pragma unroll
  for (int zz = 0; zz < NSPLIT; ++zz) {
    mm[zz] = ml[((size_t)zz * 32 + bh) * NQ + q];
    M = fmaxf(M, mm[zz].x);
  }
  float wz[NSPLIT], lsum = 0.f;
#pragma unroll
  for (int zz = 0; zz < NSPLIT; ++zz) {
    wz[zz] = fexp2(mm[zz].x - M);
    lsum += mm[zz].y * wz[zz];
  }
  const float inv = 1.f / lsum;
  float acc[16] = {};
#pragma unroll
  for (int zz = 0; zz < NSPLIT; ++zz) {
    const u16* op = Opart + (((size_t)zz * 32 + bh) * NQ + q) * 64 + dl * 16;
    u16x8 a0 = *(const u16x8*)op;
    u16x8 a1 = *(const u16x8*)(op + 8);
    float wi = wz[zz] * inv;
#pragma unroll
    for (int j = 0; j < 8; ++j) {
      acc[j] += wi * bf2f(a0[j]);
      acc[8 + j] += wi * bf2f(a1[j]);
    }
  }
  u16* orow = out + ((size_t)b * NQ + q) * H + h * HD + dl * 16;
  u16x8 o0, o1;
#pragma unroll
  for (int j = 0; j < 8; ++j) {
    o0[j] = f2bf(acc[j]);
    o1[j] = f2bf(acc[8 + j]);
  }
  *(u16x8*)orow = o0;
  *(u16x8*)(orow + 8) = o1;
}

// ---------------------------------------------------------------------------
extern "C" void kernel_launch(void* const* d_in, const int* in_sizes, int n_in,
                              void* d_out, int out_size, void* d_ws, size_t ws_size,
                              hipStream_t stream) {
  const float* queries = (const float*)d_in[0];
  const float* keys_values = (const float*)d_in[1];
  const void* amask = d_in[2];
  const float* W_qkv = (const float*)d_in[3];
  const float* b_qkv = (const float*)d_in[4];
  const float* W_out = (const float*)d_in[5];
  const float* b_out = (const float*)d_in[6];
  const float* gamma = (const float*)d_in[7];
  const float* beta = (const float*)d_in[8];

  char* ws = (char*)d_ws;
  unsigned char* maskN = (unsigned char*)ws;                 // 8 KB
  u16* Xq = (u16*)(ws + 8192);                               // [2048][1024]
  u16* Xkv = Xq + (size_t)Bb * NQ * H;                       // [8192][1024]
  u16* Wtq = Xkv + (size_t)Bb * S * H;                       // [3072][1024]
  u16* Wto = Wtq + (size_t)3 * H * H;                        // [1024][1024]
  u16* Qbuf = Wto + (size_t)H * H;                           // [B][NH][NQ][HD]
  u16* Kbuf = Qbuf + (size_t)Bb * NQ * H;                    // [B][NH][S][HD]; V^T follows
  u16* Aout = Kbuf + (size_t)2 * Bb * S * H;                 // [2048][1024]
  // attn partials OVERLAY dead Xq/Xkv region (rewritten by prep each call
  // before GEMMs read them; Opart/ml written after GEMMs consume Xq/Xkv).
  u16* Opart = (u16*)(ws + 8192);                            // 16 MB bf16
  float2* ml = (float2*)((char*)Opart + (size_t)NSPLIT * 32 * NQ * 64 * 2);  // 1 MB

  hipLaunchKernelGGL(prep_kernel, dim3(6657), dim3(256), 0, stream,
                     (const unsigned char*)amask, maskN, queries, keys_values,
                     gamma, beta, Xq, Xkv, W_qkv, W_out, Wtq, Wto);
  hipLaunchKernelGGL(gemm_q_kernel, dim3(8, 16), dim3(256), 0, stream,
                     Xq, Wtq, b_qkv, Qbuf);
  hipLaunchKernelGGL(gemm_kv_kernel, dim3(256), dim3(512), 0, stream,
                     Xkv, Wtq + (size_t)H * H, b_qkv + H, Kbuf);
  hipLaunchKernelGGL(attn_kernel, dim3(NQ / 128 * Bb * NH * NSPLIT), dim3(512), 0, stream,
                     Qbuf, Kbuf, Kbuf + (size_t)Bb * S * H, maskN, Opart, ml);
  hipLaunchKernelGGL(combine_kernel, dim3(NQ / 64, Bb * NH), dim3(256), 0, stream,
                     Opart, ml, Aout);
  hipLaunchKernelGGL(gemm_out_kernel, dim3(H / 128, Bb * NQ / 128), dim3(256), 0, stream,
                     Aout, Wto, b_out, (float*)d_out);
}

// Round 8
// 179.949 us; speedup vs baseline: 1.7402x; 1.0313x over previous
//
#include <hip/hip_runtime.h>
#include <stdint.h>

#define DEVI __device__ __forceinline__

constexpr int Bb = 2, NQ = 1024, S = 4096, H = 1024, NH = 16, HD = 64;
constexpr int NSPLIT = 4, SLEN = S / NSPLIT;

typedef __bf16 bf16x8 __attribute__((ext_vector_type(8)));
typedef float f32x4 __attribute__((ext_vector_type(4)));
typedef int i32x4 __attribute__((ext_vector_type(4)));
typedef unsigned short u16;
typedef u16 u16x8 __attribute__((ext_vector_type(8)));

DEVI u16 f2bf(float f) {
  union { float f; unsigned u; } v; v.f = f;
  unsigned r = (v.u + 0x7fffu + ((v.u >> 16) & 1u)) >> 16;
  return (u16)r;
}

DEVI float bf2f(u16 x) {
  union { unsigned u; float f; } v; v.u = ((unsigned)x) << 16;
  return v.f;
}

DEVI float fexp2(float x) {
#if __has_builtin(__builtin_amdgcn_exp2f)
  return __builtin_amdgcn_exp2f(x);
#else
  return exp2f(x);
#endif
}

DEVI void gload_lds16(const void* g, void* lds) {
  __builtin_amdgcn_global_load_lds(
      (const __attribute__((address_space(1))) void*)(uintptr_t)g,
      (__attribute__((address_space(3))) void*)(uint32_t)(uintptr_t)lds,
      16, 0, 0);
}

// ---------------- fused prep: mask-norm | LN(q) | LN(kv) | W transposes ----
DEVI void ln_body(const float* __restrict__ x, const float* __restrict__ gamma,
                  const float* __restrict__ beta, u16* __restrict__ out, int row) {
  int lane = threadIdx.x & 63;
  const float4* xr = (const float4*)(x + (size_t)row * H);
  float4 v[4];
  float s = 0.f, s2 = 0.f;
#pragma unroll
  for (int i = 0; i < 4; ++i) {
    v[i] = xr[lane + i * 64];
    s += v[i].x + v[i].y + v[i].z + v[i].w;
    s2 += v[i].x * v[i].x + v[i].y * v[i].y + v[i].z * v[i].z + v[i].w * v[i].w;
  }
#pragma unroll
  for (int d = 1; d < 64; d <<= 1) { s += __shfl_xor(s, d); s2 += __shfl_xor(s2, d); }
  float mu = s * (1.f / H);
  float rstd = rsqrtf(s2 * (1.f / H) - mu * mu + 1e-6f);
  u16* orow = out + (size_t)row * H;
  const float4* g4 = (const float4*)gamma;
  const float4* b4 = (const float4*)beta;
#pragma unroll
  for (int i = 0; i < 4; ++i) {
    float4 g = g4[lane + i * 64], bb = b4[lane + i * 64];
    ushort4 o;
    o.x = f2bf((v[i].x - mu) * rstd * g.x + bb.x);
    o.y = f2bf((v[i].y - mu) * rstd * g.y + bb.y);
    o.z = f2bf((v[i].z - mu) * rstd * g.z + bb.z);
    o.w = f2bf((v[i].w - mu) * rstd * g.w + bb.w);
    *(ushort4*)(orow + (size_t)(lane + i * 64) * 4) = o;
  }
}

__global__ __launch_bounds__(256) void prep_kernel(
    const unsigned char* __restrict__ mraw, unsigned char* __restrict__ maskN,
    const float* __restrict__ queries, const float* __restrict__ keys_values,
    const float* __restrict__ gamma, const float* __restrict__ beta,
    u16* __restrict__ Xq, u16* __restrict__ Xkv,
    const float* __restrict__ W_qkv, const float* __restrict__ W_out,
    u16* __restrict__ Wtq, u16* __restrict__ Wto) {
  __shared__ int isByte;
  __shared__ float tile[32][33];
  const int b = blockIdx.x;
  if (b == 0) {
    if (threadIdx.x == 0) isByte = 0;
    __syncthreads();
    int any = 0;
    for (int p = threadIdx.x; p < Bb * S; p += 256)
      if ((p & 3) && mraw[p]) any = 1;
    if (any) atomicOr(&isByte, 1);
    __syncthreads();
    const int bytemode = isByte;
    for (int i = threadIdx.x; i < Bb * S; i += 256) {
      unsigned char v = bytemode ? (unsigned char)(mraw[i] != 0)
                                 : (unsigned char)(((const int*)mraw)[i] != 0);
      maskN[i] = v;
    }
  } else if (b < 513) {
    ln_body(queries, gamma, beta, Xq, (b - 1) * 4 + (threadIdx.x >> 6));
  } else if (b < 2561) {
    ln_body(keys_values, gamma, beta, Xkv, (b - 513) * 4 + (threadIdx.x >> 6));
  } else {
    const float* in; u16* out; int C, t;
    if (b < 5633) { t = b - 2561; in = W_qkv; out = Wtq; C = 3 * H; }
    else          { t = b - 5633; in = W_out; out = Wto; C = H; }
    const int nbx = C / 32;
    int c0 = (t % nbx) * 32, r0 = (t / nbx) * 32;
    int tx = threadIdx.x & 31, ty = threadIdx.x >> 5;
#pragma unroll
    for (int i = 0; i < 32; i += 8)
      tile[ty + i][tx] = in[(size_t)(r0 + ty + i) * C + c0 + tx];
    __syncthreads();
#pragma unroll
    for (int i = 0; i < 32; i += 8)
      out[(size_t)(c0 + ty + i) * H + r0 + tx] = f2bf(tile[tx][ty + i]);
  }
}

// ---------------- GEMM core (128x128 tile, BK=32, single-buffered) ---------
#define GEMM_CORE(Ag, Bg)                                                        \
  f32x4 acc[4][4] = {};                                                          \
  {                                                                              \
    for (int k0 = 0; k0 < 1024; k0 += 32) {                                      \
      gload_lds16(Ag + (size_t)(c0 >> 2) * 1024 + k0 + (c0 & 3) * 8, Ash + c0 * 8); \
      gload_lds16(Ag + (size_t)(c1 >> 2) * 1024 + k0 + (c1 & 3) * 8, Ash + c1 * 8); \
      gload_lds16(Bg + (size_t)(c0 >> 2) * 1024 + k0 + (c0 & 3) * 8, Bsh + c0 * 8); \
      gload_lds16(Bg + (size_t)(c1 >> 2) * 1024 + k0 + (c1 & 3) * 8, Bsh + c1 * 8); \
      asm volatile("s_waitcnt vmcnt(0)" ::: "memory");                           \
      __syncthreads();                                                           \
      bf16x8 af[4], bfr[4];                                                      \
      _Pragma("unroll") for (int m = 0; m < 4; ++m)                              \
          af[m] = *(const bf16x8*)(Ash + (wr + m * 16 + fr) * 32 + fq * 8);      \
      _Pragma("unroll") for (int n = 0; n < 4; ++n)                              \
          bfr[n] = *(const bf16x8*)(Bsh + (wc + n * 16 + fr) * 32 + fq * 8);     \
      _Pragma("unroll") for (int m = 0; m < 4; ++m)                              \
          _Pragma("unroll") for (int n = 0; n < 4; ++n)                          \
              acc[m][n] = __builtin_amdgcn_mfma_f32_16x16x32_bf16(af[m], bfr[n], acc[m][n], 0, 0, 0); \
      __syncthreads();                                                           \
    }                                                                            \
  }

// ---------------- Q projection GEMM (128^2) -> Qbuf bf16, pre-scaled -------
__global__ __launch_bounds__(256) void gemm_q_kernel(
    const u16* __restrict__ Xq, const u16* __restrict__ Wtq,
    const float* __restrict__ bias, u16* __restrict__ Qbuf) {
  __shared__ __align__(16) u16 Ash[128 * 32];
  __shared__ __align__(16) u16 Bsh[128 * 32];
  const int tid = threadIdx.x, w = tid >> 6, lane = tid & 63;
  const int c0 = tid, c1 = tid + 256;
  const int wr = (w >> 1) * 64, wc = (w & 1) * 64;
  const int fr = lane & 15, fq = lane >> 4;
  const int brow = blockIdx.y * 128, bcol = blockIdx.x * 128;
  const u16* Ag = Xq + (size_t)brow * 1024;
  const u16* Bg = Wtq + (size_t)bcol * 1024;
  GEMM_CORE(Ag, Bg)
  constexpr float QSCALE = 0.125f * 1.4426950408889634f;
#pragma unroll
  for (int m = 0; m < 4; ++m)
#pragma unroll
    for (int n = 0; n < 4; ++n) {
      const int c = bcol + wc + n * 16 + fr;
      const int r0 = brow + wr + m * 16 + fq * 4;
#pragma unroll
      for (int i = 0; i < 4; ++i) {
        int r = r0 + i;
        Qbuf[((((size_t)(r >> 10)) * NH + (c >> 6)) * NQ + (r & (NQ - 1))) * HD + (c & 63)] =
            f2bf((acc[m][n][i] + bias[c]) * QSCALE);
      }
    }
}

// ---------------- KV projection GEMM: 256^2, BK=32, 4-buffer counted-vmcnt -
// 8 waves (2Mx4N), per-wave 128x64 output. XCD-chunked block map (A-panel
// L2-resident per XCD). Ring: stage tile t+3 after iter-t barrier (race-free:
// buf[(t+3)&3] = buf[(t-1)&3], whose readers all passed this barrier).
// Steady-state s_waitcnt vmcnt(8): 2 tiles x 4 loads stay in flight across
// barriers (T3/T4). LDS chunk swizzle ch^((row>>1)&3): 16 lanes -> 8 slots,
// 2-way = free (T2). setprio around MFMA cluster (T5).
__global__ __launch_bounds__(512, 2) void gemm_kv_kernel(
    const u16* __restrict__ Xkv, const u16* __restrict__ WtqKV,
    const float* __restrict__ bias, u16* __restrict__ KVbuf) {
  __shared__ __align__(16) u16 Abuf[4][256 * 32];
  __shared__ __align__(16) u16 Bbuf[4][256 * 32];
  const int tid = threadIdx.x, wid = tid >> 6, lane = tid & 63;
  const int fr = lane & 15, fq = lane >> 4;
  const int wr = (wid >> 2) * 128, wc = (wid & 3) * 64;
  const int bid = blockIdx.x;
  const int xcd = bid & 7, loc = bid >> 3;
  const int by = xcd * 4 + (loc & 3), bx = loc >> 2;  // by:0..31, bx:0..7
  const u16* Ag = Xkv + (size_t)(by * 256) * 1024;
  const u16* Bg = WtqKV + (size_t)(bx * 256) * 1024;

  f32x4 acc[8][4] = {};

  auto stage = [&](int tt) {
    const int k0 = tt * 32;
    u16* Ad = &Abuf[tt & 3][0];
    u16* Bd = &Bbuf[tt & 3][0];
#pragma unroll
    for (int l = 0; l < 2; ++l) {
      int ci = tid + l * 512;
      int row = ci >> 2, ch = ci & 3;
      int chs = ch ^ ((row >> 1) & 3);
      gload_lds16(Ag + (size_t)row * 1024 + k0 + chs * 8, Ad + ci * 8);
      gload_lds16(Bg + (size_t)row * 1024 + k0 + chs * 8, Bd + ci * 8);
    }
  };

#define KV_ITER(T, VM)                                                          \
  {                                                                             \
    asm volatile("s_waitcnt vmcnt(" #VM ")" ::: "memory");                      \
    __syncthreads();                                                            \
    const u16* Ac = &Abuf[(T) & 3][0];                                          \
    const u16* Bc = &Bbuf[(T) & 3][0];                                          \
    bf16x8 af[8], bfv[4];                                                       \
    _Pragma("unroll") for (int m = 0; m < 8; ++m) {                             \
      int row = wr + m * 16 + fr;                                               \
      af[m] = *(const bf16x8*)(Ac + row * 32 + (fq ^ ((row >> 1) & 3)) * 8);    \
    }                                                                           \
    _Pragma("unroll") for (int n = 0; n < 4; ++n) {                             \
      int row = wc + n * 16 + fr;                                               \
      bfv[n] = *(const bf16x8*)(Bc + row * 32 + (fq ^ ((row >> 1) & 3)) * 8);   \
    }                                                                           \
    if ((T) + 3 < 32) stage((T) + 3);                                           \
    __builtin_amdgcn_s_setprio(1);                                              \
    _Pragma("unroll") for (int m = 0; m < 8; ++m)                               \
      _Pragma("unroll") for (int n = 0; n < 4; ++n)                             \
        acc[m][n] = __builtin_amdgcn_mfma_f32_16x16x32_bf16(af[m], bfv[n], acc[m][n], 0, 0, 0); \
    __builtin_amdgcn_s_setprio(0);                                              \
  }

  // prologue: stage tiles 0,1,2 (12 per-thread loads in flight)
  stage(0);
  stage(1);
  stage(2);
  for (int t = 0; t < 29; ++t) KV_ITER(t, 8)
  KV_ITER(29, 8)
  KV_ITER(30, 4)
  KV_ITER(31, 0)
#undef KV_ITER

  // epilogue: c<1024 -> K [B][NH][S][HD]; c>=1024 -> V^T [B][NH][HD][S]
#pragma unroll
  for (int m = 0; m < 8; ++m)
#pragma unroll
    for (int n = 0; n < 4; ++n) {
      const int c = bx * 256 + wc + n * 16 + fr;
      const int r0 = by * 256 + wr + m * 16 + fq * 4;
      const float bv = bias[c];
      if (c >= 1024) {
        int bb = r0 >> 12, kv = r0 & (S - 1);
        int cc = c - 1024, head = cc >> 6, d = cc & 63;
        ushort4 o;
        o.x = f2bf(acc[m][n][0] + bv);
        o.y = f2bf(acc[m][n][1] + bv);
        o.z = f2bf(acc[m][n][2] + bv);
        o.w = f2bf(acc[m][n][3] + bv);
        u16* vb = KVbuf + (size_t)Bb * NH * S * HD;
        *(ushort4*)(vb + (((size_t)(bb * NH + head)) * HD + d) * S + kv) = o;
      } else {
#pragma unroll
        for (int i = 0; i < 4; ++i) {
          int r = r0 + i;
          KVbuf[((((size_t)(r >> 12)) * NH + (c >> 6)) * S + (r & (S - 1))) * HD + (c & 63)] =
              f2bf(acc[m][n][i] + bv);
        }
      }
    }
}

// ---------------- output projection GEMM -> f32 d_out ----------------------
__global__ __launch_bounds__(256) void gemm_out_kernel(
    const u16* __restrict__ A, const u16* __restrict__ Bt,
    const float* __restrict__ bias, float* __restrict__ outp) {
  __shared__ __align__(16) u16 Ash[128 * 32];
  __shared__ __align__(16) u16 Bsh[128 * 32];
  const int tid = threadIdx.x, w = tid >> 6, lane = tid & 63;
  const int c0 = tid, c1 = tid + 256;
  const int wr = (w >> 1) * 64, wc = (w & 1) * 64;
  const int fr = lane & 15, fq = lane >> 4;
  const int brow = blockIdx.y * 128, bcol = blockIdx.x * 128;
  const u16* Ag = A + (size_t)brow * 1024;
  const u16* Bg = Bt + (size_t)bcol * 1024;
  GEMM_CORE(Ag, Bg)
#pragma unroll
  for (int m = 0; m < 4; ++m)
#pragma unroll
    for (int n = 0; n < 4; ++n) {
      const int c = bcol + wc + n * 16 + fr;
      const int r0 = brow + wr + m * 16 + fq * 4;
#pragma unroll
      for (int i = 0; i < 4; ++i)
        outp[(size_t)(r0 + i) * H + c] = acc[m][n][i] + bias[c];
    }
}

// ---------------- flash attention, 8 waves, QBLK=128, split-S=4 ------------
__global__ __launch_bounds__(512, 4) void attn_kernel(
    const u16* __restrict__ Qb, const u16* __restrict__ Kb,
    const u16* __restrict__ Vt, const unsigned char* __restrict__ mask,
    u16* __restrict__ Opart, float2* __restrict__ ml) {
  __shared__ __align__(16) char smem[34816];
  u16* Ktile = (u16*)smem;
  u16* Vtile = Ktile + 8192;
  float* Mb = (float*)(Vtile + 8192);
  const int bflat = blockIdx.x;
  const int r = bflat & 7, cb = bflat >> 3;
  const int q0 = (cb & 7) * 128;
  const int g = r * 16 + (cb >> 3);
  const int bh = g & 31, z = g >> 5;
  const int b = bh >> 4, kv0 = z * SLEN;
  const int tid = threadIdx.x, w = tid >> 6, lane = tid & 63;
  const int fr = lane & 15, fq = lane >> 4, fr7 = fr & 7;
  const u16* Qg = Qb + ((size_t)bh * NQ + q0 + w * 16) * HD;
  const u16* Kg = Kb + (size_t)bh * S * HD;
  const u16* Vg = Vt + (size_t)bh * HD * S;
  const unsigned char* mg = mask + (size_t)b * S + kv0;

  const int rs = tid >> 3, gs = (tid & 7) ^ (rs & 7);

  bf16x8 qf0 = *(const bf16x8*)(Qg + fr * HD + fq * 8);
  bf16x8 qf1 = *(const bf16x8*)(Qg + fr * HD + 32 + fq * 8);

  const int A0 = ((((fq << 1)) & 3) * 16 + fr) << 2;
  const int A1 = ((((fq << 1) + 1) & 3) * 16 + fr) << 2;
  const bool lofq = (fq < 2);

  f32x4 oacc[4] = {};
  float mrow = -1e30f, lrow = 0.f;

  if (tid < 64) Mb[tid] = mg[tid] ? 0.f : -1e30f;
  gload_lds16(Kg + (size_t)(kv0 + rs) * HD + gs * 8, Ktile + tid * 8);
  gload_lds16(Vg + (size_t)rs * S + kv0 + gs * 8, Vtile + tid * 8);
  asm volatile("s_waitcnt vmcnt(0)" ::: "memory");
  __syncthreads();

  int cur = 0;
  for (int kt = 0; kt < SLEN; kt += 64) {
    const int nb = cur ^ 1, kn = kt + 64;
    if (kn < SLEN) {
      if (tid < 64) Mb[nb * 64 + tid] = mg[kn + tid] ? 0.f : -1e30f;
      gload_lds16(Kg + (size_t)(kv0 + kn + rs) * HD + gs * 8, Ktile + nb * 4096 + tid * 8);
      gload_lds16(Vg + (size_t)rs * S + kv0 + kn + gs * 8, Vtile + nb * 4096 + tid * 8);
    }

    const u16* Kc = Ktile + cur * 4096;
    const u16* Vc = Vtile + cur * 4096;

    float sv[4][4];
    __builtin_amdgcn_s_setprio(1);
#pragma unroll
    for (int nt = 0; nt < 4; ++nt) {
      const u16* kb2 = Kc + (nt * 16 + fr) * 64;
      bf16x8 k0v = *(const bf16x8*)(kb2 + ((fq) ^ fr7) * 8);
      bf16x8 k1v = *(const bf16x8*)(kb2 + ((4 + fq) ^ fr7) * 8);
      f32x4 t = {};
      t = __builtin_amdgcn_mfma_f32_16x16x32_bf16(k0v, qf0, t, 0, 0, 0);
      t = __builtin_amdgcn_mfma_f32_16x16x32_bf16(k1v, qf1, t, 0, 0, 0);
      float4 mb = *(const float4*)&Mb[cur * 64 + nt * 16 + fq * 4];
      sv[nt][0] = t[0] + mb.x;
      sv[nt][1] = t[1] + mb.y;
      sv[nt][2] = t[2] + mb.z;
      sv[nt][3] = t[3] + mb.w;
    }
    __builtin_amdgcn_s_setprio(0);

    float pmax;
    {
      float m0 = fmaxf(fmaxf(sv[0][0], sv[0][1]), fmaxf(sv[0][2], sv[0][3]));
      float m1 = fmaxf(fmaxf(sv[1][0], sv[1][1]), fmaxf(sv[1][2], sv[1][3]));
      float m2 = fmaxf(fmaxf(sv[2][0], sv[2][1]), fmaxf(sv[2][2], sv[2][3]));
      float m3 = fmaxf(fmaxf(sv[3][0], sv[3][1]), fmaxf(sv[3][2], sv[3][3]));
      pmax = fmaxf(fmaxf(m0, m1), fmaxf(m2, m3));
    }
    if (__any(pmax > mrow + 12.f)) {
      pmax = fmaxf(pmax, __shfl_xor(pmax, 16));
      pmax = fmaxf(pmax, __shfl_xor(pmax, 32));
      float nm = fmaxf(mrow, pmax);
      float al = fexp2(mrow - nm);
      mrow = nm;
      lrow *= al;
#pragma unroll
      for (int nt = 0; nt < 4; ++nt)
#pragma unroll
        for (int i = 0; i < 4; ++i) oacc[nt][i] *= al;
    }

    float p[4][4];
#pragma unroll
    for (int nt = 0; nt < 4; ++nt)
#pragma unroll
      for (int i = 0; i < 4; ++i) p[nt][i] = fexp2(sv[nt][i] - mrow);
    {
      float s0 = (p[0][0] + p[0][1]) + (p[0][2] + p[0][3]);
      float s1 = (p[1][0] + p[1][1]) + (p[1][2] + p[1][3]);
      float s2 = (p[2][0] + p[2][1]) + (p[2][2] + p[2][3]);
      float s3 = (p[3][0] + p[3][1]) + (p[3][2] + p[3][3]);
      lrow += (s0 + s1) + (s2 + s3);
    }

    int pk[4][2];
#pragma unroll
    for (int nt = 0; nt < 4; ++nt) {
      asm("v_cvt_pk_bf16_f32 %0, %1, %2" : "=v"(pk[nt][0]) : "v"(p[nt][0]), "v"(p[nt][1]));
      asm("v_cvt_pk_bf16_f32 %0, %1, %2" : "=v"(pk[nt][1]) : "v"(p[nt][2]), "v"(p[nt][3]));
    }

#pragma unroll
    for (int b2 = 0; b2 < 2; ++b2) {
      int w0a = __builtin_amdgcn_ds_bpermute(A0, pk[2 * b2][0]);
      int w0b = __builtin_amdgcn_ds_bpermute(A0, pk[2 * b2 + 1][0]);
      int w1a = __builtin_amdgcn_ds_bpermute(A0, pk[2 * b2][1]);
      int w1b = __builtin_amdgcn_ds_bpermute(A0, pk[2 * b2 + 1][1]);
      int w2a = __builtin_amdgcn_ds_bpermute(A1, pk[2 * b2][0]);
      int w2b = __builtin_amdgcn_ds_bpermute(A1, pk[2 * b2 + 1][0]);
      int w3a = __builtin_amdgcn_ds_bpermute(A1, pk[2 * b2][1]);
      int w3b = __builtin_amdgcn_ds_bpermute(A1, pk[2 * b2 + 1][1]);
      i32x4 wv;
      wv[0] = lofq ? w0a : w0b;
      wv[1] = lofq ? w1a : w1b;
      wv[2] = lofq ? w2a : w2b;
      wv[3] = lofq ? w3a : w3b;
      bf16x8 pfrag = __builtin_bit_cast(bf16x8, wv);
      __builtin_amdgcn_s_setprio(1);
#pragma unroll
      for (int nt = 0; nt < 4; ++nt) {
        const u16* vb2 = Vc + (nt * 16 + fr) * 64;
        bf16x8 vf = *(const bf16x8*)(vb2 + ((b2 * 4 + fq) ^ fr7) * 8);
        oacc[nt] = __builtin_amdgcn_mfma_f32_16x16x32_bf16(vf, pfrag, oacc[nt], 0, 0, 0);
      }
      __builtin_amdgcn_s_setprio(0);
    }

    asm volatile("s_waitcnt vmcnt(0)" ::: "memory");
    __syncthreads();
    cur = nb;
  }

  lrow += __shfl_xor(lrow, 16);
  lrow += __shfl_xor(lrow, 32);
  if (fq == 0)
    ml[((size_t)z * 32 + bh) * NQ + q0 + w * 16 + fr] = float2{mrow, lrow};

  float* tb = (float*)smem + w * 1088;
#pragma unroll
  for (int nt = 0; nt < 4; ++nt)
#pragma unroll
    for (int i = 0; i < 4; ++i)
      tb[fr * 68 + nt * 16 + fq * 4 + i] = oacc[nt][i];

  const int qloc = lane >> 2, dl = lane & 3;
  const float* trow = tb + qloc * 68 + dl * 16;
  u16* gdst = Opart + (((size_t)z * 32 + bh) * NQ + q0 + w * 16 + qloc) * 64 + dl * 16;
  u16x8 o0, o1;
#pragma unroll
  for (int j = 0; j < 8; ++j) {
    o0[j] = f2bf(trow[j]);
    o1[j] = f2bf(trow[8 + j]);
  }
  *(u16x8*)gdst = o0;
  *(u16x8*)(gdst + 8) = o1;
}

// ---------------- combine split partials -> bf16 Aout ----------------------
__global__ __launch_bounds__(256) void combine_kernel(
    const u16* __restrict__ Opart, const float2* __restrict__ ml,
    u16* __restrict__ out) {
  const int bh = blockIdx.y, b = bh >> 4, h = bh & 15;
  const int q = blockIdx.x * 64 + (threadIdx.x >> 2);
  const int dl = threadIdx.x & 3;
  float2 mm[NSPLIT];
  float M = -1e30f;
#pragma unroll
  for (int zz = 0; zz < NSPLIT; ++zz) {
    mm[zz] = ml[((size_t)zz * 32 + bh) * NQ + q];
    M = fmaxf(M, mm[zz].x);
  }
  float wz[NSPLIT], lsum = 0.f;
#pragma unroll
  for (int zz = 0; zz < NSPLIT; ++zz) {
    wz[zz] = fexp2(mm[zz].x - M);
    lsum += mm[zz].y * wz[zz];
  }
  const float inv = 1.f / lsum;
  float acc[16] = {};
#pragma unroll
  for (int zz = 0; zz < NSPLIT; ++zz) {
    const u16* op = Opart + (((size_t)zz * 32 + bh) * NQ + q) * 64 + dl * 16;
    u16x8 a0 = *(const u16x8*)op;
    u16x8 a1 = *(const u16x8*)(op + 8);
    float wi = wz[zz] * inv;
#pragma unroll
    for (int j = 0; j < 8; ++j) {
      acc[j] += wi * bf2f(a0[j]);
      acc[8 + j] += wi * bf2f(a1[j]);
    }
  }
  u16* orow = out + ((size_t)b * NQ + q) * H + h * HD + dl * 16;
  u16x8 o0, o1;
#pragma unroll
  for (int j = 0; j < 8; ++j) {
    o0[j] = f2bf(acc[j]);
    o1[j] = f2bf(acc[8 + j]);
  }
  *(u16x8*)orow = o0;
  *(u16x8*)(orow + 8) = o1;
}

// ---------------------------------------------------------------------------
extern "C" void kernel_launch(void* const* d_in, const int* in_sizes, int n_in,
                              void* d_out, int out_size, void* d_ws, size_t ws_size,
                              hipStream_t stream) {
  const float* queries = (const float*)d_in[0];
  const float* keys_values = (const float*)d_in[1];
  const void* amask = d_in[2];
  const float* W_qkv = (const float*)d_in[3];
  const float* b_qkv = (const float*)d_in[4];
  const float* W_out = (const float*)d_in[5];
  const float* b_out = (const float*)d_in[6];
  const float* gamma = (const float*)d_in[7];
  const float* beta = (const float*)d_in[8];

  char* ws = (char*)d_ws;
  unsigned char* maskN = (unsigned char*)ws;                 // 8 KB
  u16* Xq = (u16*)(ws + 8192);                               // [2048][1024]
  u16* Xkv = Xq + (size_t)Bb * NQ * H;                       // [8192][1024]
  u16* Wtq = Xkv + (size_t)Bb * S * H;                       // [3072][1024]
  u16* Wto = Wtq + (size_t)3 * H * H;                        // [1024][1024]
  u16* Qbuf = Wto + (size_t)H * H;                           // [B][NH][NQ][HD]
  u16* Kbuf = Qbuf + (size_t)Bb * NQ * H;                    // [B][NH][S][HD]; V^T follows
  u16* Aout = Kbuf + (size_t)2 * Bb * S * H;                 // [2048][1024]
  // attn partials OVERLAY dead Xq/Xkv region (rewritten by prep each call
  // before GEMMs read them; Opart/ml written after GEMMs consume Xq/Xkv).
  u16* Opart = (u16*)(ws + 8192);                            // 16 MB bf16
  float2* ml = (float2*)((char*)Opart + (size_t)NSPLIT * 32 * NQ * 64 * 2);  // 1 MB

  hipLaunchKernelGGL(prep_kernel, dim3(6657), dim3(256), 0, stream,
                     (const unsigned char*)amask, maskN, queries, keys_values,
                     gamma, beta, Xq, Xkv, W_qkv, W_out, Wtq, Wto);
  hipLaunchKernelGGL(gemm_q_kernel, dim3(8, 16), dim3(256), 0, stream,
                     Xq, Wtq, b_qkv, Qbuf);
  hipLaunchKernelGGL(gemm_kv_kernel, dim3(256), dim3(512), 0, stream,
                     Xkv, Wtq + (size_t)H * H, b_qkv + H, Kbuf);
  hipLaunchKernelGGL(attn_kernel, dim3(NQ / 128 * Bb * NH * NSPLIT), dim3(512), 0, stream,
                     Qbuf, Kbuf, Kbuf + (size_t)Bb * S * H, maskN, Opart, ml);
  hipLaunchKernelGGL(combine_kernel, dim3(NQ / 64, Bb * NH), dim3(256), 0, stream,
                     Opart, ml, Aout);
  hipLaunchKernelGGL(gemm_out_kernel, dim3(H / 128, Bb * NQ / 128), dim3(256), 0, stream,
                     Aout, Wto, b_out, (float*)d_out);
}

// Round 9
// 172.989 us; speedup vs baseline: 1.8102x; 1.0402x over previous
//
#include <hip/hip_runtime.h>
#include <stdint.h>

#define DEVI __device__ __forceinline__

constexpr int Bb = 2, NQ = 1024, S = 4096, H = 1024, NH = 16, HD = 64;
constexpr int NSPLIT = 4, SLEN = S / NSPLIT;

typedef __bf16 bf16x8 __attribute__((ext_vector_type(8)));
typedef float f32x4 __attribute__((ext_vector_type(4)));
typedef int i32x4 __attribute__((ext_vector_type(4)));
typedef unsigned short u16;
typedef u16 u16x8 __attribute__((ext_vector_type(8)));

DEVI u16 f2bf(float f) {
  union { float f; unsigned u; } v; v.f = f;
  unsigned r = (v.u + 0x7fffu + ((v.u >> 16) & 1u)) >> 16;
  return (u16)r;
}

DEVI float bf2f(u16 x) {
  union { unsigned u; float f; } v; v.u = ((unsigned)x) << 16;
  return v.f;
}

DEVI float fexp2(float x) {
#if __has_builtin(__builtin_amdgcn_exp2f)
  return __builtin_amdgcn_exp2f(x);
#else
  return exp2f(x);
#endif
}

DEVI void gload_lds16(const void* g, void* lds) {
  __builtin_amdgcn_global_load_lds(
      (const __attribute__((address_space(1))) void*)(uintptr_t)g,
      (__attribute__((address_space(3))) void*)(uint32_t)(uintptr_t)lds,
      16, 0, 0);
}

// ---------------- fused prep: mask-norm | LN(q) | LN(kv) | W transposes ----
DEVI void ln_body(const float* __restrict__ x, const float* __restrict__ gamma,
                  const float* __restrict__ beta, u16* __restrict__ out, int row) {
  int lane = threadIdx.x & 63;
  const float4* xr = (const float4*)(x + (size_t)row * H);
  float4 v[4];
  float s = 0.f, s2 = 0.f;
#pragma unroll
  for (int i = 0; i < 4; ++i) {
    v[i] = xr[lane + i * 64];
    s += v[i].x + v[i].y + v[i].z + v[i].w;
    s2 += v[i].x * v[i].x + v[i].y * v[i].y + v[i].z * v[i].z + v[i].w * v[i].w;
  }
#pragma unroll
  for (int d = 1; d < 64; d <<= 1) { s += __shfl_xor(s, d); s2 += __shfl_xor(s2, d); }
  float mu = s * (1.f / H);
  float rstd = rsqrtf(s2 * (1.f / H) - mu * mu + 1e-6f);
  u16* orow = out + (size_t)row * H;
  const float4* g4 = (const float4*)gamma;
  const float4* b4 = (const float4*)beta;
#pragma unroll
  for (int i = 0; i < 4; ++i) {
    float4 g = g4[lane + i * 64], bb = b4[lane + i * 64];
    ushort4 o;
    o.x = f2bf((v[i].x - mu) * rstd * g.x + bb.x);
    o.y = f2bf((v[i].y - mu) * rstd * g.y + bb.y);
    o.z = f2bf((v[i].z - mu) * rstd * g.z + bb.z);
    o.w = f2bf((v[i].w - mu) * rstd * g.w + bb.w);
    *(ushort4*)(orow + (size_t)(lane + i * 64) * 4) = o;
  }
}

__global__ __launch_bounds__(256) void prep_kernel(
    const unsigned char* __restrict__ mraw, unsigned char* __restrict__ maskN,
    const float* __restrict__ queries, const float* __restrict__ keys_values,
    const float* __restrict__ gamma, const float* __restrict__ beta,
    u16* __restrict__ Xq, u16* __restrict__ Xkv,
    const float* __restrict__ W_qkv, const float* __restrict__ W_out,
    u16* __restrict__ Wtq, u16* __restrict__ Wto) {
  __shared__ int isByte;
  __shared__ float tile[32][33];
  const int b = blockIdx.x;
  if (b == 0) {
    if (threadIdx.x == 0) isByte = 0;
    __syncthreads();
    int any = 0;
    for (int p = threadIdx.x; p < Bb * S; p += 256)
      if ((p & 3) && mraw[p]) any = 1;
    if (any) atomicOr(&isByte, 1);
    __syncthreads();
    const int bytemode = isByte;
    for (int i = threadIdx.x; i < Bb * S; i += 256) {
      unsigned char v = bytemode ? (unsigned char)(mraw[i] != 0)
                                 : (unsigned char)(((const int*)mraw)[i] != 0);
      maskN[i] = v;
    }
  } else if (b < 513) {
    ln_body(queries, gamma, beta, Xq, (b - 1) * 4 + (threadIdx.x >> 6));
  } else if (b < 2561) {
    ln_body(keys_values, gamma, beta, Xkv, (b - 513) * 4 + (threadIdx.x >> 6));
  } else {
    const float* in; u16* out; int C, t;
    if (b < 5633) { t = b - 2561; in = W_qkv; out = Wtq; C = 3 * H; }
    else          { t = b - 5633; in = W_out; out = Wto; C = H; }
    const int nbx = C / 32;
    int c0 = (t % nbx) * 32, r0 = (t / nbx) * 32;
    int tx = threadIdx.x & 31, ty = threadIdx.x >> 5;
#pragma unroll
    for (int i = 0; i < 32; i += 8)
      tile[ty + i][tx] = in[(size_t)(r0 + ty + i) * C + c0 + tx];
    __syncthreads();
#pragma unroll
    for (int i = 0; i < 32; i += 8)
      out[(size_t)(c0 + ty + i) * H + r0 + tx] = f2bf(tile[tx][ty + i]);
  }
}

// ---------------- GEMM core (128x128 tile, BK=32, single-buffered) ---------
#define GEMM_CORE(Ag, Bg)                                                        \
  f32x4 acc[4][4] = {};                                                          \
  {                                                                              \
    for (int k0 = 0; k0 < 1024; k0 += 32) {                                      \
      gload_lds16(Ag + (size_t)(c0 >> 2) * 1024 + k0 + (c0 & 3) * 8, Ash + c0 * 8); \
      gload_lds16(Ag + (size_t)(c1 >> 2) * 1024 + k0 + (c1 & 3) * 8, Ash + c1 * 8); \
      gload_lds16(Bg + (size_t)(c0 >> 2) * 1024 + k0 + (c0 & 3) * 8, Bsh + c0 * 8); \
      gload_lds16(Bg + (size_t)(c1 >> 2) * 1024 + k0 + (c1 & 3) * 8, Bsh + c1 * 8); \
      asm volatile("s_waitcnt vmcnt(0)" ::: "memory");                           \
      __syncthreads();                                                           \
      bf16x8 af[4], bfr[4];                                                      \
      _Pragma("unroll") for (int m = 0; m < 4; ++m)                              \
          af[m] = *(const bf16x8*)(Ash + (wr + m * 16 + fr) * 32 + fq * 8);      \
      _Pragma("unroll") for (int n = 0; n < 4; ++n)                              \
          bfr[n] = *(const bf16x8*)(Bsh + (wc + n * 16 + fr) * 32 + fq * 8);     \
      _Pragma("unroll") for (int m = 0; m < 4; ++m)                              \
          _Pragma("unroll") for (int n = 0; n < 4; ++n)                          \
              acc[m][n] = __builtin_amdgcn_mfma_f32_16x16x32_bf16(af[m], bfr[n], acc[m][n], 0, 0, 0); \
      __syncthreads();                                                           \
    }                                                                            \
  }

// ---------------- Q projection GEMM (128^2) -> Qbuf bf16, pre-scaled -------
__global__ __launch_bounds__(256) void gemm_q_kernel(
    const u16* __restrict__ Xq, const u16* __restrict__ Wtq,
    const float* __restrict__ bias, u16* __restrict__ Qbuf) {
  __shared__ __align__(16) u16 Ash[128 * 32];
  __shared__ __align__(16) u16 Bsh[128 * 32];
  const int tid = threadIdx.x, w = tid >> 6, lane = tid & 63;
  const int c0 = tid, c1 = tid + 256;
  const int wr = (w >> 1) * 64, wc = (w & 1) * 64;
  const int fr = lane & 15, fq = lane >> 4;
  const int brow = blockIdx.y * 128, bcol = blockIdx.x * 128;
  const u16* Ag = Xq + (size_t)brow * 1024;
  const u16* Bg = Wtq + (size_t)bcol * 1024;
  GEMM_CORE(Ag, Bg)
  constexpr float QSCALE = 0.125f * 1.4426950408889634f;
#pragma unroll
  for (int m = 0; m < 4; ++m)
#pragma unroll
    for (int n = 0; n < 4; ++n) {
      const int c = bcol + wc + n * 16 + fr;
      const int r0 = brow + wr + m * 16 + fq * 4;
#pragma unroll
      for (int i = 0; i < 4; ++i) {
        int r = r0 + i;
        Qbuf[((((size_t)(r >> 10)) * NH + (c >> 6)) * NQ + (r & (NQ - 1))) * HD + (c & 63)] =
            f2bf((acc[m][n][i] + bias[c]) * QSCALE);
      }
    }
}

// ---------------- KV projection GEMM: 256^2, BK=32, 4-buffer counted-vmcnt -
__global__ __launch_bounds__(512, 2) void gemm_kv_kernel(
    const u16* __restrict__ Xkv, const u16* __restrict__ WtqKV,
    const float* __restrict__ bias, u16* __restrict__ KVbuf) {
  __shared__ __align__(16) u16 Abuf[4][256 * 32];
  __shared__ __align__(16) u16 Bbuf[4][256 * 32];
  const int tid = threadIdx.x, wid = tid >> 6, lane = tid & 63;
  const int fr = lane & 15, fq = lane >> 4;
  const int wr = (wid >> 2) * 128, wc = (wid & 3) * 64;
  const int bid = blockIdx.x;
  const int xcd = bid & 7, loc = bid >> 3;
  const int by = xcd * 4 + (loc & 3), bx = loc >> 2;  // by:0..31, bx:0..7
  const u16* Ag = Xkv + (size_t)(by * 256) * 1024;
  const u16* Bg = WtqKV + (size_t)(bx * 256) * 1024;

  f32x4 acc[8][4] = {};

  auto stage = [&](int tt) {
    const int k0 = tt * 32;
    u16* Ad = &Abuf[tt & 3][0];
    u16* Bd = &Bbuf[tt & 3][0];
#pragma unroll
    for (int l = 0; l < 2; ++l) {
      int ci = tid + l * 512;
      int row = ci >> 2, ch = ci & 3;
      int chs = ch ^ ((row >> 1) & 3);
      gload_lds16(Ag + (size_t)row * 1024 + k0 + chs * 8, Ad + ci * 8);
      gload_lds16(Bg + (size_t)row * 1024 + k0 + chs * 8, Bd + ci * 8);
    }
  };

#define KV_ITER(T, VM)                                                          \
  {                                                                             \
    asm volatile("s_waitcnt vmcnt(" #VM ")" ::: "memory");                      \
    __syncthreads();                                                            \
    const u16* Ac = &Abuf[(T) & 3][0];                                          \
    const u16* Bc = &Bbuf[(T) & 3][0];                                          \
    bf16x8 af[8], bfv[4];                                                       \
    _Pragma("unroll") for (int m = 0; m < 8; ++m) {                             \
      int row = wr + m * 16 + fr;                                               \
      af[m] = *(const bf16x8*)(Ac + row * 32 + (fq ^ ((row >> 1) & 3)) * 8);    \
    }                                                                           \
    _Pragma("unroll") for (int n = 0; n < 4; ++n) {                             \
      int row = wc + n * 16 + fr;                                               \
      bfv[n] = *(const bf16x8*)(Bc + row * 32 + (fq ^ ((row >> 1) & 3)) * 8);   \
    }                                                                           \
    if ((T) + 3 < 32) stage((T) + 3);                                           \
    __builtin_amdgcn_s_setprio(1);                                              \
    _Pragma("unroll") for (int m = 0; m < 8; ++m)                               \
      _Pragma("unroll") for (int n = 0; n < 4; ++n)                             \
        acc[m][n] = __builtin_amdgcn_mfma_f32_16x16x32_bf16(af[m], bfv[n], acc[m][n], 0, 0, 0); \
    __builtin_amdgcn_s_setprio(0);                                              \
  }

  stage(0);
  stage(1);
  stage(2);
  for (int t = 0; t < 29; ++t) KV_ITER(t, 8)
  KV_ITER(29, 8)
  KV_ITER(30, 4)
  KV_ITER(31, 0)
#undef KV_ITER

#pragma unroll
  for (int m = 0; m < 8; ++m)
#pragma unroll
    for (int n = 0; n < 4; ++n) {
      const int c = bx * 256 + wc + n * 16 + fr;
      const int r0 = by * 256 + wr + m * 16 + fq * 4;
      const float bv = bias[c];
      if (c >= 1024) {
        int bb = r0 >> 12, kv = r0 & (S - 1);
        int cc = c - 1024, head = cc >> 6, d = cc & 63;
        ushort4 o;
        o.x = f2bf(acc[m][n][0] + bv);
        o.y = f2bf(acc[m][n][1] + bv);
        o.z = f2bf(acc[m][n][2] + bv);
        o.w = f2bf(acc[m][n][3] + bv);
        u16* vb = KVbuf + (size_t)Bb * NH * S * HD;
        *(ushort4*)(vb + (((size_t)(bb * NH + head)) * HD + d) * S + kv) = o;
      } else {
#pragma unroll
        for (int i = 0; i < 4; ++i) {
          int r = r0 + i;
          KVbuf[((((size_t)(r >> 12)) * NH + (c >> 6)) * S + (r & (S - 1))) * HD + (c & 63)] =
              f2bf(acc[m][n][i] + bv);
        }
      }
    }
}

// ---------------- output projection GEMM -> f32 d_out ----------------------
__global__ __launch_bounds__(256) void gemm_out_kernel(
    const u16* __restrict__ A, const u16* __restrict__ Bt,
    const float* __restrict__ bias, float* __restrict__ outp) {
  __shared__ __align__(16) u16 Ash[128 * 32];
  __shared__ __align__(16) u16 Bsh[128 * 32];
  const int tid = threadIdx.x, w = tid >> 6, lane = tid & 63;
  const int c0 = tid, c1 = tid + 256;
  const int wr = (w >> 1) * 64, wc = (w & 1) * 64;
  const int fr = lane & 15, fq = lane >> 4;
  const int brow = blockIdx.y * 128, bcol = blockIdx.x * 128;
  const u16* Ag = A + (size_t)brow * 1024;
  const u16* Bg = Bt + (size_t)bcol * 1024;
  GEMM_CORE(Ag, Bg)
#pragma unroll
  for (int m = 0; m < 4; ++m)
#pragma unroll
    for (int n = 0; n < 4; ++n) {
      const int c = bcol + wc + n * 16 + fr;
      const int r0 = brow + wr + m * 16 + fq * 4;
#pragma unroll
      for (int i = 0; i < 4; ++i)
        outp[(size_t)(r0 + i) * H + c] = acc[m][n][i] + bias[c];
    }
}

// ---------------- flash attention: 8 waves, QBLK=256, 2 q-groups/wave ------
// Wave w owns q rows [q0+w*32, q0+w*32+32) as two 16-row fragment groups A/B
// sharing one set of K/V fragment loads (halves LDS reads per q, 2 indep
// dependency chains). Swapped QK^T in-register softmax; split-S=4.
__global__ __launch_bounds__(512, 4) void attn_kernel(
    const u16* __restrict__ Qb, const u16* __restrict__ Kb,
    const u16* __restrict__ Vt, const unsigned char* __restrict__ mask,
    u16* __restrict__ Opart, float2* __restrict__ ml) {
  __shared__ __align__(16) char smem[34816];
  u16* Ktile = (u16*)smem;
  u16* Vtile = Ktile + 8192;
  float* Mb = (float*)(Vtile + 8192);
  // decode: xcd = bflat&7; idx = bflat>>3; qb = idx&3; g = (idx>>2)*8 + xcd
  const int bflat = blockIdx.x;
  const int r = bflat & 7, idx = bflat >> 3;
  const int q0 = (idx & 3) * 256;
  const int g = (idx >> 2) * 8 + r;
  const int bh = g & 31, z = g >> 5;
  const int b = bh >> 4, kv0 = z * SLEN;
  const int tid = threadIdx.x, w = tid >> 6, lane = tid & 63;
  const int fr = lane & 15, fq = lane >> 4, fr7 = fr & 7;
  const u16* QgA = Qb + ((size_t)bh * NQ + q0 + w * 32) * HD;
  const u16* QgB = QgA + 16 * HD;
  const u16* Kg = Kb + (size_t)bh * S * HD;
  const u16* Vg = Vt + (size_t)bh * HD * S;
  const unsigned char* mg = mask + (size_t)b * S + kv0;

  const int rs = tid >> 3, gs = (tid & 7) ^ (rs & 7);

  bf16x8 qfA0 = *(const bf16x8*)(QgA + fr * HD + fq * 8);
  bf16x8 qfA1 = *(const bf16x8*)(QgA + fr * HD + 32 + fq * 8);
  bf16x8 qfB0 = *(const bf16x8*)(QgB + fr * HD + fq * 8);
  bf16x8 qfB1 = *(const bf16x8*)(QgB + fr * HD + 32 + fq * 8);

  const int A0 = ((((fq << 1)) & 3) * 16 + fr) << 2;
  const int A1 = ((((fq << 1) + 1) & 3) * 16 + fr) << 2;
  const bool lofq = (fq < 2);

  f32x4 oaccA[4] = {}, oaccB[4] = {};
  float mrowA = -1e30f, lrowA = 0.f, mrowB = -1e30f, lrowB = 0.f;

  if (tid < 64) Mb[tid] = mg[tid] ? 0.f : -1e30f;
  gload_lds16(Kg + (size_t)(kv0 + rs) * HD + gs * 8, Ktile + tid * 8);
  gload_lds16(Vg + (size_t)rs * S + kv0 + gs * 8, Vtile + tid * 8);
  asm volatile("s_waitcnt vmcnt(0)" ::: "memory");
  __syncthreads();

  int cur = 0;
  for (int kt = 0; kt < SLEN; kt += 64) {
    const int nb = cur ^ 1, kn = kt + 64;
    if (kn < SLEN) {
      if (tid < 64) Mb[nb * 64 + tid] = mg[kn + tid] ? 0.f : -1e30f;
      gload_lds16(Kg + (size_t)(kv0 + kn + rs) * HD + gs * 8, Ktile + nb * 4096 + tid * 8);
      gload_lds16(Vg + (size_t)rs * S + kv0 + kn + gs * 8, Vtile + nb * 4096 + tid * 8);
    }

    const u16* Kc = Ktile + cur * 4096;
    const u16* Vc = Vtile + cur * 4096;

    float svA[4][4], svB[4][4];
    __builtin_amdgcn_s_setprio(1);
#pragma unroll
    for (int nt = 0; nt < 4; ++nt) {
      const u16* kb2 = Kc + (nt * 16 + fr) * 64;
      bf16x8 k0v = *(const bf16x8*)(kb2 + ((fq) ^ fr7) * 8);
      bf16x8 k1v = *(const bf16x8*)(kb2 + ((4 + fq) ^ fr7) * 8);
      f32x4 tA = {}, tB = {};
      tA = __builtin_amdgcn_mfma_f32_16x16x32_bf16(k0v, qfA0, tA, 0, 0, 0);
      tA = __builtin_amdgcn_mfma_f32_16x16x32_bf16(k1v, qfA1, tA, 0, 0, 0);
      tB = __builtin_amdgcn_mfma_f32_16x16x32_bf16(k0v, qfB0, tB, 0, 0, 0);
      tB = __builtin_amdgcn_mfma_f32_16x16x32_bf16(k1v, qfB1, tB, 0, 0, 0);
      float4 mb = *(const float4*)&Mb[cur * 64 + nt * 16 + fq * 4];
      svA[nt][0] = tA[0] + mb.x; svA[nt][1] = tA[1] + mb.y;
      svA[nt][2] = tA[2] + mb.z; svA[nt][3] = tA[3] + mb.w;
      svB[nt][0] = tB[0] + mb.x; svB[nt][1] = tB[1] + mb.y;
      svB[nt][2] = tB[2] + mb.z; svB[nt][3] = tB[3] + mb.w;
    }
    __builtin_amdgcn_s_setprio(0);

    float pmaxA, pmaxB;
    {
      float a0 = fmaxf(fmaxf(svA[0][0], svA[0][1]), fmaxf(svA[0][2], svA[0][3]));
      float a1 = fmaxf(fmaxf(svA[1][0], svA[1][1]), fmaxf(svA[1][2], svA[1][3]));
      float a2 = fmaxf(fmaxf(svA[2][0], svA[2][1]), fmaxf(svA[2][2], svA[2][3]));
      float a3 = fmaxf(fmaxf(svA[3][0], svA[3][1]), fmaxf(svA[3][2], svA[3][3]));
      pmaxA = fmaxf(fmaxf(a0, a1), fmaxf(a2, a3));
      float b0 = fmaxf(fmaxf(svB[0][0], svB[0][1]), fmaxf(svB[0][2], svB[0][3]));
      float b1 = fmaxf(fmaxf(svB[1][0], svB[1][1]), fmaxf(svB[1][2], svB[1][3]));
      float b2 = fmaxf(fmaxf(svB[2][0], svB[2][1]), fmaxf(svB[2][2], svB[2][3]));
      float b3 = fmaxf(fmaxf(svB[3][0], svB[3][1]), fmaxf(svB[3][2], svB[3][3]));
      pmaxB = fmaxf(fmaxf(b0, b1), fmaxf(b2, b3));
    }
    if (__any(pmaxA > mrowA + 12.f)) {
      pmaxA = fmaxf(pmaxA, __shfl_xor(pmaxA, 16));
      pmaxA = fmaxf(pmaxA, __shfl_xor(pmaxA, 32));
      float nm = fmaxf(mrowA, pmaxA);
      float al = fexp2(mrowA - nm);
      mrowA = nm; lrowA *= al;
#pragma unroll
      for (int nt = 0; nt < 4; ++nt)
#pragma unroll
        for (int i = 0; i < 4; ++i) oaccA[nt][i] *= al;
    }
    if (__any(pmaxB > mrowB + 12.f)) {
      pmaxB = fmaxf(pmaxB, __shfl_xor(pmaxB, 16));
      pmaxB = fmaxf(pmaxB, __shfl_xor(pmaxB, 32));
      float nm = fmaxf(mrowB, pmaxB);
      float al = fexp2(mrowB - nm);
      mrowB = nm; lrowB *= al;
#pragma unroll
      for (int nt = 0; nt < 4; ++nt)
#pragma unroll
        for (int i = 0; i < 4; ++i) oaccB[nt][i] *= al;
    }

    float pA[4][4], pB[4][4];
#pragma unroll
    for (int nt = 0; nt < 4; ++nt)
#pragma unroll
      for (int i = 0; i < 4; ++i) {
        pA[nt][i] = fexp2(svA[nt][i] - mrowA);
        pB[nt][i] = fexp2(svB[nt][i] - mrowB);
      }
    {
      float s0 = (pA[0][0] + pA[0][1]) + (pA[0][2] + pA[0][3]);
      float s1 = (pA[1][0] + pA[1][1]) + (pA[1][2] + pA[1][3]);
      float s2 = (pA[2][0] + pA[2][1]) + (pA[2][2] + pA[2][3]);
      float s3 = (pA[3][0] + pA[3][1]) + (pA[3][2] + pA[3][3]);
      lrowA += (s0 + s1) + (s2 + s3);
      float t0 = (pB[0][0] + pB[0][1]) + (pB[0][2] + pB[0][3]);
      float t1 = (pB[1][0] + pB[1][1]) + (pB[1][2] + pB[1][3]);
      float t2 = (pB[2][0] + pB[2][1]) + (pB[2][2] + pB[2][3]);
      float t3 = (pB[3][0] + pB[3][1]) + (pB[3][2] + pB[3][3]);
      lrowB += (t0 + t1) + (t2 + t3);
    }

    int pkA[4][2], pkB[4][2];
#pragma unroll
    for (int nt = 0; nt < 4; ++nt) {
      asm("v_cvt_pk_bf16_f32 %0, %1, %2" : "=v"(pkA[nt][0]) : "v"(pA[nt][0]), "v"(pA[nt][1]));
      asm("v_cvt_pk_bf16_f32 %0, %1, %2" : "=v"(pkA[nt][1]) : "v"(pA[nt][2]), "v"(pA[nt][3]));
      asm("v_cvt_pk_bf16_f32 %0, %1, %2" : "=v"(pkB[nt][0]) : "v"(pB[nt][0]), "v"(pB[nt][1]));
      asm("v_cvt_pk_bf16_f32 %0, %1, %2" : "=v"(pkB[nt][1]) : "v"(pB[nt][2]), "v"(pB[nt][3]));
    }

#pragma unroll
    for (int b2 = 0; b2 < 2; ++b2) {
      i32x4 wvA, wvB;
      {
        int w0a = __builtin_amdgcn_ds_bpermute(A0, pkA[2 * b2][0]);
        int w0b = __builtin_amdgcn_ds_bpermute(A0, pkA[2 * b2 + 1][0]);
        int w1a = __builtin_amdgcn_ds_bpermute(A0, pkA[2 * b2][1]);
        int w1b = __builtin_amdgcn_ds_bpermute(A0, pkA[2 * b2 + 1][1]);
        int w2a = __builtin_amdgcn_ds_bpermute(A1, pkA[2 * b2][0]);
        int w2b = __builtin_amdgcn_ds_bpermute(A1, pkA[2 * b2 + 1][0]);
        int w3a = __builtin_amdgcn_ds_bpermute(A1, pkA[2 * b2][1]);
        int w3b = __builtin_amdgcn_ds_bpermute(A1, pkA[2 * b2 + 1][1]);
        wvA[0] = lofq ? w0a : w0b;
        wvA[1] = lofq ? w1a : w1b;
        wvA[2] = lofq ? w2a : w2b;
        wvA[3] = lofq ? w3a : w3b;
      }
      {
        int w0a = __builtin_amdgcn_ds_bpermute(A0, pkB[2 * b2][0]);
        int w0b = __builtin_amdgcn_ds_bpermute(A0, pkB[2 * b2 + 1][0]);
        int w1a = __builtin_amdgcn_ds_bpermute(A0, pkB[2 * b2][1]);
        int w1b = __builtin_amdgcn_ds_bpermute(A0, pkB[2 * b2 + 1][1]);
        int w2a = __builtin_amdgcn_ds_bpermute(A1, pkB[2 * b2][0]);
        int w2b = __builtin_amdgcn_ds_bpermute(A1, pkB[2 * b2 + 1][0]);
        int w3a = __builtin_amdgcn_ds_bpermute(A1, pkB[2 * b2][1]);
        int w3b = __builtin_amdgcn_ds_bpermute(A1, pkB[2 * b2 + 1][1]);
        wvB[0] = lofq ? w0a : w0b;
        wvB[1] = lofq ? w1a : w1b;
        wvB[2] = lofq ? w2a : w2b;
        wvB[3] = lofq ? w3a : w3b;
      }
      bf16x8 pfragA = __builtin_bit_cast(bf16x8, wvA);
      bf16x8 pfragB = __builtin_bit_cast(bf16x8, wvB);
      __builtin_amdgcn_s_setprio(1);
#pragma unroll
      for (int nt = 0; nt < 4; ++nt) {
        const u16* vb2 = Vc + (nt * 16 + fr) * 64;
        bf16x8 vf = *(const bf16x8*)(vb2 + ((b2 * 4 + fq) ^ fr7) * 8);
        oaccA[nt] = __builtin_amdgcn_mfma_f32_16x16x32_bf16(vf, pfragA, oaccA[nt], 0, 0, 0);
        oaccB[nt] = __builtin_amdgcn_mfma_f32_16x16x32_bf16(vf, pfragB, oaccB[nt], 0, 0, 0);
      }
      __builtin_amdgcn_s_setprio(0);
    }

    asm volatile("s_waitcnt vmcnt(0)" ::: "memory");
    __syncthreads();
    cur = nb;
  }

  lrowA += __shfl_xor(lrowA, 16);
  lrowA += __shfl_xor(lrowA, 32);
  lrowB += __shfl_xor(lrowB, 16);
  lrowB += __shfl_xor(lrowB, 32);
  if (fq == 0) {
    ml[((size_t)z * 32 + bh) * NQ + q0 + w * 32 + fr] = float2{mrowA, lrowA};
    ml[((size_t)z * 32 + bh) * NQ + q0 + w * 32 + 16 + fr] = float2{mrowB, lrowB};
  }

  // epilogue: two passes through wave-private 16x68 f32 LDS region
  float* tb = (float*)smem + w * 1088;
  const int qloc = lane >> 2, dl = lane & 3;
#pragma unroll
  for (int gsel = 0; gsel < 2; ++gsel) {
    const f32x4* oc = gsel ? oaccB : oaccA;
#pragma unroll
    for (int nt = 0; nt < 4; ++nt)
#pragma unroll
      for (int i = 0; i < 4; ++i)
        tb[fr * 68 + nt * 16 + fq * 4 + i] = oc[nt][i];
    const float* trow = tb + qloc * 68 + dl * 16;
    u16* gdst = Opart +
        (((size_t)z * 32 + bh) * NQ + q0 + w * 32 + gsel * 16 + qloc) * 64 + dl * 16;
    u16x8 o0, o1;
#pragma unroll
    for (int j = 0; j < 8; ++j) {
      o0[j] = f2bf(trow[j]);
      o1[j] = f2bf(trow[8 + j]);
    }
    *(u16x8*)gdst = o0;
    *(u16x8*)(gdst + 8) = o1;
  }
}

// ---------------- combine split partials -> bf16 Aout ----------------------
__global__ __launch_bounds__(256) void combine_kernel(
    const u16* __restrict__ Opart, const float2* __restrict__ ml,
    u16* __restrict__ out) {
  const int bh = blockIdx.y, b = bh >> 4, h = bh & 15;
  const int q = blockIdx.x * 64 + (threadIdx.x >> 2);
  const int dl = threadIdx.x & 3;
  float2 mm[NSPLIT];
  float M = -1e30f;
#pragma unroll
  for (int zz = 0; zz < NSPLIT; ++zz) {
    mm[zz] = ml[((size_t)zz * 32 + bh) * NQ + q];
    M = fmaxf(M, mm[zz].x);
  }
  float wz[NSPLIT], lsum = 0.f;
#pragma unroll
  for (int zz = 0; zz < NSPLIT; ++zz) {
    wz[zz] = fexp2(mm[zz].x - M);
    lsum += mm[zz].y * wz[zz];
  }
  const float inv = 1.f / lsum;
  float acc[16] = {};
#pragma unroll
  for (int zz = 0; zz < NSPLIT; ++zz) {
    const u16* op = Opart + (((size_t)zz * 32 + bh) * NQ + q) * 64 + dl * 16;
    u16x8 a0 = *(const u16x8*)op;
    u16x8 a1 = *(const u16x8*)(op + 8);
    float wi = wz[zz] * inv;
#pragma unroll
    for (int j = 0; j < 8; ++j) {
      acc[j] += wi * bf2f(a0[j]);
      acc[8 + j] += wi * bf2f(a1[j]);
    }
  }
  u16* orow = out + ((size_t)b * NQ + q) * H + h * HD + dl * 16;
  u16x8 o0, o1;
#pragma unroll
  for (int j = 0; j < 8; ++j) {
    o0[j] = f2bf(acc[j]);
    o1[j] = f2bf(acc[8 + j]);
  }
  *(u16x8*)orow = o0;
  *(u16x8*)(orow + 8) = o1;
}

// ---------------------------------------------------------------------------
extern "C" void kernel_launch(void* const* d_in, const int* in_sizes, int n_in,
                              void* d_out, int out_size, void* d_ws, size_t ws_size,
                              hipStream_t stream) {
  const float* queries = (const float*)d_in[0];
  const float* keys_values = (const float*)d_in[1];
  const void* amask = d_in[2];
  const float* W_qkv = (const float*)d_in[3];
  const float* b_qkv = (const float*)d_in[4];
  const float* W_out = (const float*)d_in[5];
  const float* b_out = (const float*)d_in[6];
  const float* gamma = (const float*)d_in[7];
  const float* beta = (const float*)d_in[8];

  char* ws = (char*)d_ws;
  unsigned char* maskN = (unsigned char*)ws;                 // 8 KB
  u16* Xq = (u16*)(ws + 8192);                               // [2048][1024]
  u16* Xkv = Xq + (size_t)Bb * NQ * H;                       // [8192][1024]
  u16* Wtq = Xkv + (size_t)Bb * S * H;                       // [3072][1024]
  u16* Wto = Wtq + (size_t)3 * H * H;                        // [1024][1024]
  u16* Qbuf = Wto + (size_t)H * H;                           // [B][NH][NQ][HD]
  u16* Kbuf = Qbuf + (size_t)Bb * NQ * H;                    // [B][NH][S][HD]; V^T follows
  u16* Aout = Kbuf + (size_t)2 * Bb * S * H;                 // [2048][1024]
  u16* Opart = (u16*)(ws + 8192);                            // 16 MB bf16 overlay
  float2* ml = (float2*)((char*)Opart + (size_t)NSPLIT * 32 * NQ * 64 * 2);  // 1 MB

  hipLaunchKernelGGL(prep_kernel, dim3(6657), dim3(256), 0, stream,
                     (const unsigned char*)amask, maskN, queries, keys_values,
                     gamma, beta, Xq, Xkv, W_qkv, W_out, Wtq, Wto);
  hipLaunchKernelGGL(gemm_q_kernel, dim3(8, 16), dim3(256), 0, stream,
                     Xq, Wtq, b_qkv, Qbuf);
  hipLaunchKernelGGL(gemm_kv_kernel, dim3(256), dim3(512), 0, stream,
                     Xkv, Wtq + (size_t)H * H, b_qkv + H, Kbuf);
  hipLaunchKernelGGL(attn_kernel, dim3(NQ / 256 * Bb * NH * NSPLIT), dim3(512), 0, stream,
                     Qbuf, Kbuf, Kbuf + (size_t)Bb * S * H, maskN, Opart, ml);
  hipLaunchKernelGGL(combine_kernel, dim3(NQ / 64, Bb * NH), dim3(256), 0, stream,
                     Opart, ml, Aout);
  hipLaunchKernelGGL(gemm_out_kernel, dim3(H / 128, Bb * NQ / 128), dim3(256), 0, stream,
                     Aout, Wto, b_out, (float*)d_out);
}